// Round 8
// baseline (941.847 us; speedup 1.0000x reference)
//
#include <hip/hip_runtime.h>
#include <hip/hip_fp16.h>

#define NA 100000
#define NBATCH 4096
#define NBIN 1971       // 5 maps * 391 atom-ranges + 16 batch-ranges
#define MAPS_BINS 1955  // 5 * 391

typedef _Float16 f16;
typedef f16 half8 __attribute__((ext_vector_type(8)));
typedef f16 half4 __attribute__((ext_vector_type(4)));
typedef float f32x4 __attribute__((ext_vector_type(4)));
union HU { uint4 u; half8 h; f16 s[8]; };

// ---------------- two-level counting sort CSR build ----------------
__device__ __forceinline__ unsigned capbase_of(int b) {
  if (b < 391)  return 0u       + (unsigned)(b       ) * 1536u;
  if (b < 782)  return 600576u  + (unsigned)(b -  391) * 2048u;
  if (b < 1173) return 1401344u + (unsigned)(b -  782) * 2560u;
  if (b < 1564) return 2402304u + (unsigned)(b - 1173) * 1024u;
  if (b < 1955) return 2802688u + (unsigned)(b - 1564) * 1232u;
  return 3284400u + (unsigned)(b - 1955) * 12500u;
}

struct PassAParams {
  const int* row[6];
  int start[6];
  int total;
};

__global__ __launch_bounds__(256) void k_passA(PassAParams pp, unsigned* ccursor,
                                               unsigned* pairs) {
  __shared__ int hist[NBIN];
  __shared__ unsigned hbase[NBIN];
  int t = threadIdx.x;
  for (int b = t; b < NBIN; b += 256) hist[b] = 0;
  __syncthreads();
  int g0 = blockIdx.x * 8192;
  unsigned keys[32];
#pragma unroll
  for (int i = 0; i < 32; i++) {
    int g = g0 + i * 256 + t;
    keys[i] = 0xFFFFFFFFu;
    if (g < pp.total) {
      int m = 0;
#pragma unroll
      for (int j = 1; j < 6; j++) if (g >= pp.start[j]) m = j;
      int e = g - pp.start[m];
      int a = pp.row[m][e];
      int bin = (m < 5) ? m * 391 + (a >> 8) : MAPS_BINS + (a >> 8);
      keys[i] = ((unsigned)bin << 8) | (unsigned)(a & 255);
      atomicAdd(&hist[bin], 1);
    }
  }
  __syncthreads();
  for (int b = t; b < NBIN; b += 256) {
    int h = hist[b];
    hbase[b] = h ? atomicAdd(&ccursor[b], (unsigned)h) : 0u;
  }
  __syncthreads();
#pragma unroll
  for (int i = 0; i < 32; i++) {
    unsigned kv = keys[i];
    if (kv == 0xFFFFFFFFu) continue;
    int bin = (int)(kv >> 8);
    int g = g0 + i * 256 + t;
    int m = 0;
#pragma unroll
    for (int j = 1; j < 6; j++) if (g >= pp.start[j]) m = j;
    int e = g - pp.start[m];
    unsigned pos = atomicAdd(&hbase[bin], 1u);
    pairs[pos] = ((unsigned)e << 8) | (kv & 255u);
  }
}

__global__ __launch_bounds__(256) void k_cscan(const unsigned* ccursor, unsigned* cbase) {
  __shared__ unsigned s[256];
  int t = threadIdx.x;
  unsigned carry = 0;
  for (int c0 = 0; c0 < NBIN; c0 += 256) {
    int b = c0 + t;
    unsigned v = 0;
    if (b < NBIN) v = ccursor[b] - capbase_of(b);
    s[t] = v;
    __syncthreads();
    for (int d = 1; d < 256; d <<= 1) {
      unsigned x = (t >= d) ? s[t - d] : 0;
      __syncthreads();
      s[t] += x;
      __syncthreads();
    }
    if (b < NBIN) cbase[b] = s[t] - v + carry;
    unsigned tot = s[255];
    __syncthreads();
    carry += tot;
  }
}

__global__ __launch_bounds__(256) void k_passB(const unsigned* ccursor, const unsigned* cbase,
                                               const unsigned* pairs, int* bucket,
                                               int* cnt, int* basea) {
  __shared__ int hist[256];
  __shared__ int scn[256];
  __shared__ unsigned cur[256];
  int b = blockIdx.x;
  int t = threadIdx.x;
  unsigned cb0 = capbase_of(b);
  int count = (int)(ccursor[b] - cb0);
  const unsigned* src = pairs + cb0;
  hist[t] = 0;
  __syncthreads();
  for (int i = t; i < count; i += 256) atomicAdd(&hist[src[i] & 255u], 1);
  __syncthreads();
  int h = hist[t];
  scn[t] = h;
  __syncthreads();
  for (int d = 1; d < 256; d <<= 1) {
    int x = (t >= d) ? scn[t - d] : 0;
    __syncthreads();
    scn[t] += x;
    __syncthreads();
  }
  int excl = scn[t] - h;
  unsigned gbase = cbase[b];
  int m, a0, off, amax;
  if (b < MAPS_BINS) { m = b / 391; a0 = (b - m * 391) << 8; off = m * 100000; amax = 100000; }
  else { m = 5; a0 = (b - MAPS_BINS) << 8; off = 500000; amax = NBATCH; }
  if (a0 + t < amax) {
    cnt[off + a0 + t] = h;
    basea[off + a0 + t] = (int)(gbase + (unsigned)excl);
  }
  cur[t] = gbase + (unsigned)excl;
  __syncthreads();
  for (int i = t; i < count; i += 256) {
    unsigned v = src[i];
    unsigned pos = atomicAdd(&cur[v & 255u], 1u);
    bucket[pos] = (int)(v >> 8);
  }
}

// ---------------- merged prep kernel: atom_init + prepB + prepW + prepT + initc --------

struct PrepParams {
  const int* xa; const float *e0; const float *e1; const float *e2; f16* x;
  const float *pK; const float *cK; f16* Bp;
  const float *pW; const float *cW; const float *pWa; const float *cWa; f16* Wp;
  const float *path_emb; const float *cycle_emb; f16* T;
  unsigned* ccursor;
};

__global__ __launch_bounds__(256) void k_prep(PrepParams q) {
  int bid = blockIdx.x, t = threadIdx.x;
  if (bid < 6250) {
    int idx = bid * 256 + t;
    int a = idx >> 4, qq = idx & 15;
    int f0 = q.xa[a * 3], f1 = q.xa[a * 3 + 1], f2 = q.xa[a * 3 + 2];
    float4 v0 = ((const float4*)q.e0)[f0 * 16 + qq];
    float4 v1 = ((const float4*)q.e1)[f1 * 16 + qq];
    float4 v2 = ((const float4*)q.e2)[f2 * 16 + qq];
    half4 h = {(f16)(v0.x + v1.x + v2.x), (f16)(v0.y + v1.y + v2.y),
               (f16)(v0.z + v1.z + v2.z), (f16)(v0.w + v1.w + v2.w)};
    ((half4*)q.x)[idx] = h;
  } else if (bid < 6730) {
    int tid = (bid - 6250) * 256 + t;
    int set = tid / 12288, pos = tid % 12288;
    int j = pos & 7, lane = (pos >> 3) & 63, kcnt = pos >> 9;
    int kc = kcnt % 6, nt = kcnt / 6;
    int k = kc * 32 + ((lane >> 4) << 3) + j;
    int n = (nt << 4) + (lane & 15);
    int w = k >> 6, ji = k & 63;
    const float* K = (set < 6) ? (q.pK + set * 3 * 4096) : (q.cK + (set - 6) * 3 * 4096);
    float v = K[w * 4096 + ji * 64 + n];
    if (set >= 6) v = 0.5f * (v + K[(2 - w) * 4096 + ji * 64 + n]);
    q.Bp[tid] = (f16)v;
  } else if (bid < 7050) {
    int tid = (bid - 6730) * 256 + t;
    int set = tid >> 12, pos = tid & 4095;
    int j = pos & 7, lane = (pos >> 3) & 63, ntkc = pos >> 9;
    int kc = ntkc & 1, nt = ntkc >> 1;
    int k = kc * 32 + ((lane >> 4) << 3) + j;
    int n = (nt << 4) + (lane & 15);
    const float* W;
    if (set < 6) W = q.pW + set * 4096;
    else if (set < 10) W = q.cW + (set - 6) * 4096;
    else if (set < 16) W = q.pWa + (set - 10) * 4096;
    else W = q.cWa + (set - 16) * 4096;
    q.Wp[tid] = (f16)W[k * 64 + n];
  } else {
    int idx = (bid - 7050) * 256 + t;
    if (idx < 1664) {
      float v = (idx < 1152) ? q.path_emb[idx] : q.cycle_emb[idx - 1152];
      q.T[idx] = (f16)v;
    }
    if (idx < NBIN) q.ccursor[idx] = capbase_of(idx);
  }
}

// ---------------- fused a2p+conv (swapped-operand MFMA) ----------------
// R7 skeleton (interleaved gathers, 4 barriers, bias-init acc, pk-f16 epilogue RMW).
// New: prefetch / copy-out loops software-unrolled 3-wide (all loads issued before
// all ds_writes) — removes 2 serialized global-latency round-trips per phase.

struct FusedParams {
  const f16* xh;
  const int* gidx[3];
  const int* vals[3];
  const f16* tab[3];
  __half* xp[3];
  const f16* Wa[3];
  const float* ba[3];
  const f16* Bp[3];
  const float* Kb[3];
  int k[3];
  int P[3];
  int ppb[3];
  int blk_start[3];
  int nseg;
  int cyclic;
  int use_tab;
};

__global__ __launch_bounds__(256) void k_fused(FusedParams p) {
  __shared__ uint4 xn4[873];     // 97 rows x 9 uint4 (72 f16/row, row 96 = zero pad)
  __shared__ float bl[64], kbl[64];
  __shared__ int ridx[96];
  __shared__ short prevs[96], nexts[96];
  int bid = blockIdx.x;
  int seg = 0;
#pragma unroll
  for (int i = 1; i < 3; i++) if (i < p.nseg && bid >= p.blk_start[i]) seg = i;
  int kk = p.k[seg], ppb = p.ppb[seg], P = p.P[seg];
  int cyc = p.cyclic;
  int t = threadIdx.x;
  int p0 = (bid - p.blk_start[seg]) * ppb;
  int np = min(ppb, P - p0);
  int R = np * kk;    // always a multiple of 16 for these ppb choices
  int mtb = R >> 4;
  long ebase = (long)p0 * kk;
  if (t < 64) { bl[t] = p.ba[seg][t]; kbl[t] = p.Kb[seg][t]; }
  if (t < 9) { uint4 z; z.x = z.y = z.z = z.w = 0; xn4[96 * 9 + t] = z; }
  if (t < R) ridx[t] = p.gidx[seg][ebase + t];
  if (t < 96) {
    int sm = t % kk;
    prevs[t] = (short)((sm >= 1) ? t - 1 : (cyc ? t + kk - 1 : 96));
    nexts[t] = (short)((sm + 1 < kk) ? t + 1 : (cyc ? t + 1 - kk : 96));
  }
  uint4* xg = (uint4*)(p.xp[seg] + (long)ebase * 64);
  int n8 = R * 8;   // <= 768 = 3*256
  // residual prefetch into xn4, 3-wide unrolled (loads first, then ds_writes)
  if (p.use_tab) {
    const uint4* tabu = (const uint4*)p.tab[seg];
    const int* vseg = p.vals[seg];
    int vr[3];
#pragma unroll
    for (int u = 0; u < 3; u++) {
      int idx = t + 256 * u;
      if (idx < n8) vr[u] = vseg[ebase + (idx >> 3)];
    }
    uint4 pf[3];
#pragma unroll
    for (int u = 0; u < 3; u++) {
      int idx = t + 256 * u;
      if (idx < n8) pf[u] = tabu[vr[u] * 8 + (idx & 7)];
    }
#pragma unroll
    for (int u = 0; u < 3; u++) {
      int idx = t + 256 * u;
      if (idx < n8) xn4[(idx >> 3) * 9 + (idx & 7)] = pf[u];
    }
  } else {
    uint4 pf[3];
#pragma unroll
    for (int u = 0; u < 3; u++) {
      int idx = t + 256 * u;
      if (idx < n8) pf[u] = xg[idx];
    }
#pragma unroll
    for (int u = 0; u < 3; u++) {
      int idx = t + 256 * u;
      if (idx < n8) xn4[(idx >> 3) * 9 + (idx & 7)] = pf[u];
    }
  }
  __syncthreads();
  int lane = t & 63, wid = t >> 6;
  int wave_n = wid & 1, wave_m = wid >> 1;
  int mtA = (mtb + 1) >> 1;
  int m0 = wave_m ? mtA : 0;
  int mcnt = wave_m ? (mtb - mtA) : mtA;
  f16* xnh = (f16*)xn4;
  int chq0 = wave_n * 32 + ((lane >> 4) << 2);   // jn=0 channel quad
  int chq1 = chq0 + 16;                           // jn=1 channel quad
  // stage A: xn += relu(x_gather @ Wa + ba)  (bias via acc init; pk-f16 residual add)
  {
    f32x4 b0 = {bl[chq0], bl[chq0 + 1], bl[chq0 + 2], bl[chq0 + 3]};
    f32x4 b1 = {bl[chq1], bl[chq1 + 1], bl[chq1 + 2], bl[chq1 + 3]};
    f32x4 acc1[3][2];
#pragma unroll
    for (int i = 0; i < 3; i++) { acc1[i][0] = b0; acc1[i][1] = b1; }
    const uint4* Wau = (const uint4*)p.Wa[seg];
    HU w[2][2];
#pragma unroll
    for (int kc = 0; kc < 2; kc++)
#pragma unroll
      for (int jn = 0; jn < 2; jn++)
        w[kc][jn].u = Wau[(((wave_n * 2 + jn) << 1) + kc) * 64 + lane];
    const uint4* xh4 = (const uint4*)p.xh;
#pragma unroll
    for (int i = 0; i < 3; i++) {
      if (i >= mcnt) continue;
      int rowid = ridx[((m0 + i) << 4) + (lane & 15)];
      HU xa, xb;
      xa.u = xh4[(long)rowid * 8 + (lane >> 4)];
      xb.u = xh4[(long)rowid * 8 + 4 + (lane >> 4)];
#pragma unroll
      for (int jn = 0; jn < 2; jn++) {
        acc1[i][jn] = __builtin_amdgcn_mfma_f32_16x16x32_f16(w[0][jn].h, xa.h, acc1[i][jn], 0, 0, 0);
        acc1[i][jn] = __builtin_amdgcn_mfma_f32_16x16x32_f16(w[1][jn].h, xb.h, acc1[i][jn], 0, 0, 0);
      }
    }
#pragma unroll
    for (int i = 0; i < 3; i++) {
      if (i >= mcnt) continue;
      int r = ((m0 + i) << 4) + (lane & 15);
#pragma unroll
      for (int jn = 0; jn < 2; jn++) {
        int chq = jn ? chq1 : chq0;
        half4 cv;
#pragma unroll
        for (int reg = 0; reg < 4; reg++) {
          float v = acc1[i][jn][reg];
          cv[reg] = (f16)(v > 0.f ? v : 0.f);
        }
        half4* pxl = (half4*)(xnh + r * 72 + chq);
        *pxl = *pxl + cv;   // v_pk_add_f16 x2
      }
    }
  }
  __syncthreads();
  // conv MFMAs reading xn4 (neighbor rows via LDS tables); bias via acc init
  f32x4 k0 = {kbl[chq0], kbl[chq0 + 1], kbl[chq0 + 2], kbl[chq0 + 3]};
  f32x4 k1 = {kbl[chq1], kbl[chq1 + 1], kbl[chq1 + 2], kbl[chq1 + 3]};
  f32x4 acc2[3][2];
#pragma unroll
  for (int i = 0; i < 3; i++) { acc2[i][0] = k0; acc2[i][1] = k1; }
  int rdw[3][3];
#pragma unroll
  for (int i = 0; i < 3; i++) {
    if (i >= mcnt) continue;
    int mr = ((m0 + i) << 4) + (lane & 15);
    rdw[i][0] = prevs[mr];
    rdw[i][1] = mr;
    rdw[i][2] = nexts[mr];
  }
  const uint4* Bg = (const uint4*)p.Bp[seg];
  for (int kc = 0; kc < 6; kc++) {
    int w_ = kc >> 1;
    int chunk = ((kc & 1) << 2) + (lane >> 4);
    HU ak[2], xv[3];
#pragma unroll
    for (int jn = 0; jn < 2; jn++)
      ak[jn].u = Bg[((wave_n * 2 + jn) * 6 + kc) * 64 + lane];
#pragma unroll
    for (int i = 0; i < 3; i++)
      if (i < mcnt) xv[i].u = xn4[rdw[i][w_] * 9 + chunk];
#pragma unroll
    for (int i = 0; i < 3; i++)
      if (i < mcnt) {
#pragma unroll
        for (int jn = 0; jn < 2; jn++)
          acc2[i][jn] = __builtin_amdgcn_mfma_f32_16x16x32_f16(ak[jn].h, xv[i].h, acc2[i][jn], 0, 0, 0);
      }
  }
  __syncthreads();  // conv reads of xn4 complete before overwrite
  // epilogue 2: final = xn + relu(conv + Kb), pk-f16 RMW in LDS
#pragma unroll
  for (int i = 0; i < 3; i++) {
    if (i >= mcnt) continue;
    int r = ((m0 + i) << 4) + (lane & 15);
#pragma unroll
    for (int jn = 0; jn < 2; jn++) {
      int chq = jn ? chq1 : chq0;
      half4 cv;
#pragma unroll
      for (int reg = 0; reg < 4; reg++) {
        float v = acc2[i][jn][reg];
        cv[reg] = (f16)(v > 0.f ? v : 0.f);
      }
      half4* pxl = (half4*)(xnh + r * 72 + chq);
      *pxl = *pxl + cv;
    }
  }
  __syncthreads();
  // coalesced copy-out, 3-wide unrolled (ds_reads first, then stores)
  {
    uint4 co[3];
#pragma unroll
    for (int u = 0; u < 3; u++) {
      int idx = t + 256 * u;
      if (idx < n8) co[u] = xn4[(idx >> 3) * 9 + (idx & 7)];
    }
#pragma unroll
    for (int u = 0; u < 3; u++) {
      int idx = t + 256 * u;
      if (idx < n8) xg[idx] = co[u];
    }
  }
}

// ---------------- p2a apply v2: CSR gather (no atomics); edge loop unrolled x4 --------

struct Apply2Params {
  const f16* xp[3];
  const int* cnt[3];
  const int* basea[3];
  const int* bucket;
  const f16* Wp[3];
  const float* bias[3];
  int nm;
};

__global__ __launch_bounds__(256) void k_apply2(Apply2Params p, f16* x) {
  __shared__ uint4 Af[512];
  __shared__ float bl[64];
  int t = threadIdx.x;
  int a0 = blockIdx.x * 64;
  int lane = t & 63, wid = t >> 6;
  int al = t >> 2, q = t & 3;
  int atom = a0 + al;
  f32x4 addv[4];
#pragma unroll
  for (int nt = 0; nt < 4; nt++) { f32x4 z = {0.f, 0.f, 0.f, 0.f}; addv[nt] = z; }
  for (int mi = 0; mi < p.nm; mi++) {
    __syncthreads();
    if (t < 64) bl[t] = p.bias[mi][t];
    float s[16];
#pragma unroll
    for (int i = 0; i < 16; i++) s[i] = 0.f;
    int cb = 0, base = 0;
    if (atom < NA) { cb = p.cnt[mi][atom]; base = p.basea[mi][atom]; }
    const uint4* xpu = (const uint4*)p.xp[mi];
    int i = 0;
    for (; i + 4 <= cb; i += 4) {
      int e0 = p.bucket[base + i], e1 = p.bucket[base + i + 1];
      int e2 = p.bucket[base + i + 2], e3 = p.bucket[base + i + 3];
      HU va0, vb0, va1, vb1, va2, vb2, va3, vb3;
      va0.u = xpu[(long)e0 * 8 + q * 2]; vb0.u = xpu[(long)e0 * 8 + q * 2 + 1];
      va1.u = xpu[(long)e1 * 8 + q * 2]; vb1.u = xpu[(long)e1 * 8 + q * 2 + 1];
      va2.u = xpu[(long)e2 * 8 + q * 2]; vb2.u = xpu[(long)e2 * 8 + q * 2 + 1];
      va3.u = xpu[(long)e3 * 8 + q * 2]; vb3.u = xpu[(long)e3 * 8 + q * 2 + 1];
#pragma unroll
      for (int j = 0; j < 8; j++) {
        s[j] += ((float)va0.s[j] + (float)va1.s[j]) + ((float)va2.s[j] + (float)va3.s[j]);
        s[8 + j] += ((float)vb0.s[j] + (float)vb1.s[j]) + ((float)vb2.s[j] + (float)vb3.s[j]);
      }
    }
    for (; i < cb; i++) {
      int e = p.bucket[base + i];
      HU v0, v1;
      v0.u = xpu[(long)e * 8 + q * 2];
      v1.u = xpu[(long)e * 8 + q * 2 + 1];
#pragma unroll
      for (int j = 0; j < 8; j++) { s[j] += (float)v0.s[j]; s[8 + j] += (float)v1.s[j]; }
    }
    float inv = 1.f / (float)(cb > 0 ? cb : 1);
    HU o0, o1;
#pragma unroll
    for (int j = 0; j < 8; j++) { o0.s[j] = (f16)(s[j] * inv); o1.s[j] = (f16)(s[8 + j] * inv); }
    int jb = ((al >> 4) * 2 + (q >> 1)) * 64 + (q & 1) * 32 + (al & 15);
    Af[jb] = o0.u;
    Af[jb + 16] = o1.u;
    __syncthreads();
    HU af0, af1;
    af0.u = Af[((wid << 1) + 0) * 64 + lane];
    af1.u = Af[((wid << 1) + 1) * 64 + lane];
    const uint4* Wu = (const uint4*)p.Wp[mi];
#pragma unroll
    for (int nt = 0; nt < 4; nt++) {
      HU b0, b1;
      b0.u = Wu[((nt << 1) + 0) * 64 + lane];
      b1.u = Wu[((nt << 1) + 1) * 64 + lane];
      float bv = bl[nt * 16 + (lane & 15)];
      f32x4 z = {bv, bv, bv, bv};
      z = __builtin_amdgcn_mfma_f32_16x16x32_f16(af0.h, b0.h, z, 0, 0, 0);
      z = __builtin_amdgcn_mfma_f32_16x16x32_f16(af1.h, b1.h, z, 0, 0, 0);
#pragma unroll
      for (int r = 0; r < 4; r++) {
        float vv = z[r];
        addv[nt][r] += vv > 0.f ? vv : 0.f;
      }
    }
  }
  int rowb = a0 + wid * 16 + ((lane >> 4) << 2);
#pragma unroll
  for (int nt = 0; nt < 4; nt++) {
    int n = nt * 16 + (lane & 15);
#pragma unroll
    for (int r = 0; r < 4; r++) {
      int atomw = rowb + r;
      if (atomw < NA) {
        long oi = (long)atomw * 64 + n;
        x[oi] = (f16)((float)x[oi] + addv[nt][r]);
      }
    }
  }
}

// ---------------- batch mean over f16 x ----------------

__global__ __launch_bounds__(256) void k_meanscatter(const f16* src, const int* bucket,
                                                     const int* basea, const int* cnta,
                                                     float* dst, int nseg) {
  int wid = (blockIdx.x * 256 + threadIdx.x) >> 6;
  int lane = threadIdx.x & 63;
  if (wid >= nseg) return;
  int b0 = basea[wid], cnt = cnta[wid];
  float s = 0.f;
  for (int i = 0; i < cnt; i++) {
    int e = bucket[b0 + i];
    s += (float)src[(long)e * 64 + lane];
  }
  dst[(long)wid * 64 + lane] = s / (float)(cnt > 0 ? cnt : 1);
}

// ---------------- head gemm ----------------

__global__ __launch_bounds__(256) void k_head(const float* g1, const float* W,
                                              const float* bias, float* g2) {
  __shared__ float Wl[4096];
  __shared__ float inl[32 * 64];
  __shared__ float bl[64];
  int t = threadIdx.x;
  int brow = blockIdx.x * 32;
#pragma unroll
  for (int i = 0; i < 4; i++) ((float4*)Wl)[t + 256 * i] = ((const float4*)W)[t + 256 * i];
  if (t < 64) bl[t] = bias[t];
  __syncthreads();
#pragma unroll
  for (int i = 0; i < 2; i++) {
    int idx = t + 256 * i;
    int r = idx >> 4, q = idx & 15;
    ((float4*)inl)[idx] = ((const float4*)(g1 + (long)(brow + r) * 64))[q];
  }
  __syncthreads();
  int c = t & 63, rq = t >> 6;
  float acc[8];
#pragma unroll
  for (int i = 0; i < 8; i++) acc[i] = 0.f;
  for (int j = 0; j < 64; j += 4) {
    float w0 = Wl[(j + 0) * 64 + c], w1 = Wl[(j + 1) * 64 + c];
    float w2 = Wl[(j + 2) * 64 + c], w3 = Wl[(j + 3) * 64 + c];
#pragma unroll
    for (int i = 0; i < 8; i++) {
      int r = rq * 8 + i;
      float4 v = *(const float4*)&inl[r * 64 + j];
      acc[i] += v.x * w0 + v.y * w1 + v.z * w2 + v.w * w3;
    }
  }
#pragma unroll
  for (int i = 0; i < 8; i++) {
    long r = brow + rq * 8 + i;
    float v = acc[i] + bl[c];
    g2[r * 64 + c] = v > 0.f ? v : 0.f;
  }
}

__global__ __launch_bounds__(256) void k_final(const float* g2, const float* linW,
                                               const float* linb, float* out) {
  int wid = (blockIdx.x * 256 + threadIdx.x) >> 6;
  int lane = threadIdx.x & 63;
  if (wid >= NBATCH) return;
  float v = g2[(long)wid * 64 + lane] * linW[lane];
  for (int o = 32; o > 0; o >>= 1) v += __shfl_down(v, o, 64);
  if (lane == 0) out[wid] = v + linb[0];
}

__global__ __launch_bounds__(256) void k_zero_out(float* out, int n) {
  for (int i = blockIdx.x * 256 + threadIdx.x; i < n; i += gridDim.x * 256) out[i] = 0.f;
}

// ---------------- launcher ----------------

extern "C" void kernel_launch(void* const* d_in, const int* in_sizes, int n_in,
                              void* d_out, int out_size, void* d_ws, size_t ws_size,
                              hipStream_t stream) {
  (void)in_sizes; (void)n_in;

  const int* x_atom = (const int*)d_in[0];
  const int* vals[5] = {(const int*)d_in[1], (const int*)d_in[4], (const int*)d_in[7],
                        (const int*)d_in[10], (const int*)d_in[13]};
  const int* rowm[5] = {(const int*)d_in[2], (const int*)d_in[5], (const int*)d_in[8],
                        (const int*)d_in[11], (const int*)d_in[14]};
  const int* batch = (const int*)d_in[16];
  const float* aemb0 = (const float*)d_in[17];
  const float* aemb1 = (const float*)d_in[18];
  const float* aemb2 = (const float*)d_in[19];
  const float* path_emb = (const float*)d_in[20];
  const float* cycle_emb = (const float*)d_in[21];
  const float* pW_a2p = (const float*)d_in[22];
  const float* pb_a2p = (const float*)d_in[23];
  const float* pW_p2a = (const float*)d_in[24];
  const float* pb_p2a = (const float*)d_in[25];
  const float* pK = (const float*)d_in[26];
  const float* pKb = (const float*)d_in[27];
  const float* cW_a2p = (const float*)d_in[28];
  const float* cb_a2p = (const float*)d_in[29];
  const float* cW_p2a = (const float*)d_in[30];
  const float* cb_p2a = (const float*)d_in[31];
  const float* cK = (const float*)d_in[32];
  const float* cKb = (const float*)d_in[33];
  const float* alW = (const float*)d_in[34];
  const float* alb = (const float*)d_in[35];
  const float* linW = (const float*)d_in[36];
  const float* linb = (const float*)d_in[37];

  static const int Em[5] = {300000, 400000, 500000, 200000, 240000};
  static const int Km[5] = {3, 4, 5, 5, 6};
  static const int Ppb[5] = {32, 24, 16, 16, 16};
  const int CNT_N = 5 * 100000 + NBATCH;  // 504096
  const int BUCKET_N = 1640000 + NA;      // 1740000

  char* ws = (char*)d_ws;
  size_t off = 0;
  auto alloc = [&](size_t nbytes) -> char* {
    char* p = ws + off;
    off = (off + nbytes + 255) & ~(size_t)255;
    return p;
  };
  f16* x = (f16*)alloc((size_t)NA * 64 * 2);   // f16 master
  __half* xp[5];
  for (int m = 0; m < 5; m++) xp[m] = (__half*)alloc((size_t)Em[m] * 64 * 2);
  float* g1 = (float*)alloc((size_t)NBATCH * 64 * 4);
  float* g2 = (float*)alloc((size_t)NBATCH * 64 * 4);
  int* cnt = (int*)alloc((size_t)CNT_N * 4);
  int* basea = (int*)alloc((size_t)CNT_N * 4);
  int* bucket = (int*)alloc((size_t)BUCKET_N * 4);
  unsigned* ccursor = (unsigned*)alloc((size_t)NBIN * 4);
  unsigned* cbase = (unsigned*)alloc((size_t)NBIN * 4);
  f16* Bp = (f16*)alloc((size_t)10 * 12288 * 2);
  f16* Wpk = (f16*)alloc((size_t)20 * 4096 * 2);
  f16* Tabs = (f16*)alloc((size_t)1664 * 2);
  // pairs array (~14 MB) aliases xp[2]: consumed by k_passB before k_fused writes xp[2].
  unsigned* pairs = (unsigned*)xp[2];

  if (ws_size < off) {
    k_zero_out<<<16, 256, 0, stream>>>((float*)d_out, out_size);
    return;
  }

  // ---- merged prep (atom_init + prepB + prepW + prepT + initc)
  {
    PrepParams q;
    q.xa = x_atom; q.e0 = aemb0; q.e1 = aemb1; q.e2 = aemb2; q.x = x;
    q.pK = pK; q.cK = cK; q.Bp = Bp;
    q.pW = pW_p2a; q.cW = cW_p2a; q.pWa = pW_a2p; q.cWa = cW_a2p; q.Wp = Wpk;
    q.path_emb = path_emb; q.cycle_emb = cycle_emb; q.T = Tabs;
    q.ccursor = ccursor;
    k_prep<<<7058, 256, 0, stream>>>(q);
  }

  // ---- CSR build: two-level counting sort
  PassAParams pp;
  {
    int s = 0;
    for (int m = 0; m < 5; m++) { pp.row[m] = rowm[m]; pp.start[m] = s; s += Em[m]; }
    pp.row[5] = batch; pp.start[5] = s;
    pp.total = s + NA;  // 1740000
  }
  k_passA<<<(1740000 + 8191) / 8192, 256, 0, stream>>>(pp, ccursor, pairs);
  k_cscan<<<1, 256, 0, stream>>>(ccursor, cbase);
  k_passB<<<NBIN, 256, 0, stream>>>(ccursor, cbase, pairs, bucket, cnt, basea);

  int apply_blocks = (NA + 63) / 64;  // 1563

  auto p2aW = [&](int l, int m) -> const f16* {
    return (m < 3) ? Wpk + (size_t)(l * 3 + m) * 4096
                   : Wpk + (size_t)(6 + l * 2 + (m - 3)) * 4096;
  };
  auto p2aB = [&](int l, int m) -> const float* {
    return (m < 3) ? pb_p2a + (l * 3 + m) * 64 : cb_p2a + (l * 2 + (m - 3)) * 64;
  };

  for (int l = 0; l < 2; l++) {
    // === paths group (maps 0..2), non-cyclic
    {
      FusedParams fp{};
      fp.nseg = 3; fp.cyclic = 0; fp.xh = x; fp.use_tab = (l == 0) ? 1 : 0;
      int bs = 0;
      for (int m = 0; m < 3; m++) {
        fp.gidx[m] = rowm[m]; fp.xp[m] = xp[m];
        fp.vals[m] = vals[m]; fp.tab[m] = Tabs + (size_t)m * 384;
        fp.Wa[m] = Wpk + (size_t)(10 + l * 3 + m) * 4096;
        fp.ba[m] = pb_a2p + (l * 3 + m) * 64;
        fp.Bp[m] = Bp + (size_t)(l * 3 + m) * 12288;
        fp.Kb[m] = pKb + (l * 3 + m) * 64;
        fp.k[m] = Km[m]; fp.P[m] = Em[m] / Km[m]; fp.ppb[m] = Ppb[m];
        fp.blk_start[m] = bs;
        bs += (fp.P[m] + fp.ppb[m] - 1) / fp.ppb[m];
      }
      k_fused<<<bs, 256, 0, stream>>>(fp);

      Apply2Params ap{};
      ap.nm = 3; ap.bucket = bucket;
      for (int m = 0; m < 3; m++) {
        ap.xp[m] = (const f16*)xp[m];
        ap.cnt[m] = cnt + (size_t)m * 100000;
        ap.basea[m] = basea + (size_t)m * 100000;
        ap.Wp[m] = p2aW(l, m); ap.bias[m] = p2aB(l, m);
      }
      k_apply2<<<apply_blocks, 256, 0, stream>>>(ap, x);
    }
    // === cycles group (maps 3..4), cyclic
    {
      FusedParams fp{};
      fp.nseg = 2; fp.cyclic = 1; fp.xh = x; fp.use_tab = (l == 0) ? 1 : 0;
      int bs = 0;
      for (int m = 3; m < 5; m++) {
        int i = m - 3;
        fp.gidx[i] = rowm[m]; fp.xp[i] = xp[m];
        fp.vals[i] = vals[m]; fp.tab[i] = Tabs + 1152 + (size_t)i * 256;
        fp.Wa[i] = Wpk + (size_t)(16 + l * 2 + i) * 4096;
        fp.ba[i] = cb_a2p + (l * 2 + i) * 64;
        fp.Bp[i] = Bp + (size_t)(6 + l * 2 + i) * 12288;
        fp.Kb[i] = cKb + (l * 2 + i) * 64;
        fp.k[i] = Km[m]; fp.P[i] = Em[m] / Km[m]; fp.ppb[i] = Ppb[m];
        fp.blk_start[i] = bs;
        bs += (fp.P[i] + fp.ppb[i] - 1) / fp.ppb[i];
      }
      k_fused<<<bs, 256, 0, stream>>>(fp);

      Apply2Params ap{};
      ap.nm = 2; ap.bucket = bucket;
      for (int m = 3; m < 5; m++) {
        int i = m - 3;
        ap.xp[i] = (const f16*)xp[m];
        ap.cnt[i] = cnt + (size_t)m * 100000;
        ap.basea[i] = basea + (size_t)m * 100000;
        ap.Wp[i] = p2aW(l, m); ap.bias[i] = p2aB(l, m);
      }
      k_apply2<<<apply_blocks, 256, 0, stream>>>(ap, x);
    }
  }

  // ---- head (basea entries for the batch segment are GLOBAL bucket positions)
  k_meanscatter<<<NBATCH / 4, 256, 0, stream>>>(x, bucket, basea + 500000,
                                                cnt + 500000, g1, NBATCH);
  k_head<<<NBATCH / 32, 256, 0, stream>>>(g1, alW, alb, g2);
  k_final<<<NBATCH / 4, 256, 0, stream>>>(g2, linW, linb, (float*)d_out);
}

// Round 9
// 701.555 us; speedup vs baseline: 1.3425x; 1.3425x over previous
//
#include <hip/hip_runtime.h>
#include <hip/hip_fp16.h>

#define NA 100000
#define NBATCH 4096
#define NBIN 1971       // 5 maps * 391 atom-ranges + 16 batch-ranges
#define MAPS_BINS 1955  // 5 * 391

typedef _Float16 f16;
typedef f16 half8 __attribute__((ext_vector_type(8)));
typedef f16 half4 __attribute__((ext_vector_type(4)));
typedef float f32x4 __attribute__((ext_vector_type(4)));
union HU { uint4 u; half8 h; f16 s[8]; };

// ---------------- two-level counting sort CSR build ----------------
__device__ __forceinline__ unsigned capbase_of(int b) {
  if (b < 391)  return 0u       + (unsigned)(b       ) * 1536u;
  if (b < 782)  return 600576u  + (unsigned)(b -  391) * 2048u;
  if (b < 1173) return 1401344u + (unsigned)(b -  782) * 2560u;
  if (b < 1564) return 2402304u + (unsigned)(b - 1173) * 1024u;
  if (b < 1955) return 2802688u + (unsigned)(b - 1564) * 1232u;
  return 3284400u + (unsigned)(b - 1955) * 12500u;
}

struct PassAParams {
  const int* row[6];
  int start[6];
  int total;
};

__global__ __launch_bounds__(256) void k_passA(PassAParams pp, unsigned* ccursor,
                                               unsigned* pairs) {
  __shared__ int hist[NBIN];
  __shared__ unsigned hbase[NBIN];
  int t = threadIdx.x;
  for (int b = t; b < NBIN; b += 256) hist[b] = 0;
  __syncthreads();
  int g0 = blockIdx.x * 8192;
  unsigned keys[32];
#pragma unroll
  for (int i = 0; i < 32; i++) {
    int g = g0 + i * 256 + t;
    keys[i] = 0xFFFFFFFFu;
    if (g < pp.total) {
      int m = 0;
#pragma unroll
      for (int j = 1; j < 6; j++) if (g >= pp.start[j]) m = j;
      int e = g - pp.start[m];
      int a = pp.row[m][e];
      int bin = (m < 5) ? m * 391 + (a >> 8) : MAPS_BINS + (a >> 8);
      keys[i] = ((unsigned)bin << 8) | (unsigned)(a & 255);
      atomicAdd(&hist[bin], 1);
    }
  }
  __syncthreads();
  for (int b = t; b < NBIN; b += 256) {
    int h = hist[b];
    hbase[b] = h ? atomicAdd(&ccursor[b], (unsigned)h) : 0u;
  }
  __syncthreads();
#pragma unroll
  for (int i = 0; i < 32; i++) {
    unsigned kv = keys[i];
    if (kv == 0xFFFFFFFFu) continue;
    int bin = (int)(kv >> 8);
    int g = g0 + i * 256 + t;
    int m = 0;
#pragma unroll
    for (int j = 1; j < 6; j++) if (g >= pp.start[j]) m = j;
    int e = g - pp.start[m];
    unsigned pos = atomicAdd(&hbase[bin], 1u);
    pairs[pos] = ((unsigned)e << 8) | (kv & 255u);
  }
}

__global__ __launch_bounds__(256) void k_cscan(const unsigned* ccursor, unsigned* cbase) {
  __shared__ unsigned s[256];
  int t = threadIdx.x;
  unsigned carry = 0;
  for (int c0 = 0; c0 < NBIN; c0 += 256) {
    int b = c0 + t;
    unsigned v = 0;
    if (b < NBIN) v = ccursor[b] - capbase_of(b);
    s[t] = v;
    __syncthreads();
    for (int d = 1; d < 256; d <<= 1) {
      unsigned x = (t >= d) ? s[t - d] : 0;
      __syncthreads();
      s[t] += x;
      __syncthreads();
    }
    if (b < NBIN) cbase[b] = s[t] - v + carry;
    unsigned tot = s[255];
    __syncthreads();
    carry += tot;
  }
}

__global__ __launch_bounds__(256) void k_passB(const unsigned* ccursor, const unsigned* cbase,
                                               const unsigned* pairs, int* bucket,
                                               int* cnt, int* basea) {
  __shared__ int hist[256];
  __shared__ int scn[256];
  __shared__ unsigned cur[256];
  int b = blockIdx.x;
  int t = threadIdx.x;
  unsigned cb0 = capbase_of(b);
  int count = (int)(ccursor[b] - cb0);
  const unsigned* src = pairs + cb0;
  hist[t] = 0;
  __syncthreads();
  for (int i = t; i < count; i += 256) atomicAdd(&hist[src[i] & 255u], 1);
  __syncthreads();
  int h = hist[t];
  scn[t] = h;
  __syncthreads();
  for (int d = 1; d < 256; d <<= 1) {
    int x = (t >= d) ? scn[t - d] : 0;
    __syncthreads();
    scn[t] += x;
    __syncthreads();
  }
  int excl = scn[t] - h;
  unsigned gbase = cbase[b];
  int m, a0, off, amax;
  if (b < MAPS_BINS) { m = b / 391; a0 = (b - m * 391) << 8; off = m * 100000; amax = 100000; }
  else { m = 5; a0 = (b - MAPS_BINS) << 8; off = 500000; amax = NBATCH; }
  if (a0 + t < amax) {
    cnt[off + a0 + t] = h;
    basea[off + a0 + t] = (int)(gbase + (unsigned)excl);
  }
  cur[t] = gbase + (unsigned)excl;
  __syncthreads();
  for (int i = t; i < count; i += 256) {
    unsigned v = src[i];
    unsigned pos = atomicAdd(&cur[v & 255u], 1u);
    bucket[pos] = (int)(v >> 8);
  }
}

// ---------------- merged prep kernel: atom_init + prepB + prepW + prepT + initc --------

struct PrepParams {
  const int* xa; const float *e0; const float *e1; const float *e2; f16* x;
  const float *pK; const float *cK; f16* Bp;
  const float *pW; const float *cW; const float *pWa; const float *cWa; f16* Wp;
  const float *path_emb; const float *cycle_emb; f16* T;
  unsigned* ccursor;
};

__global__ __launch_bounds__(256) void k_prep(PrepParams q) {
  int bid = blockIdx.x, t = threadIdx.x;
  if (bid < 6250) {
    int idx = bid * 256 + t;
    int a = idx >> 4, qq = idx & 15;
    int f0 = q.xa[a * 3], f1 = q.xa[a * 3 + 1], f2 = q.xa[a * 3 + 2];
    float4 v0 = ((const float4*)q.e0)[f0 * 16 + qq];
    float4 v1 = ((const float4*)q.e1)[f1 * 16 + qq];
    float4 v2 = ((const float4*)q.e2)[f2 * 16 + qq];
    half4 h = {(f16)(v0.x + v1.x + v2.x), (f16)(v0.y + v1.y + v2.y),
               (f16)(v0.z + v1.z + v2.z), (f16)(v0.w + v1.w + v2.w)};
    ((half4*)q.x)[idx] = h;
  } else if (bid < 6730) {
    int tid = (bid - 6250) * 256 + t;
    int set = tid / 12288, pos = tid % 12288;
    int j = pos & 7, lane = (pos >> 3) & 63, kcnt = pos >> 9;
    int kc = kcnt % 6, nt = kcnt / 6;
    int k = kc * 32 + ((lane >> 4) << 3) + j;
    int n = (nt << 4) + (lane & 15);
    int w = k >> 6, ji = k & 63;
    const float* K = (set < 6) ? (q.pK + set * 3 * 4096) : (q.cK + (set - 6) * 3 * 4096);
    float v = K[w * 4096 + ji * 64 + n];
    if (set >= 6) v = 0.5f * (v + K[(2 - w) * 4096 + ji * 64 + n]);
    q.Bp[tid] = (f16)v;
  } else if (bid < 7050) {
    int tid = (bid - 6730) * 256 + t;
    int set = tid >> 12, pos = tid & 4095;
    int j = pos & 7, lane = (pos >> 3) & 63, ntkc = pos >> 9;
    int kc = ntkc & 1, nt = ntkc >> 1;
    int k = kc * 32 + ((lane >> 4) << 3) + j;
    int n = (nt << 4) + (lane & 15);
    const float* W;
    if (set < 6) W = q.pW + set * 4096;
    else if (set < 10) W = q.cW + (set - 6) * 4096;
    else if (set < 16) W = q.pWa + (set - 10) * 4096;
    else W = q.cWa + (set - 16) * 4096;
    q.Wp[tid] = (f16)W[k * 64 + n];
  } else {
    int idx = (bid - 7050) * 256 + t;
    if (idx < 1664) {
      float v = (idx < 1152) ? q.path_emb[idx] : q.cycle_emb[idx - 1152];
      q.T[idx] = (f16)v;
    }
    if (idx < NBIN) q.ccursor[idx] = capbase_of(idx);
  }
}

// ---------------- fused a2p+conv (swapped-operand MFMA) ----------------
// R7 skeleton (measured 710us total). Prefetch/copy-out use NAMED SCALARS with a
// block-uniform full-tile fast path (n8==768) — R8's predicated uint4 ARRAYS went
// to scratch (WRITE_SIZE 150->437 MB, +70us/dispatch). No arrays, no predicates.

struct FusedParams {
  const f16* xh;
  const int* gidx[3];
  const int* vals[3];
  const f16* tab[3];
  __half* xp[3];
  const f16* Wa[3];
  const float* ba[3];
  const f16* Bp[3];
  const float* Kb[3];
  int k[3];
  int P[3];
  int ppb[3];
  int blk_start[3];
  int nseg;
  int cyclic;
  int use_tab;
};

__global__ __launch_bounds__(256) void k_fused(FusedParams p) {
  __shared__ uint4 xn4[873];     // 97 rows x 9 uint4 (72 f16/row, row 96 = zero pad)
  __shared__ float bl[64], kbl[64];
  __shared__ int ridx[96];
  __shared__ short prevs[96], nexts[96];
  int bid = blockIdx.x;
  int seg = 0;
#pragma unroll
  for (int i = 1; i < 3; i++) if (i < p.nseg && bid >= p.blk_start[i]) seg = i;
  int kk = p.k[seg], ppb = p.ppb[seg], P = p.P[seg];
  int cyc = p.cyclic;
  int t = threadIdx.x;
  int p0 = (bid - p.blk_start[seg]) * ppb;
  int np = min(ppb, P - p0);
  int R = np * kk;    // always a multiple of 16 for these ppb choices
  int mtb = R >> 4;
  long ebase = (long)p0 * kk;
  if (t < 64) { bl[t] = p.ba[seg][t]; kbl[t] = p.Kb[seg][t]; }
  if (t < 9) { uint4 z; z.x = z.y = z.z = z.w = 0; xn4[96 * 9 + t] = z; }
  if (t < R) ridx[t] = p.gidx[seg][ebase + t];
  if (t < 96) {
    int sm = t % kk;
    prevs[t] = (short)((sm >= 1) ? t - 1 : (cyc ? t + kk - 1 : 96));
    nexts[t] = (short)((sm + 1 < kk) ? t + 1 : (cyc ? t + 1 - kk : 96));
  }
  uint4* xg = (uint4*)(p.xp[seg] + (long)ebase * 64);
  int n8 = R * 8;   // 768 for full blocks (only one partial block exists, in map 1)
  int ch = t & 7;
  // residual prefetch into xn4 (named scalars; uniform fast path = no scratch)
  if (p.use_tab) {
    const uint4* tabu = (const uint4*)p.tab[seg];
    const int* vseg = p.vals[seg];
    if (n8 == 768) {
      int v0 = vseg[ebase + (t >> 3)];
      int v1 = vseg[ebase + ((t + 256) >> 3)];
      int v2 = vseg[ebase + ((t + 512) >> 3)];
      uint4 a0 = tabu[v0 * 8 + ch];
      uint4 a1 = tabu[v1 * 8 + ch];
      uint4 a2 = tabu[v2 * 8 + ch];
      xn4[(t >> 3) * 9 + ch] = a0;
      xn4[((t + 256) >> 3) * 9 + ch] = a1;
      xn4[((t + 512) >> 3) * 9 + ch] = a2;
    } else {
      for (int idx = t; idx < n8; idx += 256) {
        int row = idx >> 3;
        xn4[row * 9 + ch] = tabu[vseg[ebase + row] * 8 + ch];
      }
    }
  } else {
    if (n8 == 768) {
      uint4 a0 = xg[t];
      uint4 a1 = xg[t + 256];
      uint4 a2 = xg[t + 512];
      xn4[(t >> 3) * 9 + ch] = a0;
      xn4[((t + 256) >> 3) * 9 + ch] = a1;
      xn4[((t + 512) >> 3) * 9 + ch] = a2;
    } else {
      for (int idx = t; idx < n8; idx += 256)
        xn4[(idx >> 3) * 9 + ch] = xg[idx];
    }
  }
  __syncthreads();
  int lane = t & 63, wid = t >> 6;
  int wave_n = wid & 1, wave_m = wid >> 1;
  int mtA = (mtb + 1) >> 1;
  int m0 = wave_m ? mtA : 0;
  int mcnt = wave_m ? (mtb - mtA) : mtA;
  f16* xnh = (f16*)xn4;
  int chq0 = wave_n * 32 + ((lane >> 4) << 2);   // jn=0 channel quad
  int chq1 = chq0 + 16;                           // jn=1 channel quad
  // stage A: xn += relu(x_gather @ Wa + ba)  (bias via acc init; pk-f16 residual add)
  {
    f32x4 b0 = {bl[chq0], bl[chq0 + 1], bl[chq0 + 2], bl[chq0 + 3]};
    f32x4 b1 = {bl[chq1], bl[chq1 + 1], bl[chq1 + 2], bl[chq1 + 3]};
    f32x4 acc1[3][2];
#pragma unroll
    for (int i = 0; i < 3; i++) { acc1[i][0] = b0; acc1[i][1] = b1; }
    const uint4* Wau = (const uint4*)p.Wa[seg];
    HU w[2][2];
#pragma unroll
    for (int kc = 0; kc < 2; kc++)
#pragma unroll
      for (int jn = 0; jn < 2; jn++)
        w[kc][jn].u = Wau[(((wave_n * 2 + jn) << 1) + kc) * 64 + lane];
    const uint4* xh4 = (const uint4*)p.xh;
#pragma unroll
    for (int i = 0; i < 3; i++) {
      if (i >= mcnt) continue;
      int rowid = ridx[((m0 + i) << 4) + (lane & 15)];
      HU xa, xb;
      xa.u = xh4[(long)rowid * 8 + (lane >> 4)];
      xb.u = xh4[(long)rowid * 8 + 4 + (lane >> 4)];
#pragma unroll
      for (int jn = 0; jn < 2; jn++) {
        acc1[i][jn] = __builtin_amdgcn_mfma_f32_16x16x32_f16(w[0][jn].h, xa.h, acc1[i][jn], 0, 0, 0);
        acc1[i][jn] = __builtin_amdgcn_mfma_f32_16x16x32_f16(w[1][jn].h, xb.h, acc1[i][jn], 0, 0, 0);
      }
    }
#pragma unroll
    for (int i = 0; i < 3; i++) {
      if (i >= mcnt) continue;
      int r = ((m0 + i) << 4) + (lane & 15);
#pragma unroll
      for (int jn = 0; jn < 2; jn++) {
        int chq = jn ? chq1 : chq0;
        half4 cv;
#pragma unroll
        for (int reg = 0; reg < 4; reg++) {
          float v = acc1[i][jn][reg];
          cv[reg] = (f16)(v > 0.f ? v : 0.f);
        }
        half4* pxl = (half4*)(xnh + r * 72 + chq);
        *pxl = *pxl + cv;   // v_pk_add_f16 x2
      }
    }
  }
  __syncthreads();
  // conv MFMAs reading xn4 (neighbor rows via LDS tables); bias via acc init
  f32x4 k0 = {kbl[chq0], kbl[chq0 + 1], kbl[chq0 + 2], kbl[chq0 + 3]};
  f32x4 k1 = {kbl[chq1], kbl[chq1 + 1], kbl[chq1 + 2], kbl[chq1 + 3]};
  f32x4 acc2[3][2];
#pragma unroll
  for (int i = 0; i < 3; i++) { acc2[i][0] = k0; acc2[i][1] = k1; }
  int rdw[3][3];
#pragma unroll
  for (int i = 0; i < 3; i++) {
    if (i >= mcnt) continue;
    int mr = ((m0 + i) << 4) + (lane & 15);
    rdw[i][0] = prevs[mr];
    rdw[i][1] = mr;
    rdw[i][2] = nexts[mr];
  }
  const uint4* Bg = (const uint4*)p.Bp[seg];
  for (int kc = 0; kc < 6; kc++) {
    int w_ = kc >> 1;
    int chunk = ((kc & 1) << 2) + (lane >> 4);
    HU ak[2], xv[3];
#pragma unroll
    for (int jn = 0; jn < 2; jn++)
      ak[jn].u = Bg[((wave_n * 2 + jn) * 6 + kc) * 64 + lane];
#pragma unroll
    for (int i = 0; i < 3; i++)
      if (i < mcnt) xv[i].u = xn4[rdw[i][w_] * 9 + chunk];
#pragma unroll
    for (int i = 0; i < 3; i++)
      if (i < mcnt) {
#pragma unroll
        for (int jn = 0; jn < 2; jn++)
          acc2[i][jn] = __builtin_amdgcn_mfma_f32_16x16x32_f16(ak[jn].h, xv[i].h, acc2[i][jn], 0, 0, 0);
      }
  }
  __syncthreads();  // conv reads of xn4 complete before overwrite
  // epilogue 2: final = xn + relu(conv + Kb), pk-f16 RMW in LDS
#pragma unroll
  for (int i = 0; i < 3; i++) {
    if (i >= mcnt) continue;
    int r = ((m0 + i) << 4) + (lane & 15);
#pragma unroll
    for (int jn = 0; jn < 2; jn++) {
      int chq = jn ? chq1 : chq0;
      half4 cv;
#pragma unroll
      for (int reg = 0; reg < 4; reg++) {
        float v = acc2[i][jn][reg];
        cv[reg] = (f16)(v > 0.f ? v : 0.f);
      }
      half4* pxl = (half4*)(xnh + r * 72 + chq);
      *pxl = *pxl + cv;
    }
  }
  __syncthreads();
  // coalesced copy-out (named scalars; uniform fast path)
  if (n8 == 768) {
    uint4 c0 = xn4[(t >> 3) * 9 + ch];
    uint4 c1 = xn4[((t + 256) >> 3) * 9 + ch];
    uint4 c2 = xn4[((t + 512) >> 3) * 9 + ch];
    xg[t] = c0;
    xg[t + 256] = c1;
    xg[t + 512] = c2;
  } else {
    for (int idx = t; idx < n8; idx += 256)
      xg[idx] = xn4[(idx >> 3) * 9 + ch];
  }
}

// ---------------- p2a apply v2: CSR gather (no atomics); edge loop unrolled x4 --------

struct Apply2Params {
  const f16* xp[3];
  const int* cnt[3];
  const int* basea[3];
  const int* bucket;
  const f16* Wp[3];
  const float* bias[3];
  int nm;
};

__global__ __launch_bounds__(256) void k_apply2(Apply2Params p, f16* x) {
  __shared__ uint4 Af[512];
  __shared__ float bl[64];
  int t = threadIdx.x;
  int a0 = blockIdx.x * 64;
  int lane = t & 63, wid = t >> 6;
  int al = t >> 2, q = t & 3;
  int atom = a0 + al;
  f32x4 addv[4];
#pragma unroll
  for (int nt = 0; nt < 4; nt++) { f32x4 z = {0.f, 0.f, 0.f, 0.f}; addv[nt] = z; }
  for (int mi = 0; mi < p.nm; mi++) {
    __syncthreads();
    if (t < 64) bl[t] = p.bias[mi][t];
    float s[16];
#pragma unroll
    for (int i = 0; i < 16; i++) s[i] = 0.f;
    int cb = 0, base = 0;
    if (atom < NA) { cb = p.cnt[mi][atom]; base = p.basea[mi][atom]; }
    const uint4* xpu = (const uint4*)p.xp[mi];
    int i = 0;
    for (; i + 4 <= cb; i += 4) {
      int e0 = p.bucket[base + i], e1 = p.bucket[base + i + 1];
      int e2 = p.bucket[base + i + 2], e3 = p.bucket[base + i + 3];
      HU va0, vb0, va1, vb1, va2, vb2, va3, vb3;
      va0.u = xpu[(long)e0 * 8 + q * 2]; vb0.u = xpu[(long)e0 * 8 + q * 2 + 1];
      va1.u = xpu[(long)e1 * 8 + q * 2]; vb1.u = xpu[(long)e1 * 8 + q * 2 + 1];
      va2.u = xpu[(long)e2 * 8 + q * 2]; vb2.u = xpu[(long)e2 * 8 + q * 2 + 1];
      va3.u = xpu[(long)e3 * 8 + q * 2]; vb3.u = xpu[(long)e3 * 8 + q * 2 + 1];
#pragma unroll
      for (int j = 0; j < 8; j++) {
        s[j] += ((float)va0.s[j] + (float)va1.s[j]) + ((float)va2.s[j] + (float)va3.s[j]);
        s[8 + j] += ((float)vb0.s[j] + (float)vb1.s[j]) + ((float)vb2.s[j] + (float)vb3.s[j]);
      }
    }
    for (; i < cb; i++) {
      int e = p.bucket[base + i];
      HU v0, v1;
      v0.u = xpu[(long)e * 8 + q * 2];
      v1.u = xpu[(long)e * 8 + q * 2 + 1];
#pragma unroll
      for (int j = 0; j < 8; j++) { s[j] += (float)v0.s[j]; s[8 + j] += (float)v1.s[j]; }
    }
    float inv = 1.f / (float)(cb > 0 ? cb : 1);
    HU o0, o1;
#pragma unroll
    for (int j = 0; j < 8; j++) { o0.s[j] = (f16)(s[j] * inv); o1.s[j] = (f16)(s[8 + j] * inv); }
    int jb = ((al >> 4) * 2 + (q >> 1)) * 64 + (q & 1) * 32 + (al & 15);
    Af[jb] = o0.u;
    Af[jb + 16] = o1.u;
    __syncthreads();
    HU af0, af1;
    af0.u = Af[((wid << 1) + 0) * 64 + lane];
    af1.u = Af[((wid << 1) + 1) * 64 + lane];
    const uint4* Wu = (const uint4*)p.Wp[mi];
#pragma unroll
    for (int nt = 0; nt < 4; nt++) {
      HU b0, b1;
      b0.u = Wu[((nt << 1) + 0) * 64 + lane];
      b1.u = Wu[((nt << 1) + 1) * 64 + lane];
      float bv = bl[nt * 16 + (lane & 15)];
      f32x4 z = {bv, bv, bv, bv};
      z = __builtin_amdgcn_mfma_f32_16x16x32_f16(af0.h, b0.h, z, 0, 0, 0);
      z = __builtin_amdgcn_mfma_f32_16x16x32_f16(af1.h, b1.h, z, 0, 0, 0);
#pragma unroll
      for (int r = 0; r < 4; r++) {
        float vv = z[r];
        addv[nt][r] += vv > 0.f ? vv : 0.f;
      }
    }
  }
  int rowb = a0 + wid * 16 + ((lane >> 4) << 2);
#pragma unroll
  for (int nt = 0; nt < 4; nt++) {
    int n = nt * 16 + (lane & 15);
#pragma unroll
    for (int r = 0; r < 4; r++) {
      int atomw = rowb + r;
      if (atomw < NA) {
        long oi = (long)atomw * 64 + n;
        x[oi] = (f16)((float)x[oi] + addv[nt][r]);
      }
    }
  }
}

// ---------------- batch mean over f16 x ----------------

__global__ __launch_bounds__(256) void k_meanscatter(const f16* src, const int* bucket,
                                                     const int* basea, const int* cnta,
                                                     float* dst, int nseg) {
  int wid = (blockIdx.x * 256 + threadIdx.x) >> 6;
  int lane = threadIdx.x & 63;
  if (wid >= nseg) return;
  int b0 = basea[wid], cnt = cnta[wid];
  float s = 0.f;
  for (int i = 0; i < cnt; i++) {
    int e = bucket[b0 + i];
    s += (float)src[(long)e * 64 + lane];
  }
  dst[(long)wid * 64 + lane] = s / (float)(cnt > 0 ? cnt : 1);
}

// ---------------- head gemm ----------------

__global__ __launch_bounds__(256) void k_head(const float* g1, const float* W,
                                              const float* bias, float* g2) {
  __shared__ float Wl[4096];
  __shared__ float inl[32 * 64];
  __shared__ float bl[64];
  int t = threadIdx.x;
  int brow = blockIdx.x * 32;
#pragma unroll
  for (int i = 0; i < 4; i++) ((float4*)Wl)[t + 256 * i] = ((const float4*)W)[t + 256 * i];
  if (t < 64) bl[t] = bias[t];
  __syncthreads();
#pragma unroll
  for (int i = 0; i < 2; i++) {
    int idx = t + 256 * i;
    int r = idx >> 4, q = idx & 15;
    ((float4*)inl)[idx] = ((const float4*)(g1 + (long)(brow + r) * 64))[q];
  }
  __syncthreads();
  int c = t & 63, rq = t >> 6;
  float acc[8];
#pragma unroll
  for (int i = 0; i < 8; i++) acc[i] = 0.f;
  for (int j = 0; j < 64; j += 4) {
    float w0 = Wl[(j + 0) * 64 + c], w1 = Wl[(j + 1) * 64 + c];
    float w2 = Wl[(j + 2) * 64 + c], w3 = Wl[(j + 3) * 64 + c];
#pragma unroll
    for (int i = 0; i < 8; i++) {
      int r = rq * 8 + i;
      float4 v = *(const float4*)&inl[r * 64 + j];
      acc[i] += v.x * w0 + v.y * w1 + v.z * w2 + v.w * w3;
    }
  }
#pragma unroll
  for (int i = 0; i < 8; i++) {
    long r = brow + rq * 8 + i;
    float v = acc[i] + bl[c];
    g2[r * 64 + c] = v > 0.f ? v : 0.f;
  }
}

__global__ __launch_bounds__(256) void k_final(const float* g2, const float* linW,
                                               const float* linb, float* out) {
  int wid = (blockIdx.x * 256 + threadIdx.x) >> 6;
  int lane = threadIdx.x & 63;
  if (wid >= NBATCH) return;
  float v = g2[(long)wid * 64 + lane] * linW[lane];
  for (int o = 32; o > 0; o >>= 1) v += __shfl_down(v, o, 64);
  if (lane == 0) out[wid] = v + linb[0];
}

__global__ __launch_bounds__(256) void k_zero_out(float* out, int n) {
  for (int i = blockIdx.x * 256 + threadIdx.x; i < n; i += gridDim.x * 256) out[i] = 0.f;
}

// ---------------- launcher ----------------

extern "C" void kernel_launch(void* const* d_in, const int* in_sizes, int n_in,
                              void* d_out, int out_size, void* d_ws, size_t ws_size,
                              hipStream_t stream) {
  (void)in_sizes; (void)n_in;

  const int* x_atom = (const int*)d_in[0];
  const int* vals[5] = {(const int*)d_in[1], (const int*)d_in[4], (const int*)d_in[7],
                        (const int*)d_in[10], (const int*)d_in[13]};
  const int* rowm[5] = {(const int*)d_in[2], (const int*)d_in[5], (const int*)d_in[8],
                        (const int*)d_in[11], (const int*)d_in[14]};
  const int* batch = (const int*)d_in[16];
  const float* aemb0 = (const float*)d_in[17];
  const float* aemb1 = (const float*)d_in[18];
  const float* aemb2 = (const float*)d_in[19];
  const float* path_emb = (const float*)d_in[20];
  const float* cycle_emb = (const float*)d_in[21];
  const float* pW_a2p = (const float*)d_in[22];
  const float* pb_a2p = (const float*)d_in[23];
  const float* pW_p2a = (const float*)d_in[24];
  const float* pb_p2a = (const float*)d_in[25];
  const float* pK = (const float*)d_in[26];
  const float* pKb = (const float*)d_in[27];
  const float* cW_a2p = (const float*)d_in[28];
  const float* cb_a2p = (const float*)d_in[29];
  const float* cW_p2a = (const float*)d_in[30];
  const float* cb_p2a = (const float*)d_in[31];
  const float* cK = (const float*)d_in[32];
  const float* cKb = (const float*)d_in[33];
  const float* alW = (const float*)d_in[34];
  const float* alb = (const float*)d_in[35];
  const float* linW = (const float*)d_in[36];
  const float* linb = (const float*)d_in[37];

  static const int Em[5] = {300000, 400000, 500000, 200000, 240000};
  static const int Km[5] = {3, 4, 5, 5, 6};
  static const int Ppb[5] = {32, 24, 16, 16, 16};
  const int CNT_N = 5 * 100000 + NBATCH;  // 504096
  const int BUCKET_N = 1640000 + NA;      // 1740000

  char* ws = (char*)d_ws;
  size_t off = 0;
  auto alloc = [&](size_t nbytes) -> char* {
    char* p = ws + off;
    off = (off + nbytes + 255) & ~(size_t)255;
    return p;
  };
  f16* x = (f16*)alloc((size_t)NA * 64 * 2);   // f16 master
  __half* xp[5];
  for (int m = 0; m < 5; m++) xp[m] = (__half*)alloc((size_t)Em[m] * 64 * 2);
  float* g1 = (float*)alloc((size_t)NBATCH * 64 * 4);
  float* g2 = (float*)alloc((size_t)NBATCH * 64 * 4);
  int* cnt = (int*)alloc((size_t)CNT_N * 4);
  int* basea = (int*)alloc((size_t)CNT_N * 4);
  int* bucket = (int*)alloc((size_t)BUCKET_N * 4);
  unsigned* ccursor = (unsigned*)alloc((size_t)NBIN * 4);
  unsigned* cbase = (unsigned*)alloc((size_t)NBIN * 4);
  f16* Bp = (f16*)alloc((size_t)10 * 12288 * 2);
  f16* Wpk = (f16*)alloc((size_t)20 * 4096 * 2);
  f16* Tabs = (f16*)alloc((size_t)1664 * 2);
  // pairs array (~14 MB) aliases xp[2]: consumed by k_passB before k_fused writes xp[2].
  unsigned* pairs = (unsigned*)xp[2];

  if (ws_size < off) {
    k_zero_out<<<16, 256, 0, stream>>>((float*)d_out, out_size);
    return;
  }

  // ---- merged prep (atom_init + prepB + prepW + prepT + initc)
  {
    PrepParams q;
    q.xa = x_atom; q.e0 = aemb0; q.e1 = aemb1; q.e2 = aemb2; q.x = x;
    q.pK = pK; q.cK = cK; q.Bp = Bp;
    q.pW = pW_p2a; q.cW = cW_p2a; q.pWa = pW_a2p; q.cWa = cW_a2p; q.Wp = Wpk;
    q.path_emb = path_emb; q.cycle_emb = cycle_emb; q.T = Tabs;
    q.ccursor = ccursor;
    k_prep<<<7058, 256, 0, stream>>>(q);
  }

  // ---- CSR build: two-level counting sort
  PassAParams pp;
  {
    int s = 0;
    for (int m = 0; m < 5; m++) { pp.row[m] = rowm[m]; pp.start[m] = s; s += Em[m]; }
    pp.row[5] = batch; pp.start[5] = s;
    pp.total = s + NA;  // 1740000
  }
  k_passA<<<(1740000 + 8191) / 8192, 256, 0, stream>>>(pp, ccursor, pairs);
  k_cscan<<<1, 256, 0, stream>>>(ccursor, cbase);
  k_passB<<<NBIN, 256, 0, stream>>>(ccursor, cbase, pairs, bucket, cnt, basea);

  int apply_blocks = (NA + 63) / 64;  // 1563

  auto p2aW = [&](int l, int m) -> const f16* {
    return (m < 3) ? Wpk + (size_t)(l * 3 + m) * 4096
                   : Wpk + (size_t)(6 + l * 2 + (m - 3)) * 4096;
  };
  auto p2aB = [&](int l, int m) -> const float* {
    return (m < 3) ? pb_p2a + (l * 3 + m) * 64 : cb_p2a + (l * 2 + (m - 3)) * 64;
  };

  for (int l = 0; l < 2; l++) {
    // === paths group (maps 0..2), non-cyclic
    {
      FusedParams fp{};
      fp.nseg = 3; fp.cyclic = 0; fp.xh = x; fp.use_tab = (l == 0) ? 1 : 0;
      int bs = 0;
      for (int m = 0; m < 3; m++) {
        fp.gidx[m] = rowm[m]; fp.xp[m] = xp[m];
        fp.vals[m] = vals[m]; fp.tab[m] = Tabs + (size_t)m * 384;
        fp.Wa[m] = Wpk + (size_t)(10 + l * 3 + m) * 4096;
        fp.ba[m] = pb_a2p + (l * 3 + m) * 64;
        fp.Bp[m] = Bp + (size_t)(l * 3 + m) * 12288;
        fp.Kb[m] = pKb + (l * 3 + m) * 64;
        fp.k[m] = Km[m]; fp.P[m] = Em[m] / Km[m]; fp.ppb[m] = Ppb[m];
        fp.blk_start[m] = bs;
        bs += (fp.P[m] + fp.ppb[m] - 1) / fp.ppb[m];
      }
      k_fused<<<bs, 256, 0, stream>>>(fp);

      Apply2Params ap{};
      ap.nm = 3; ap.bucket = bucket;
      for (int m = 0; m < 3; m++) {
        ap.xp[m] = (const f16*)xp[m];
        ap.cnt[m] = cnt + (size_t)m * 100000;
        ap.basea[m] = basea + (size_t)m * 100000;
        ap.Wp[m] = p2aW(l, m); ap.bias[m] = p2aB(l, m);
      }
      k_apply2<<<apply_blocks, 256, 0, stream>>>(ap, x);
    }
    // === cycles group (maps 3..4), cyclic
    {
      FusedParams fp{};
      fp.nseg = 2; fp.cyclic = 1; fp.xh = x; fp.use_tab = (l == 0) ? 1 : 0;
      int bs = 0;
      for (int m = 3; m < 5; m++) {
        int i = m - 3;
        fp.gidx[i] = rowm[m]; fp.xp[i] = xp[m];
        fp.vals[i] = vals[m]; fp.tab[i] = Tabs + 1152 + (size_t)i * 256;
        fp.Wa[i] = Wpk + (size_t)(16 + l * 2 + i) * 4096;
        fp.ba[i] = cb_a2p + (l * 2 + i) * 64;
        fp.Bp[i] = Bp + (size_t)(6 + l * 2 + i) * 12288;
        fp.Kb[i] = cKb + (l * 2 + i) * 64;
        fp.k[i] = Km[m]; fp.P[i] = Em[m] / Km[m]; fp.ppb[i] = Ppb[m];
        fp.blk_start[i] = bs;
        bs += (fp.P[i] + fp.ppb[i] - 1) / fp.ppb[i];
      }
      k_fused<<<bs, 256, 0, stream>>>(fp);

      Apply2Params ap{};
      ap.nm = 2; ap.bucket = bucket;
      for (int m = 3; m < 5; m++) {
        int i = m - 3;
        ap.xp[i] = (const f16*)xp[m];
        ap.cnt[i] = cnt + (size_t)m * 100000;
        ap.basea[i] = basea + (size_t)m * 100000;
        ap.Wp[i] = p2aW(l, m); ap.bias[i] = p2aB(l, m);
      }
      k_apply2<<<apply_blocks, 256, 0, stream>>>(ap, x);
    }
  }

  // ---- head (basea entries for the batch segment are GLOBAL bucket positions)
  k_meanscatter<<<NBATCH / 4, 256, 0, stream>>>(x, bucket, basea + 500000,
                                                cnt + 500000, g1, NBATCH);
  k_head<<<NBATCH / 32, 256, 0, stream>>>(g1, alW, alb, g2);
  k_final<<<NBATCH / 4, 256, 0, stream>>>(g2, linW, linb, (float*)d_out);
}

// Round 10
// 666.598 us; speedup vs baseline: 1.4129x; 1.0524x over previous
//
#include <hip/hip_runtime.h>
#include <hip/hip_fp16.h>

#define NA 100000
#define NBATCH 4096
#define NBIN 1971       // 5 maps * 391 atom-ranges + 16 batch-ranges
#define MAPS_BINS 1955  // 5 * 391

typedef _Float16 f16;
typedef f16 half8 __attribute__((ext_vector_type(8)));
typedef f16 half4 __attribute__((ext_vector_type(4)));
typedef float f32x4 __attribute__((ext_vector_type(4)));
union HU { uint4 u; half8 h; f16 s[8]; };

// ---------------- two-level counting sort CSR build (gapped bucket, no scan) ----------
__device__ __forceinline__ unsigned capbase_of(int b) {
  if (b < 391)  return 0u       + (unsigned)(b       ) * 1536u;
  if (b < 782)  return 600576u  + (unsigned)(b -  391) * 2048u;
  if (b < 1173) return 1401344u + (unsigned)(b -  782) * 2560u;
  if (b < 1564) return 2402304u + (unsigned)(b - 1173) * 1024u;
  if (b < 1955) return 2802688u + (unsigned)(b - 1564) * 1232u;
  return 3284400u + (unsigned)(b - 1955) * 12500u;
}
// bucket/pairs capacity = 3484400 slots (bucket stays GAPPED at capbase offsets;
// basea[] holds absolute positions, so no compaction scan is needed)

struct PassAParams {
  const int* row[6];
  int start[6];
  int total;
};

__global__ __launch_bounds__(256) void k_passA(PassAParams pp, unsigned* ccursor,
                                               unsigned* pairs) {
  __shared__ int hist[NBIN];
  __shared__ unsigned hbase[NBIN];
  int t = threadIdx.x;
  for (int b = t; b < NBIN; b += 256) hist[b] = 0;
  __syncthreads();
  int g0 = blockIdx.x * 8192;
  unsigned keys[32];
#pragma unroll
  for (int i = 0; i < 32; i++) {
    int g = g0 + i * 256 + t;
    keys[i] = 0xFFFFFFFFu;
    if (g < pp.total) {
      int m = 0;
#pragma unroll
      for (int j = 1; j < 6; j++) if (g >= pp.start[j]) m = j;
      int e = g - pp.start[m];
      int a = pp.row[m][e];
      int bin = (m < 5) ? m * 391 + (a >> 8) : MAPS_BINS + (a >> 8);
      keys[i] = ((unsigned)bin << 8) | (unsigned)(a & 255);
      atomicAdd(&hist[bin], 1);
    }
  }
  __syncthreads();
  for (int b = t; b < NBIN; b += 256) {
    int h = hist[b];
    hbase[b] = h ? atomicAdd(&ccursor[b], (unsigned)h) : 0u;
  }
  __syncthreads();
#pragma unroll
  for (int i = 0; i < 32; i++) {
    unsigned kv = keys[i];
    if (kv == 0xFFFFFFFFu) continue;
    int bin = (int)(kv >> 8);
    int g = g0 + i * 256 + t;
    int m = 0;
#pragma unroll
    for (int j = 1; j < 6; j++) if (g >= pp.start[j]) m = j;
    int e = g - pp.start[m];
    unsigned pos = atomicAdd(&hbase[bin], 1u);
    pairs[pos] = ((unsigned)e << 8) | (kv & 255u);
  }
}

__global__ __launch_bounds__(256) void k_passB(const unsigned* ccursor,
                                               const unsigned* pairs, int* bucket,
                                               int* cnt, int* basea) {
  __shared__ int hist[256];
  __shared__ int scn[256];
  __shared__ unsigned cur[256];
  int b = blockIdx.x;
  int t = threadIdx.x;
  unsigned cb0 = capbase_of(b);
  int count = (int)(ccursor[b] - cb0);
  const unsigned* src = pairs + cb0;
  hist[t] = 0;
  __syncthreads();
  for (int i = t; i < count; i += 256) atomicAdd(&hist[src[i] & 255u], 1);
  __syncthreads();
  int h = hist[t];
  scn[t] = h;
  __syncthreads();
  for (int d = 1; d < 256; d <<= 1) {
    int x = (t >= d) ? scn[t - d] : 0;
    __syncthreads();
    scn[t] += x;
    __syncthreads();
  }
  int excl = scn[t] - h;
  unsigned gbase = cb0;   // gapped layout: bucket lives at capbase offsets
  int m, a0, off, amax;
  if (b < MAPS_BINS) { m = b / 391; a0 = (b - m * 391) << 8; off = m * 100000; amax = 100000; }
  else { m = 5; a0 = (b - MAPS_BINS) << 8; off = 500000; amax = NBATCH; }
  if (a0 + t < amax) {
    cnt[off + a0 + t] = h;
    basea[off + a0 + t] = (int)(gbase + (unsigned)excl);
  }
  cur[t] = gbase + (unsigned)excl;
  __syncthreads();
  for (int i = t; i < count; i += 256) {
    unsigned v = src[i];
    unsigned pos = atomicAdd(&cur[v & 255u], 1u);
    bucket[pos] = (int)(v >> 8);
  }
}

// ---------------- merged prep kernel: atom_init + prepB + prepW + prepT + initc --------

struct PrepParams {
  const int* xa; const float *e0; const float *e1; const float *e2; f16* x;
  const float *pK; const float *cK; f16* Bp;
  const float *pW; const float *cW; const float *pWa; const float *cWa; f16* Wp;
  const float *path_emb; const float *cycle_emb; f16* T;
  unsigned* ccursor;
};

__global__ __launch_bounds__(256) void k_prep(PrepParams q) {
  int bid = blockIdx.x, t = threadIdx.x;
  if (bid < 6250) {
    int idx = bid * 256 + t;
    int a = idx >> 4, qq = idx & 15;
    int f0 = q.xa[a * 3], f1 = q.xa[a * 3 + 1], f2 = q.xa[a * 3 + 2];
    float4 v0 = ((const float4*)q.e0)[f0 * 16 + qq];
    float4 v1 = ((const float4*)q.e1)[f1 * 16 + qq];
    float4 v2 = ((const float4*)q.e2)[f2 * 16 + qq];
    half4 h = {(f16)(v0.x + v1.x + v2.x), (f16)(v0.y + v1.y + v2.y),
               (f16)(v0.z + v1.z + v2.z), (f16)(v0.w + v1.w + v2.w)};
    ((half4*)q.x)[idx] = h;
  } else if (bid < 6730) {
    int tid = (bid - 6250) * 256 + t;
    int set = tid / 12288, pos = tid % 12288;
    int j = pos & 7, lane = (pos >> 3) & 63, kcnt = pos >> 9;
    int kc = kcnt % 6, nt = kcnt / 6;
    int k = kc * 32 + ((lane >> 4) << 3) + j;
    int n = (nt << 4) + (lane & 15);
    int w = k >> 6, ji = k & 63;
    const float* K = (set < 6) ? (q.pK + set * 3 * 4096) : (q.cK + (set - 6) * 3 * 4096);
    float v = K[w * 4096 + ji * 64 + n];
    if (set >= 6) v = 0.5f * (v + K[(2 - w) * 4096 + ji * 64 + n]);
    q.Bp[tid] = (f16)v;
  } else if (bid < 7050) {
    int tid = (bid - 6730) * 256 + t;
    int set = tid >> 12, pos = tid & 4095;
    int j = pos & 7, lane = (pos >> 3) & 63, ntkc = pos >> 9;
    int kc = ntkc & 1, nt = ntkc >> 1;
    int k = kc * 32 + ((lane >> 4) << 3) + j;
    int n = (nt << 4) + (lane & 15);
    const float* W;
    if (set < 6) W = q.pW + set * 4096;
    else if (set < 10) W = q.cW + (set - 6) * 4096;
    else if (set < 16) W = q.pWa + (set - 10) * 4096;
    else W = q.cWa + (set - 16) * 4096;
    q.Wp[tid] = (f16)W[k * 64 + n];
  } else {
    int idx = (bid - 7050) * 256 + t;
    if (idx < 1664) {
      float v = (idx < 1152) ? q.path_emb[idx] : q.cycle_emb[idx - 1152];
      q.T[idx] = (f16)v;
    }
    if (idx < NBIN) q.ccursor[idx] = capbase_of(idx);
  }
}

// ---------------- fused a2p+conv (swapped-operand MFMA) ----------------
// R9 skeleton + early gather: gidx and x-row fragments are loaded BEFORE the prefetch
// barrier (unconditional, row index clamped to R-1 — no predicated arrays, no scratch),
// overlapping the gather's 2-deep global chain with the residual prefetch.

struct FusedParams {
  const f16* xh;
  const int* gidx[3];
  const int* vals[3];
  const f16* tab[3];
  __half* xp[3];
  const f16* Wa[3];
  const float* ba[3];
  const f16* Bp[3];
  const float* Kb[3];
  int k[3];
  int P[3];
  int ppb[3];
  int blk_start[3];
  int nseg;
  int cyclic;
  int use_tab;
};

__global__ __launch_bounds__(256) void k_fused(FusedParams p) {
  __shared__ uint4 xn4[873];     // 97 rows x 9 uint4 (72 f16/row, row 96 = zero pad)
  __shared__ float bl[64], kbl[64];
  __shared__ short prevs[96], nexts[96];
  int bid = blockIdx.x;
  int seg = 0;
#pragma unroll
  for (int i = 1; i < 3; i++) if (i < p.nseg && bid >= p.blk_start[i]) seg = i;
  int kk = p.k[seg], ppb = p.ppb[seg], P = p.P[seg];
  int cyc = p.cyclic;
  int t = threadIdx.x;
  int p0 = (bid - p.blk_start[seg]) * ppb;
  int np = min(ppb, P - p0);
  int R = np * kk;    // multiple of 16
  int mtb = R >> 4;
  long ebase = (long)p0 * kk;
  int lane = t & 63, wid = t >> 6;
  int wave_n = wid & 1, wave_m = wid >> 1;
  int mtA = (mtb + 1) >> 1;
  int m0 = wave_m ? mtA : 0;
  int mcnt = wave_m ? (mtb - mtA) : mtA;
  if (t < 64) { bl[t] = p.ba[seg][t]; kbl[t] = p.Kb[seg][t]; }
  if (t < 9) { uint4 z; z.x = z.y = z.z = z.w = 0; xn4[96 * 9 + t] = z; }
  if (t < 96) {
    int sm = t % kk;
    prevs[t] = (short)((sm >= 1) ? t - 1 : (cyc ? t + kk - 1 : 96));
    nexts[t] = (short)((sm + 1 < kk) ? t + 1 : (cyc ? t + 1 - kk : 96));
  }
  // ---- early gather issue (pre-barrier; clamped, unconditional, named scalars)
  const int* gseg = p.gidx[seg];
  const uint4* xh4 = (const uint4*)p.xh;
  int l15 = lane & 15, lhi = lane >> 4;
  int rr0 = min(((m0 + 0) << 4) + l15, R - 1);
  int rr1 = min(((m0 + 1) << 4) + l15, R - 1);
  int rr2 = min(((m0 + 2) << 4) + l15, R - 1);
  int rid0 = gseg[ebase + rr0];
  int rid1 = gseg[ebase + rr1];
  int rid2 = gseg[ebase + rr2];
  HU xa0, xb0, xa1, xb1, xa2, xb2;
  xa0.u = xh4[(long)rid0 * 8 + lhi];     xb0.u = xh4[(long)rid0 * 8 + 4 + lhi];
  xa1.u = xh4[(long)rid1 * 8 + lhi];     xb1.u = xh4[(long)rid1 * 8 + 4 + lhi];
  xa2.u = xh4[(long)rid2 * 8 + lhi];     xb2.u = xh4[(long)rid2 * 8 + 4 + lhi];
  // ---- stage-A weight fragments (pre-barrier)
  const uint4* Wau = (const uint4*)p.Wa[seg];
  HU w[2][2];
#pragma unroll
  for (int kc = 0; kc < 2; kc++)
#pragma unroll
    for (int jn = 0; jn < 2; jn++)
      w[kc][jn].u = Wau[(((wave_n * 2 + jn) << 1) + kc) * 64 + lane];
  // ---- residual prefetch into xn4 (R9 spill-free fast path)
  uint4* xg = (uint4*)(p.xp[seg] + (long)ebase * 64);
  int n8 = R * 8;   // 768 for full blocks (one partial block exists, in map 1)
  int ch = t & 7;
  if (p.use_tab) {
    const uint4* tabu = (const uint4*)p.tab[seg];
    const int* vseg = p.vals[seg];
    if (n8 == 768) {
      int v0 = vseg[ebase + (t >> 3)];
      int v1 = vseg[ebase + ((t + 256) >> 3)];
      int v2 = vseg[ebase + ((t + 512) >> 3)];
      uint4 a0 = tabu[v0 * 8 + ch];
      uint4 a1 = tabu[v1 * 8 + ch];
      uint4 a2 = tabu[v2 * 8 + ch];
      xn4[(t >> 3) * 9 + ch] = a0;
      xn4[((t + 256) >> 3) * 9 + ch] = a1;
      xn4[((t + 512) >> 3) * 9 + ch] = a2;
    } else {
      for (int idx = t; idx < n8; idx += 256) {
        int row = idx >> 3;
        xn4[row * 9 + ch] = tabu[vseg[ebase + row] * 8 + ch];
      }
    }
  } else {
    if (n8 == 768) {
      uint4 a0 = xg[t];
      uint4 a1 = xg[t + 256];
      uint4 a2 = xg[t + 512];
      xn4[(t >> 3) * 9 + ch] = a0;
      xn4[((t + 256) >> 3) * 9 + ch] = a1;
      xn4[((t + 512) >> 3) * 9 + ch] = a2;
    } else {
      for (int idx = t; idx < n8; idx += 256)
        xn4[(idx >> 3) * 9 + ch] = xg[idx];
    }
  }
  __syncthreads();
  f16* xnh = (f16*)xn4;
  int chq0 = wave_n * 32 + (lhi << 2);   // jn=0 channel quad
  int chq1 = chq0 + 16;                   // jn=1 channel quad
  // stage A: xn += relu(x_gather @ Wa + ba)  (bias via acc init; pk-f16 residual add)
  {
    f32x4 b0 = {bl[chq0], bl[chq0 + 1], bl[chq0 + 2], bl[chq0 + 3]};
    f32x4 b1 = {bl[chq1], bl[chq1 + 1], bl[chq1 + 2], bl[chq1 + 3]};
    f32x4 acc1[3][2];
#pragma unroll
    for (int i = 0; i < 3; i++) { acc1[i][0] = b0; acc1[i][1] = b1; }
    if (0 < mcnt) {
      acc1[0][0] = __builtin_amdgcn_mfma_f32_16x16x32_f16(w[0][0].h, xa0.h, acc1[0][0], 0, 0, 0);
      acc1[0][0] = __builtin_amdgcn_mfma_f32_16x16x32_f16(w[1][0].h, xb0.h, acc1[0][0], 0, 0, 0);
      acc1[0][1] = __builtin_amdgcn_mfma_f32_16x16x32_f16(w[0][1].h, xa0.h, acc1[0][1], 0, 0, 0);
      acc1[0][1] = __builtin_amdgcn_mfma_f32_16x16x32_f16(w[1][1].h, xb0.h, acc1[0][1], 0, 0, 0);
    }
    if (1 < mcnt) {
      acc1[1][0] = __builtin_amdgcn_mfma_f32_16x16x32_f16(w[0][0].h, xa1.h, acc1[1][0], 0, 0, 0);
      acc1[1][0] = __builtin_amdgcn_mfma_f32_16x16x32_f16(w[1][0].h, xb1.h, acc1[1][0], 0, 0, 0);
      acc1[1][1] = __builtin_amdgcn_mfma_f32_16x16x32_f16(w[0][1].h, xa1.h, acc1[1][1], 0, 0, 0);
      acc1[1][1] = __builtin_amdgcn_mfma_f32_16x16x32_f16(w[1][1].h, xb1.h, acc1[1][1], 0, 0, 0);
    }
    if (2 < mcnt) {
      acc1[2][0] = __builtin_amdgcn_mfma_f32_16x16x32_f16(w[0][0].h, xa2.h, acc1[2][0], 0, 0, 0);
      acc1[2][0] = __builtin_amdgcn_mfma_f32_16x16x32_f16(w[1][0].h, xb2.h, acc1[2][0], 0, 0, 0);
      acc1[2][1] = __builtin_amdgcn_mfma_f32_16x16x32_f16(w[0][1].h, xa2.h, acc1[2][1], 0, 0, 0);
      acc1[2][1] = __builtin_amdgcn_mfma_f32_16x16x32_f16(w[1][1].h, xb2.h, acc1[2][1], 0, 0, 0);
    }
#pragma unroll
    for (int i = 0; i < 3; i++) {
      if (i >= mcnt) continue;
      int r = ((m0 + i) << 4) + l15;
#pragma unroll
      for (int jn = 0; jn < 2; jn++) {
        int chq = jn ? chq1 : chq0;
        half4 cv;
#pragma unroll
        for (int reg = 0; reg < 4; reg++) {
          float v = acc1[i][jn][reg];
          cv[reg] = (f16)(v > 0.f ? v : 0.f);
        }
        half4* pxl = (half4*)(xnh + r * 72 + chq);
        *pxl = *pxl + cv;   // v_pk_add_f16 x2
      }
    }
  }
  __syncthreads();
  // conv MFMAs reading xn4 (neighbor rows via LDS tables); bias via acc init
  f32x4 k0 = {kbl[chq0], kbl[chq0 + 1], kbl[chq0 + 2], kbl[chq0 + 3]};
  f32x4 k1 = {kbl[chq1], kbl[chq1 + 1], kbl[chq1 + 2], kbl[chq1 + 3]};
  f32x4 acc2[3][2];
#pragma unroll
  for (int i = 0; i < 3; i++) { acc2[i][0] = k0; acc2[i][1] = k1; }
  int rdw[3][3];
#pragma unroll
  for (int i = 0; i < 3; i++) {
    if (i >= mcnt) continue;
    int mr = ((m0 + i) << 4) + l15;
    rdw[i][0] = prevs[mr];
    rdw[i][1] = mr;
    rdw[i][2] = nexts[mr];
  }
  const uint4* Bg = (const uint4*)p.Bp[seg];
  for (int kc = 0; kc < 6; kc++) {
    int w_ = kc >> 1;
    int chunk = ((kc & 1) << 2) + lhi;
    HU ak[2], xv[3];
#pragma unroll
    for (int jn = 0; jn < 2; jn++)
      ak[jn].u = Bg[((wave_n * 2 + jn) * 6 + kc) * 64 + lane];
#pragma unroll
    for (int i = 0; i < 3; i++)
      if (i < mcnt) xv[i].u = xn4[rdw[i][w_] * 9 + chunk];
#pragma unroll
    for (int i = 0; i < 3; i++)
      if (i < mcnt) {
#pragma unroll
        for (int jn = 0; jn < 2; jn++)
          acc2[i][jn] = __builtin_amdgcn_mfma_f32_16x16x32_f16(ak[jn].h, xv[i].h, acc2[i][jn], 0, 0, 0);
      }
  }
  __syncthreads();  // conv reads of xn4 complete before overwrite
  // epilogue 2: final = xn + relu(conv + Kb), pk-f16 RMW in LDS
#pragma unroll
  for (int i = 0; i < 3; i++) {
    if (i >= mcnt) continue;
    int r = ((m0 + i) << 4) + l15;
#pragma unroll
    for (int jn = 0; jn < 2; jn++) {
      int chq = jn ? chq1 : chq0;
      half4 cv;
#pragma unroll
      for (int reg = 0; reg < 4; reg++) {
        float v = acc2[i][jn][reg];
        cv[reg] = (f16)(v > 0.f ? v : 0.f);
      }
      half4* pxl = (half4*)(xnh + r * 72 + chq);
      *pxl = *pxl + cv;
    }
  }
  __syncthreads();
  // coalesced copy-out (named scalars; uniform fast path)
  if (n8 == 768) {
    uint4 c0 = xn4[(t >> 3) * 9 + ch];
    uint4 c1 = xn4[((t + 256) >> 3) * 9 + ch];
    uint4 c2 = xn4[((t + 512) >> 3) * 9 + ch];
    xg[t] = c0;
    xg[t + 256] = c1;
    xg[t + 512] = c2;
  } else {
    for (int idx = t; idx < n8; idx += 256)
      xg[idx] = xn4[(idx >> 3) * 9 + ch];
  }
}

// ---------------- p2a apply: CSR gather; vectorized x RMW via LDS transpose --------

struct Apply2Params {
  const f16* xp[3];
  const int* cnt[3];
  const int* basea[3];
  const int* bucket;
  const f16* Wp[3];
  const float* bias[3];
  int nm;
};

__global__ __launch_bounds__(256) void k_apply2(Apply2Params p, f16* x) {
  __shared__ uint4 Af[512];
  __shared__ float bl[64];
  __shared__ f16 xf[64 * 72];   // 64 atoms x 64 cols, padded stride 72 (16B-aligned rows)
  int t = threadIdx.x;
  int a0 = blockIdx.x * 64;
  int lane = t & 63, wid = t >> 6;
  int al = t >> 2, q = t & 3;
  int atom = a0 + al;
  f32x4 addv[4];
#pragma unroll
  for (int nt = 0; nt < 4; nt++) { f32x4 z = {0.f, 0.f, 0.f, 0.f}; addv[nt] = z; }
  for (int mi = 0; mi < p.nm; mi++) {
    __syncthreads();
    if (t < 64) bl[t] = p.bias[mi][t];
    float s[16];
#pragma unroll
    for (int i = 0; i < 16; i++) s[i] = 0.f;
    int cb = 0, base = 0;
    if (atom < NA) { cb = p.cnt[mi][atom]; base = p.basea[mi][atom]; }
    const uint4* xpu = (const uint4*)p.xp[mi];
    int i = 0;
    for (; i + 4 <= cb; i += 4) {
      int e0 = p.bucket[base + i], e1 = p.bucket[base + i + 1];
      int e2 = p.bucket[base + i + 2], e3 = p.bucket[base + i + 3];
      HU va0, vb0, va1, vb1, va2, vb2, va3, vb3;
      va0.u = xpu[(long)e0 * 8 + q * 2]; vb0.u = xpu[(long)e0 * 8 + q * 2 + 1];
      va1.u = xpu[(long)e1 * 8 + q * 2]; vb1.u = xpu[(long)e1 * 8 + q * 2 + 1];
      va2.u = xpu[(long)e2 * 8 + q * 2]; vb2.u = xpu[(long)e2 * 8 + q * 2 + 1];
      va3.u = xpu[(long)e3 * 8 + q * 2]; vb3.u = xpu[(long)e3 * 8 + q * 2 + 1];
#pragma unroll
      for (int j = 0; j < 8; j++) {
        s[j] += ((float)va0.s[j] + (float)va1.s[j]) + ((float)va2.s[j] + (float)va3.s[j]);
        s[8 + j] += ((float)vb0.s[j] + (float)vb1.s[j]) + ((float)vb2.s[j] + (float)vb3.s[j]);
      }
    }
    for (; i < cb; i++) {
      int e = p.bucket[base + i];
      HU v0, v1;
      v0.u = xpu[(long)e * 8 + q * 2];
      v1.u = xpu[(long)e * 8 + q * 2 + 1];
#pragma unroll
      for (int j = 0; j < 8; j++) { s[j] += (float)v0.s[j]; s[8 + j] += (float)v1.s[j]; }
    }
    float inv = 1.f / (float)(cb > 0 ? cb : 1);
    HU o0, o1;
#pragma unroll
    for (int j = 0; j < 8; j++) { o0.s[j] = (f16)(s[j] * inv); o1.s[j] = (f16)(s[8 + j] * inv); }
    int jb = ((al >> 4) * 2 + (q >> 1)) * 64 + (q & 1) * 32 + (al & 15);
    Af[jb] = o0.u;
    Af[jb + 16] = o1.u;
    __syncthreads();
    HU af0, af1;
    af0.u = Af[((wid << 1) + 0) * 64 + lane];
    af1.u = Af[((wid << 1) + 1) * 64 + lane];
    const uint4* Wu = (const uint4*)p.Wp[mi];
#pragma unroll
    for (int nt = 0; nt < 4; nt++) {
      HU b0, b1;
      b0.u = Wu[((nt << 1) + 0) * 64 + lane];
      b1.u = Wu[((nt << 1) + 1) * 64 + lane];
      float bv = bl[nt * 16 + (lane & 15)];
      f32x4 z = {bv, bv, bv, bv};
      z = __builtin_amdgcn_mfma_f32_16x16x32_f16(af0.h, b0.h, z, 0, 0, 0);
      z = __builtin_amdgcn_mfma_f32_16x16x32_f16(af1.h, b1.h, z, 0, 0, 0);
#pragma unroll
      for (int r = 0; r < 4; r++) {
        float vv = z[r];
        addv[nt][r] += vv > 0.f ? vv : 0.f;
      }
    }
  }
  // stash addv to LDS (owner-lane scalar writes, 2-way-free banks), then vector RMW of x
  int arow_w = (wid << 4) + ((lane >> 4) << 2);
#pragma unroll
  for (int nt = 0; nt < 4; nt++) {
    int n = nt * 16 + (lane & 15);
#pragma unroll
    for (int r = 0; r < 4; r++)
      xf[(arow_w + r) * 72 + n] = (f16)addv[nt][r];
  }
  __syncthreads();
#pragma unroll
  for (int u = 0; u < 2; u++) {
    int idx = t + 256 * u;
    int arow = idx >> 3, ch8 = idx & 7;
    int atomw = a0 + arow;
    if (atomw < NA) {
      uint4* px = (uint4*)(x + (long)atomw * 64 + ch8 * 8);
      HU old; old.u = *px;
      HU ad; ad.h = *(half8*)(xf + arow * 72 + ch8 * 8);
      HU o; o.h = old.h + ad.h;   // v_pk_add_f16 x4
      *px = o.u;
    }
  }
}

// ---------------- batch mean over f16 x ----------------

__global__ __launch_bounds__(256) void k_meanscatter(const f16* src, const int* bucket,
                                                     const int* basea, const int* cnta,
                                                     float* dst, int nseg) {
  int wid = (blockIdx.x * 256 + threadIdx.x) >> 6;
  int lane = threadIdx.x & 63;
  if (wid >= nseg) return;
  int b0 = basea[wid], cnt = cnta[wid];
  float s = 0.f;
  for (int i = 0; i < cnt; i++) {
    int e = bucket[b0 + i];
    s += (float)src[(long)e * 64 + lane];
  }
  dst[(long)wid * 64 + lane] = s / (float)(cnt > 0 ? cnt : 1);
}

// ---------------- head gemm ----------------

__global__ __launch_bounds__(256) void k_head(const float* g1, const float* W,
                                              const float* bias, float* g2) {
  __shared__ float Wl[4096];
  __shared__ float inl[32 * 64];
  __shared__ float bl[64];
  int t = threadIdx.x;
  int brow = blockIdx.x * 32;
#pragma unroll
  for (int i = 0; i < 4; i++) ((float4*)Wl)[t + 256 * i] = ((const float4*)W)[t + 256 * i];
  if (t < 64) bl[t] = bias[t];
  __syncthreads();
#pragma unroll
  for (int i = 0; i < 2; i++) {
    int idx = t + 256 * i;
    int r = idx >> 4, q = idx & 15;
    ((float4*)inl)[idx] = ((const float4*)(g1 + (long)(brow + r) * 64))[q];
  }
  __syncthreads();
  int c = t & 63, rq = t >> 6;
  float acc[8];
#pragma unroll
  for (int i = 0; i < 8; i++) acc[i] = 0.f;
  for (int j = 0; j < 64; j += 4) {
    float w0 = Wl[(j + 0) * 64 + c], w1 = Wl[(j + 1) * 64 + c];
    float w2 = Wl[(j + 2) * 64 + c], w3 = Wl[(j + 3) * 64 + c];
#pragma unroll
    for (int i = 0; i < 8; i++) {
      int r = rq * 8 + i;
      float4 v = *(const float4*)&inl[r * 64 + j];
      acc[i] += v.x * w0 + v.y * w1 + v.z * w2 + v.w * w3;
    }
  }
#pragma unroll
  for (int i = 0; i < 8; i++) {
    long r = brow + rq * 8 + i;
    float v = acc[i] + bl[c];
    g2[r * 64 + c] = v > 0.f ? v : 0.f;
  }
}

__global__ __launch_bounds__(256) void k_final(const float* g2, const float* linW,
                                               const float* linb, float* out) {
  int wid = (blockIdx.x * 256 + threadIdx.x) >> 6;
  int lane = threadIdx.x & 63;
  if (wid >= NBATCH) return;
  float v = g2[(long)wid * 64 + lane] * linW[lane];
  for (int o = 32; o > 0; o >>= 1) v += __shfl_down(v, o, 64);
  if (lane == 0) out[wid] = v + linb[0];
}

__global__ __launch_bounds__(256) void k_zero_out(float* out, int n) {
  for (int i = blockIdx.x * 256 + threadIdx.x; i < n; i += gridDim.x * 256) out[i] = 0.f;
}

// ---------------- launcher ----------------

extern "C" void kernel_launch(void* const* d_in, const int* in_sizes, int n_in,
                              void* d_out, int out_size, void* d_ws, size_t ws_size,
                              hipStream_t stream) {
  (void)in_sizes; (void)n_in;

  const int* x_atom = (const int*)d_in[0];
  const int* vals[5] = {(const int*)d_in[1], (const int*)d_in[4], (const int*)d_in[7],
                        (const int*)d_in[10], (const int*)d_in[13]};
  const int* rowm[5] = {(const int*)d_in[2], (const int*)d_in[5], (const int*)d_in[8],
                        (const int*)d_in[11], (const int*)d_in[14]};
  const int* batch = (const int*)d_in[16];
  const float* aemb0 = (const float*)d_in[17];
  const float* aemb1 = (const float*)d_in[18];
  const float* aemb2 = (const float*)d_in[19];
  const float* path_emb = (const float*)d_in[20];
  const float* cycle_emb = (const float*)d_in[21];
  const float* pW_a2p = (const float*)d_in[22];
  const float* pb_a2p = (const float*)d_in[23];
  const float* pW_p2a = (const float*)d_in[24];
  const float* pb_p2a = (const float*)d_in[25];
  const float* pK = (const float*)d_in[26];
  const float* pKb = (const float*)d_in[27];
  const float* cW_a2p = (const float*)d_in[28];
  const float* cb_a2p = (const float*)d_in[29];
  const float* cW_p2a = (const float*)d_in[30];
  const float* cb_p2a = (const float*)d_in[31];
  const float* cK = (const float*)d_in[32];
  const float* cKb = (const float*)d_in[33];
  const float* alW = (const float*)d_in[34];
  const float* alb = (const float*)d_in[35];
  const float* linW = (const float*)d_in[36];
  const float* linb = (const float*)d_in[37];

  static const int Em[5] = {300000, 400000, 500000, 200000, 240000};
  static const int Km[5] = {3, 4, 5, 5, 6};
  static const int Ppb[5] = {32, 24, 16, 16, 16};
  const int CNT_N = 5 * 100000 + NBATCH;  // 504096
  const int BUCKET_N = 3484400;           // gapped (capbase layout)

  char* ws = (char*)d_ws;
  size_t off = 0;
  auto alloc = [&](size_t nbytes) -> char* {
    char* p = ws + off;
    off = (off + nbytes + 255) & ~(size_t)255;
    return p;
  };
  f16* x = (f16*)alloc((size_t)NA * 64 * 2);   // f16 master
  __half* xp[5];
  for (int m = 0; m < 5; m++) xp[m] = (__half*)alloc((size_t)Em[m] * 64 * 2);
  float* g1 = (float*)alloc((size_t)NBATCH * 64 * 4);
  float* g2 = (float*)alloc((size_t)NBATCH * 64 * 4);
  int* cnt = (int*)alloc((size_t)CNT_N * 4);
  int* basea = (int*)alloc((size_t)CNT_N * 4);
  int* bucket = (int*)alloc((size_t)BUCKET_N * 4);
  unsigned* ccursor = (unsigned*)alloc((size_t)NBIN * 4);
  f16* Bp = (f16*)alloc((size_t)10 * 12288 * 2);
  f16* Wpk = (f16*)alloc((size_t)20 * 4096 * 2);
  f16* Tabs = (f16*)alloc((size_t)1664 * 2);
  // pairs array (~14 MB) aliases xp[2]: consumed by k_passB before k_fused writes xp[2].
  unsigned* pairs = (unsigned*)xp[2];

  if (ws_size < off) {
    k_zero_out<<<16, 256, 0, stream>>>((float*)d_out, out_size);
    return;
  }

  // ---- merged prep (atom_init + prepB + prepW + prepT + initc)
  {
    PrepParams q;
    q.xa = x_atom; q.e0 = aemb0; q.e1 = aemb1; q.e2 = aemb2; q.x = x;
    q.pK = pK; q.cK = cK; q.Bp = Bp;
    q.pW = pW_p2a; q.cW = cW_p2a; q.pWa = pW_a2p; q.cWa = cW_a2p; q.Wp = Wpk;
    q.path_emb = path_emb; q.cycle_emb = cycle_emb; q.T = Tabs;
    q.ccursor = ccursor;
    k_prep<<<7058, 256, 0, stream>>>(q);
  }

  // ---- CSR build: two-level counting sort (no scan; gapped bucket)
  PassAParams pp;
  {
    int s = 0;
    for (int m = 0; m < 5; m++) { pp.row[m] = rowm[m]; pp.start[m] = s; s += Em[m]; }
    pp.row[5] = batch; pp.start[5] = s;
    pp.total = s + NA;  // 1740000
  }
  k_passA<<<(1740000 + 8191) / 8192, 256, 0, stream>>>(pp, ccursor, pairs);
  k_passB<<<NBIN, 256, 0, stream>>>(ccursor, pairs, bucket, cnt, basea);

  int apply_blocks = (NA + 63) / 64;  // 1563

  auto p2aW = [&](int l, int m) -> const f16* {
    return (m < 3) ? Wpk + (size_t)(l * 3 + m) * 4096
                   : Wpk + (size_t)(6 + l * 2 + (m - 3)) * 4096;
  };
  auto p2aB = [&](int l, int m) -> const float* {
    return (m < 3) ? pb_p2a + (l * 3 + m) * 64 : cb_p2a + (l * 2 + (m - 3)) * 64;
  };

  for (int l = 0; l < 2; l++) {
    // === paths group (maps 0..2), non-cyclic
    {
      FusedParams fp{};
      fp.nseg = 3; fp.cyclic = 0; fp.xh = x; fp.use_tab = (l == 0) ? 1 : 0;
      int bs = 0;
      for (int m = 0; m < 3; m++) {
        fp.gidx[m] = rowm[m]; fp.xp[m] = xp[m];
        fp.vals[m] = vals[m]; fp.tab[m] = Tabs + (size_t)m * 384;
        fp.Wa[m] = Wpk + (size_t)(10 + l * 3 + m) * 4096;
        fp.ba[m] = pb_a2p + (l * 3 + m) * 64;
        fp.Bp[m] = Bp + (size_t)(l * 3 + m) * 12288;
        fp.Kb[m] = pKb + (l * 3 + m) * 64;
        fp.k[m] = Km[m]; fp.P[m] = Em[m] / Km[m]; fp.ppb[m] = Ppb[m];
        fp.blk_start[m] = bs;
        bs += (fp.P[m] + fp.ppb[m] - 1) / fp.ppb[m];
      }
      k_fused<<<bs, 256, 0, stream>>>(fp);

      Apply2Params ap{};
      ap.nm = 3; ap.bucket = bucket;
      for (int m = 0; m < 3; m++) {
        ap.xp[m] = (const f16*)xp[m];
        ap.cnt[m] = cnt + (size_t)m * 100000;
        ap.basea[m] = basea + (size_t)m * 100000;
        ap.Wp[m] = p2aW(l, m); ap.bias[m] = p2aB(l, m);
      }
      k_apply2<<<apply_blocks, 256, 0, stream>>>(ap, x);
    }
    // === cycles group (maps 3..4), cyclic
    {
      FusedParams fp{};
      fp.nseg = 2; fp.cyclic = 1; fp.xh = x; fp.use_tab = (l == 0) ? 1 : 0;
      int bs = 0;
      for (int m = 3; m < 5; m++) {
        int i = m - 3;
        fp.gidx[i] = rowm[m]; fp.xp[i] = xp[m];
        fp.vals[i] = vals[m]; fp.tab[i] = Tabs + 1152 + (size_t)i * 256;
        fp.Wa[i] = Wpk + (size_t)(16 + l * 2 + i) * 4096;
        fp.ba[i] = cb_a2p + (l * 2 + i) * 64;
        fp.Bp[i] = Bp + (size_t)(6 + l * 2 + i) * 12288;
        fp.Kb[i] = cKb + (l * 2 + i) * 64;
        fp.k[i] = Km[m]; fp.P[i] = Em[m] / Km[m]; fp.ppb[i] = Ppb[m];
        fp.blk_start[i] = bs;
        bs += (fp.P[i] + fp.ppb[i] - 1) / fp.ppb[i];
      }
      k_fused<<<bs, 256, 0, stream>>>(fp);

      Apply2Params ap{};
      ap.nm = 2; ap.bucket = bucket;
      for (int m = 3; m < 5; m++) {
        int i = m - 3;
        ap.xp[i] = (const f16*)xp[m];
        ap.cnt[i] = cnt + (size_t)m * 100000;
        ap.basea[i] = basea + (size_t)m * 100000;
        ap.Wp[i] = p2aW(l, m); ap.bias[i] = p2aB(l, m);
      }
      k_apply2<<<apply_blocks, 256, 0, stream>>>(ap, x);
    }
  }

  // ---- head (basea entries for the batch segment are GLOBAL bucket positions)
  k_meanscatter<<<NBATCH / 4, 256, 0, stream>>>(x, bucket, basea + 500000,
                                                cnt + 500000, g1, NBATCH);
  k_head<<<NBATCH / 32, 256, 0, stream>>>(g1, alW, alb, g2);
  k_final<<<NBATCH / 4, 256, 0, stream>>>(g2, linW, linb, (float*)d_out);
}

// Round 11
// 666.049 us; speedup vs baseline: 1.4141x; 1.0008x over previous
//
#include <hip/hip_runtime.h>
#include <hip/hip_fp16.h>

#define NA 100000
#define NBATCH 4096
#define NBIN 1971       // 5 maps * 391 atom-ranges + 16 batch-ranges
#define MAPS_BINS 1955  // 5 * 391

typedef _Float16 f16;
typedef f16 half8 __attribute__((ext_vector_type(8)));
typedef f16 half4 __attribute__((ext_vector_type(4)));
typedef float f32x4 __attribute__((ext_vector_type(4)));
union HU { uint4 u; half8 h; f16 s[8]; };

// ---------------- two-level counting sort CSR build (gapped bucket, no scan) ----------
__device__ __forceinline__ unsigned capbase_of(int b) {
  if (b < 391)  return 0u       + (unsigned)(b       ) * 1536u;
  if (b < 782)  return 600576u  + (unsigned)(b -  391) * 2048u;
  if (b < 1173) return 1401344u + (unsigned)(b -  782) * 2560u;
  if (b < 1564) return 2402304u + (unsigned)(b - 1173) * 1024u;
  if (b < 1955) return 2802688u + (unsigned)(b - 1564) * 1232u;
  return 3284400u + (unsigned)(b - 1955) * 12500u;
}

struct PassAParams {
  const int* row[6];
  int start[6];
  int total;
};

__global__ __launch_bounds__(256) void k_passA(PassAParams pp, unsigned* ccursor,
                                               unsigned* pairs) {
  __shared__ int hist[NBIN];
  __shared__ unsigned hbase[NBIN];
  int t = threadIdx.x;
  for (int b = t; b < NBIN; b += 256) hist[b] = 0;
  __syncthreads();
  int g0 = blockIdx.x * 8192;
  unsigned keys[32];
#pragma unroll
  for (int i = 0; i < 32; i++) {
    int g = g0 + i * 256 + t;
    keys[i] = 0xFFFFFFFFu;
    if (g < pp.total) {
      int m = 0;
#pragma unroll
      for (int j = 1; j < 6; j++) if (g >= pp.start[j]) m = j;
      int e = g - pp.start[m];
      int a = pp.row[m][e];
      int bin = (m < 5) ? m * 391 + (a >> 8) : MAPS_BINS + (a >> 8);
      keys[i] = ((unsigned)bin << 8) | (unsigned)(a & 255);
      atomicAdd(&hist[bin], 1);
    }
  }
  __syncthreads();
  for (int b = t; b < NBIN; b += 256) {
    int h = hist[b];
    hbase[b] = h ? atomicAdd(&ccursor[b], (unsigned)h) : 0u;
  }
  __syncthreads();
#pragma unroll
  for (int i = 0; i < 32; i++) {
    unsigned kv = keys[i];
    if (kv == 0xFFFFFFFFu) continue;
    int bin = (int)(kv >> 8);
    int g = g0 + i * 256 + t;
    int m = 0;
#pragma unroll
    for (int j = 1; j < 6; j++) if (g >= pp.start[j]) m = j;
    int e = g - pp.start[m];
    unsigned pos = atomicAdd(&hbase[bin], 1u);
    pairs[pos] = ((unsigned)e << 8) | (kv & 255u);
  }
}

__global__ __launch_bounds__(256) void k_passB(const unsigned* ccursor,
                                               const unsigned* pairs, int* bucket,
                                               int* cnt, int* basea) {
  __shared__ int hist[256];
  __shared__ int scn[256];
  __shared__ unsigned cur[256];
  int b = blockIdx.x;
  int t = threadIdx.x;
  unsigned cb0 = capbase_of(b);
  int count = (int)(ccursor[b] - cb0);
  const unsigned* src = pairs + cb0;
  hist[t] = 0;
  __syncthreads();
  for (int i = t; i < count; i += 256) atomicAdd(&hist[src[i] & 255u], 1);
  __syncthreads();
  int h = hist[t];
  scn[t] = h;
  __syncthreads();
  for (int d = 1; d < 256; d <<= 1) {
    int x = (t >= d) ? scn[t - d] : 0;
    __syncthreads();
    scn[t] += x;
    __syncthreads();
  }
  int excl = scn[t] - h;
  unsigned gbase = cb0;   // gapped layout: bucket lives at capbase offsets
  int m, a0, off, amax;
  if (b < MAPS_BINS) { m = b / 391; a0 = (b - m * 391) << 8; off = m * 100000; amax = 100000; }
  else { m = 5; a0 = (b - MAPS_BINS) << 8; off = 500000; amax = NBATCH; }
  if (a0 + t < amax) {
    cnt[off + a0 + t] = h;
    basea[off + a0 + t] = (int)(gbase + (unsigned)excl);
  }
  cur[t] = gbase + (unsigned)excl;
  __syncthreads();
  for (int i = t; i < count; i += 256) {
    unsigned v = src[i];
    unsigned pos = atomicAdd(&cur[v & 255u], 1u);
    bucket[pos] = (int)(v >> 8);
  }
}

// ---------------- merged prep kernel: atom_init + prepB + prepW + prepT + initc --------

struct PrepParams {
  const int* xa; const float *e0; const float *e1; const float *e2; f16* x;
  const float *pK; const float *cK; f16* Bp;
  const float *pW; const float *cW; const float *pWa; const float *cWa; f16* Wp;
  const float *path_emb; const float *cycle_emb; f16* T;
  unsigned* ccursor;
};

__global__ __launch_bounds__(256) void k_prep(PrepParams q) {
  int bid = blockIdx.x, t = threadIdx.x;
  if (bid < 6250) {
    int idx = bid * 256 + t;
    int a = idx >> 4, qq = idx & 15;
    int f0 = q.xa[a * 3], f1 = q.xa[a * 3 + 1], f2 = q.xa[a * 3 + 2];
    float4 v0 = ((const float4*)q.e0)[f0 * 16 + qq];
    float4 v1 = ((const float4*)q.e1)[f1 * 16 + qq];
    float4 v2 = ((const float4*)q.e2)[f2 * 16 + qq];
    half4 h = {(f16)(v0.x + v1.x + v2.x), (f16)(v0.y + v1.y + v2.y),
               (f16)(v0.z + v1.z + v2.z), (f16)(v0.w + v1.w + v2.w)};
    ((half4*)q.x)[idx] = h;
  } else if (bid < 6730) {
    int tid = (bid - 6250) * 256 + t;
    int set = tid / 12288, pos = tid % 12288;
    int j = pos & 7, lane = (pos >> 3) & 63, kcnt = pos >> 9;
    int kc = kcnt % 6, nt = kcnt / 6;
    int k = kc * 32 + ((lane >> 4) << 3) + j;
    int n = (nt << 4) + (lane & 15);
    int w = k >> 6, ji = k & 63;
    const float* K = (set < 6) ? (q.pK + set * 3 * 4096) : (q.cK + (set - 6) * 3 * 4096);
    float v = K[w * 4096 + ji * 64 + n];
    if (set >= 6) v = 0.5f * (v + K[(2 - w) * 4096 + ji * 64 + n]);
    q.Bp[tid] = (f16)v;
  } else if (bid < 7050) {
    int tid = (bid - 6730) * 256 + t;
    int set = tid >> 12, pos = tid & 4095;
    int j = pos & 7, lane = (pos >> 3) & 63, ntkc = pos >> 9;
    int kc = ntkc & 1, nt = ntkc >> 1;
    int k = kc * 32 + ((lane >> 4) << 3) + j;
    int n = (nt << 4) + (lane & 15);
    const float* W;
    if (set < 6) W = q.pW + set * 4096;
    else if (set < 10) W = q.cW + (set - 6) * 4096;
    else if (set < 16) W = q.pWa + (set - 10) * 4096;
    else W = q.cWa + (set - 16) * 4096;
    q.Wp[tid] = (f16)W[k * 64 + n];
  } else {
    int idx = (bid - 7050) * 256 + t;
    if (idx < 1664) {
      float v = (idx < 1152) ? q.path_emb[idx] : q.cycle_emb[idx - 1152];
      q.T[idx] = (f16)v;
    }
    if (idx < NBIN) q.ccursor[idx] = capbase_of(idx);
  }
}

// ---------------- fused a2p+conv (swapped-operand MFMA) ----------------
// R9-measured-best body (40 VGPR, occ ~58-61%): ridx staged in LDS, gather after
// barrier, spill-free 3-wide prefetch/copy-out. R10's early-gather variant held 6
// fragments live across the barrier (48 VGPR, occ 52%, L0 112us) — reverted.

struct FusedParams {
  const f16* xh;
  const int* gidx[3];
  const int* vals[3];
  const f16* tab[3];
  __half* xp[3];
  const f16* Wa[3];
  const float* ba[3];
  const f16* Bp[3];
  const float* Kb[3];
  int k[3];
  int P[3];
  int ppb[3];
  int blk_start[3];
  int nseg;
  int cyclic;
  int use_tab;
};

__global__ __launch_bounds__(256) void k_fused(FusedParams p) {
  __shared__ uint4 xn4[873];     // 97 rows x 9 uint4 (72 f16/row, row 96 = zero pad)
  __shared__ float bl[64], kbl[64];
  __shared__ int ridx[96];
  __shared__ short prevs[96], nexts[96];
  int bid = blockIdx.x;
  int seg = 0;
#pragma unroll
  for (int i = 1; i < 3; i++) if (i < p.nseg && bid >= p.blk_start[i]) seg = i;
  int kk = p.k[seg], ppb = p.ppb[seg], P = p.P[seg];
  int cyc = p.cyclic;
  int t = threadIdx.x;
  int p0 = (bid - p.blk_start[seg]) * ppb;
  int np = min(ppb, P - p0);
  int R = np * kk;    // always a multiple of 16 for these ppb choices
  int mtb = R >> 4;
  long ebase = (long)p0 * kk;
  if (t < 64) { bl[t] = p.ba[seg][t]; kbl[t] = p.Kb[seg][t]; }
  if (t < 9) { uint4 z; z.x = z.y = z.z = z.w = 0; xn4[96 * 9 + t] = z; }
  if (t < R) ridx[t] = p.gidx[seg][ebase + t];
  if (t < 96) {
    int sm = t % kk;
    prevs[t] = (short)((sm >= 1) ? t - 1 : (cyc ? t + kk - 1 : 96));
    nexts[t] = (short)((sm + 1 < kk) ? t + 1 : (cyc ? t + 1 - kk : 96));
  }
  uint4* xg = (uint4*)(p.xp[seg] + (long)ebase * 64);
  int n8 = R * 8;   // 768 for full blocks (only one partial block exists, in map 1)
  int ch = t & 7;
  // residual prefetch into xn4 (named scalars; uniform fast path = no scratch)
  if (p.use_tab) {
    const uint4* tabu = (const uint4*)p.tab[seg];
    const int* vseg = p.vals[seg];
    if (n8 == 768) {
      int v0 = vseg[ebase + (t >> 3)];
      int v1 = vseg[ebase + ((t + 256) >> 3)];
      int v2 = vseg[ebase + ((t + 512) >> 3)];
      uint4 a0 = tabu[v0 * 8 + ch];
      uint4 a1 = tabu[v1 * 8 + ch];
      uint4 a2 = tabu[v2 * 8 + ch];
      xn4[(t >> 3) * 9 + ch] = a0;
      xn4[((t + 256) >> 3) * 9 + ch] = a1;
      xn4[((t + 512) >> 3) * 9 + ch] = a2;
    } else {
      for (int idx = t; idx < n8; idx += 256) {
        int row = idx >> 3;
        xn4[row * 9 + ch] = tabu[vseg[ebase + row] * 8 + ch];
      }
    }
  } else {
    if (n8 == 768) {
      uint4 a0 = xg[t];
      uint4 a1 = xg[t + 256];
      uint4 a2 = xg[t + 512];
      xn4[(t >> 3) * 9 + ch] = a0;
      xn4[((t + 256) >> 3) * 9 + ch] = a1;
      xn4[((t + 512) >> 3) * 9 + ch] = a2;
    } else {
      for (int idx = t; idx < n8; idx += 256)
        xn4[(idx >> 3) * 9 + ch] = xg[idx];
    }
  }
  __syncthreads();
  int lane = t & 63, wid = t >> 6;
  int wave_n = wid & 1, wave_m = wid >> 1;
  int mtA = (mtb + 1) >> 1;
  int m0 = wave_m ? mtA : 0;
  int mcnt = wave_m ? (mtb - mtA) : mtA;
  f16* xnh = (f16*)xn4;
  int chq0 = wave_n * 32 + ((lane >> 4) << 2);   // jn=0 channel quad
  int chq1 = chq0 + 16;                           // jn=1 channel quad
  // stage A: xn += relu(x_gather @ Wa + ba)  (bias via acc init; pk-f16 residual add)
  {
    f32x4 b0 = {bl[chq0], bl[chq0 + 1], bl[chq0 + 2], bl[chq0 + 3]};
    f32x4 b1 = {bl[chq1], bl[chq1 + 1], bl[chq1 + 2], bl[chq1 + 3]};
    f32x4 acc1[3][2];
#pragma unroll
    for (int i = 0; i < 3; i++) { acc1[i][0] = b0; acc1[i][1] = b1; }
    const uint4* Wau = (const uint4*)p.Wa[seg];
    HU w[2][2];
#pragma unroll
    for (int kc = 0; kc < 2; kc++)
#pragma unroll
      for (int jn = 0; jn < 2; jn++)
        w[kc][jn].u = Wau[(((wave_n * 2 + jn) << 1) + kc) * 64 + lane];
    const uint4* xh4 = (const uint4*)p.xh;
#pragma unroll
    for (int i = 0; i < 3; i++) {
      if (i >= mcnt) continue;
      int rowid = ridx[((m0 + i) << 4) + (lane & 15)];
      HU xa, xb;
      xa.u = xh4[(long)rowid * 8 + (lane >> 4)];
      xb.u = xh4[(long)rowid * 8 + 4 + (lane >> 4)];
#pragma unroll
      for (int jn = 0; jn < 2; jn++) {
        acc1[i][jn] = __builtin_amdgcn_mfma_f32_16x16x32_f16(w[0][jn].h, xa.h, acc1[i][jn], 0, 0, 0);
        acc1[i][jn] = __builtin_amdgcn_mfma_f32_16x16x32_f16(w[1][jn].h, xb.h, acc1[i][jn], 0, 0, 0);
      }
    }
#pragma unroll
    for (int i = 0; i < 3; i++) {
      if (i >= mcnt) continue;
      int r = ((m0 + i) << 4) + (lane & 15);
#pragma unroll
      for (int jn = 0; jn < 2; jn++) {
        int chq = jn ? chq1 : chq0;
        half4 cv;
#pragma unroll
        for (int reg = 0; reg < 4; reg++) {
          float v = acc1[i][jn][reg];
          cv[reg] = (f16)(v > 0.f ? v : 0.f);
        }
        half4* pxl = (half4*)(xnh + r * 72 + chq);
        *pxl = *pxl + cv;   // v_pk_add_f16 x2
      }
    }
  }
  __syncthreads();
  // conv MFMAs reading xn4 (neighbor rows via LDS tables); bias via acc init
  f32x4 k0 = {kbl[chq0], kbl[chq0 + 1], kbl[chq0 + 2], kbl[chq0 + 3]};
  f32x4 k1 = {kbl[chq1], kbl[chq1 + 1], kbl[chq1 + 2], kbl[chq1 + 3]};
  f32x4 acc2[3][2];
#pragma unroll
  for (int i = 0; i < 3; i++) { acc2[i][0] = k0; acc2[i][1] = k1; }
  int rdw[3][3];
#pragma unroll
  for (int i = 0; i < 3; i++) {
    if (i >= mcnt) continue;
    int mr = ((m0 + i) << 4) + (lane & 15);
    rdw[i][0] = prevs[mr];
    rdw[i][1] = mr;
    rdw[i][2] = nexts[mr];
  }
  const uint4* Bg = (const uint4*)p.Bp[seg];
  for (int kc = 0; kc < 6; kc++) {
    int w_ = kc >> 1;
    int chunk = ((kc & 1) << 2) + (lane >> 4);
    HU ak[2], xv[3];
#pragma unroll
    for (int jn = 0; jn < 2; jn++)
      ak[jn].u = Bg[((wave_n * 2 + jn) * 6 + kc) * 64 + lane];
#pragma unroll
    for (int i = 0; i < 3; i++)
      if (i < mcnt) xv[i].u = xn4[rdw[i][w_] * 9 + chunk];
#pragma unroll
    for (int i = 0; i < 3; i++)
      if (i < mcnt) {
#pragma unroll
        for (int jn = 0; jn < 2; jn++)
          acc2[i][jn] = __builtin_amdgcn_mfma_f32_16x16x32_f16(ak[jn].h, xv[i].h, acc2[i][jn], 0, 0, 0);
      }
  }
  __syncthreads();  // conv reads of xn4 complete before overwrite
  // epilogue 2: final = xn + relu(conv + Kb), pk-f16 RMW in LDS
#pragma unroll
  for (int i = 0; i < 3; i++) {
    if (i >= mcnt) continue;
    int r = ((m0 + i) << 4) + (lane & 15);
#pragma unroll
    for (int jn = 0; jn < 2; jn++) {
      int chq = jn ? chq1 : chq0;
      half4 cv;
#pragma unroll
      for (int reg = 0; reg < 4; reg++) {
        float v = acc2[i][jn][reg];
        cv[reg] = (f16)(v > 0.f ? v : 0.f);
      }
      half4* pxl = (half4*)(xnh + r * 72 + chq);
      *pxl = *pxl + cv;
    }
  }
  __syncthreads();
  // coalesced copy-out (named scalars; uniform fast path)
  if (n8 == 768) {
    uint4 c0 = xn4[(t >> 3) * 9 + ch];
    uint4 c1 = xn4[((t + 256) >> 3) * 9 + ch];
    uint4 c2 = xn4[((t + 512) >> 3) * 9 + ch];
    xg[t] = c0;
    xg[t + 256] = c1;
    xg[t + 512] = c2;
  } else {
    for (int idx = t; idx < n8; idx += 256)
      xg[idx] = xn4[(idx >> 3) * 9 + ch];
  }
}

// ---------------- p2a apply: CSR gather; vectorized x RMW via LDS transpose --------

struct Apply2Params {
  const f16* xp[3];
  const int* cnt[3];
  const int* basea[3];
  const int* bucket;
  const f16* Wp[3];
  const float* bias[3];
  int nm;
};

__global__ __launch_bounds__(256) void k_apply2(Apply2Params p, f16* x) {
  __shared__ uint4 Af[512];
  __shared__ float bl[64];
  __shared__ f16 xf[64 * 72];   // 64 atoms x 64 cols, padded stride 72 (16B-aligned rows)
  int t = threadIdx.x;
  int a0 = blockIdx.x * 64;
  int lane = t & 63, wid = t >> 6;
  int al = t >> 2, q = t & 3;
  int atom = a0 + al;
  f32x4 addv[4];
#pragma unroll
  for (int nt = 0; nt < 4; nt++) { f32x4 z = {0.f, 0.f, 0.f, 0.f}; addv[nt] = z; }
  for (int mi = 0; mi < p.nm; mi++) {
    __syncthreads();
    if (t < 64) bl[t] = p.bias[mi][t];
    float s[16];
#pragma unroll
    for (int i = 0; i < 16; i++) s[i] = 0.f;
    int cb = 0, base = 0;
    if (atom < NA) { cb = p.cnt[mi][atom]; base = p.basea[mi][atom]; }
    const uint4* xpu = (const uint4*)p.xp[mi];
    int i = 0;
    for (; i + 4 <= cb; i += 4) {
      int e0 = p.bucket[base + i], e1 = p.bucket[base + i + 1];
      int e2 = p.bucket[base + i + 2], e3 = p.bucket[base + i + 3];
      HU va0, vb0, va1, vb1, va2, vb2, va3, vb3;
      va0.u = xpu[(long)e0 * 8 + q * 2]; vb0.u = xpu[(long)e0 * 8 + q * 2 + 1];
      va1.u = xpu[(long)e1 * 8 + q * 2]; vb1.u = xpu[(long)e1 * 8 + q * 2 + 1];
      va2.u = xpu[(long)e2 * 8 + q * 2]; vb2.u = xpu[(long)e2 * 8 + q * 2 + 1];
      va3.u = xpu[(long)e3 * 8 + q * 2]; vb3.u = xpu[(long)e3 * 8 + q * 2 + 1];
#pragma unroll
      for (int j = 0; j < 8; j++) {
        s[j] += ((float)va0.s[j] + (float)va1.s[j]) + ((float)va2.s[j] + (float)va3.s[j]);
        s[8 + j] += ((float)vb0.s[j] + (float)vb1.s[j]) + ((float)vb2.s[j] + (float)vb3.s[j]);
      }
    }
    for (; i < cb; i++) {
      int e = p.bucket[base + i];
      HU v0, v1;
      v0.u = xpu[(long)e * 8 + q * 2];
      v1.u = xpu[(long)e * 8 + q * 2 + 1];
#pragma unroll
      for (int j = 0; j < 8; j++) { s[j] += (float)v0.s[j]; s[8 + j] += (float)v1.s[j]; }
    }
    float inv = 1.f / (float)(cb > 0 ? cb : 1);
    HU o0, o1;
#pragma unroll
    for (int j = 0; j < 8; j++) { o0.s[j] = (f16)(s[j] * inv); o1.s[j] = (f16)(s[8 + j] * inv); }
    int jb = ((al >> 4) * 2 + (q >> 1)) * 64 + (q & 1) * 32 + (al & 15);
    Af[jb] = o0.u;
    Af[jb + 16] = o1.u;
    __syncthreads();
    HU af0, af1;
    af0.u = Af[((wid << 1) + 0) * 64 + lane];
    af1.u = Af[((wid << 1) + 1) * 64 + lane];
    const uint4* Wu = (const uint4*)p.Wp[mi];
#pragma unroll
    for (int nt = 0; nt < 4; nt++) {
      HU b0, b1;
      b0.u = Wu[((nt << 1) + 0) * 64 + lane];
      b1.u = Wu[((nt << 1) + 1) * 64 + lane];
      float bv = bl[nt * 16 + (lane & 15)];
      f32x4 z = {bv, bv, bv, bv};
      z = __builtin_amdgcn_mfma_f32_16x16x32_f16(af0.h, b0.h, z, 0, 0, 0);
      z = __builtin_amdgcn_mfma_f32_16x16x32_f16(af1.h, b1.h, z, 0, 0, 0);
#pragma unroll
      for (int r = 0; r < 4; r++) {
        float vv = z[r];
        addv[nt][r] += vv > 0.f ? vv : 0.f;
      }
    }
  }
  // stash addv to LDS (owner-lane scalar writes), then vector RMW of x
  int arow_w = (wid << 4) + ((lane >> 4) << 2);
#pragma unroll
  for (int nt = 0; nt < 4; nt++) {
    int n = nt * 16 + (lane & 15);
#pragma unroll
    for (int r = 0; r < 4; r++)
      xf[(arow_w + r) * 72 + n] = (f16)addv[nt][r];
  }
  __syncthreads();
#pragma unroll
  for (int u = 0; u < 2; u++) {
    int idx = t + 256 * u;
    int arow = idx >> 3, ch8 = idx & 7;
    int atomw = a0 + arow;
    if (atomw < NA) {
      uint4* px = (uint4*)(x + (long)atomw * 64 + ch8 * 8);
      HU old; old.u = *px;
      HU ad; ad.h = *(half8*)(xf + arow * 72 + ch8 * 8);
      HU o; o.h = old.h + ad.h;   // v_pk_add_f16 x4
      *px = o.u;
    }
  }
}

// ---------------- batch mean over f16 x ----------------

__global__ __launch_bounds__(256) void k_meanscatter(const f16* src, const int* bucket,
                                                     const int* basea, const int* cnta,
                                                     float* dst, int nseg) {
  int wid = (blockIdx.x * 256 + threadIdx.x) >> 6;
  int lane = threadIdx.x & 63;
  if (wid >= nseg) return;
  int b0 = basea[wid], cnt = cnta[wid];
  float s = 0.f;
  for (int i = 0; i < cnt; i++) {
    int e = bucket[b0 + i];
    s += (float)src[(long)e * 64 + lane];
  }
  dst[(long)wid * 64 + lane] = s / (float)(cnt > 0 ? cnt : 1);
}

// ---------------- head gemm ----------------

__global__ __launch_bounds__(256) void k_head(const float* g1, const float* W,
                                              const float* bias, float* g2) {
  __shared__ float Wl[4096];
  __shared__ float inl[32 * 64];
  __shared__ float bl[64];
  int t = threadIdx.x;
  int brow = blockIdx.x * 32;
#pragma unroll
  for (int i = 0; i < 4; i++) ((float4*)Wl)[t + 256 * i] = ((const float4*)W)[t + 256 * i];
  if (t < 64) bl[t] = bias[t];
  __syncthreads();
#pragma unroll
  for (int i = 0; i < 2; i++) {
    int idx = t + 256 * i;
    int r = idx >> 4, q = idx & 15;
    ((float4*)inl)[idx] = ((const float4*)(g1 + (long)(brow + r) * 64))[q];
  }
  __syncthreads();
  int c = t & 63, rq = t >> 6;
  float acc[8];
#pragma unroll
  for (int i = 0; i < 8; i++) acc[i] = 0.f;
  for (int j = 0; j < 64; j += 4) {
    float w0 = Wl[(j + 0) * 64 + c], w1 = Wl[(j + 1) * 64 + c];
    float w2 = Wl[(j + 2) * 64 + c], w3 = Wl[(j + 3) * 64 + c];
#pragma unroll
    for (int i = 0; i < 8; i++) {
      int r = rq * 8 + i;
      float4 v = *(const float4*)&inl[r * 64 + j];
      acc[i] += v.x * w0 + v.y * w1 + v.z * w2 + v.w * w3;
    }
  }
#pragma unroll
  for (int i = 0; i < 8; i++) {
    long r = brow + rq * 8 + i;
    float v = acc[i] + bl[c];
    g2[r * 64 + c] = v > 0.f ? v : 0.f;
  }
}

__global__ __launch_bounds__(256) void k_final(const float* g2, const float* linW,
                                               const float* linb, float* out) {
  int wid = (blockIdx.x * 256 + threadIdx.x) >> 6;
  int lane = threadIdx.x & 63;
  if (wid >= NBATCH) return;
  float v = g2[(long)wid * 64 + lane] * linW[lane];
  for (int o = 32; o > 0; o >>= 1) v += __shfl_down(v, o, 64);
  if (lane == 0) out[wid] = v + linb[0];
}

__global__ __launch_bounds__(256) void k_zero_out(float* out, int n) {
  for (int i = blockIdx.x * 256 + threadIdx.x; i < n; i += gridDim.x * 256) out[i] = 0.f;
}

// ---------------- launcher ----------------

extern "C" void kernel_launch(void* const* d_in, const int* in_sizes, int n_in,
                              void* d_out, int out_size, void* d_ws, size_t ws_size,
                              hipStream_t stream) {
  (void)in_sizes; (void)n_in;

  const int* x_atom = (const int*)d_in[0];
  const int* vals[5] = {(const int*)d_in[1], (const int*)d_in[4], (const int*)d_in[7],
                        (const int*)d_in[10], (const int*)d_in[13]};
  const int* rowm[5] = {(const int*)d_in[2], (const int*)d_in[5], (const int*)d_in[8],
                        (const int*)d_in[11], (const int*)d_in[14]};
  const int* batch = (const int*)d_in[16];
  const float* aemb0 = (const float*)d_in[17];
  const float* aemb1 = (const float*)d_in[18];
  const float* aemb2 = (const float*)d_in[19];
  const float* path_emb = (const float*)d_in[20];
  const float* cycle_emb = (const float*)d_in[21];
  const float* pW_a2p = (const float*)d_in[22];
  const float* pb_a2p = (const float*)d_in[23];
  const float* pW_p2a = (const float*)d_in[24];
  const float* pb_p2a = (const float*)d_in[25];
  const float* pK = (const float*)d_in[26];
  const float* pKb = (const float*)d_in[27];
  const float* cW_a2p = (const float*)d_in[28];
  const float* cb_a2p = (const float*)d_in[29];
  const float* cW_p2a = (const float*)d_in[30];
  const float* cb_p2a = (const float*)d_in[31];
  const float* cK = (const float*)d_in[32];
  const float* cKb = (const float*)d_in[33];
  const float* alW = (const float*)d_in[34];
  const float* alb = (const float*)d_in[35];
  const float* linW = (const float*)d_in[36];
  const float* linb = (const float*)d_in[37];

  static const int Em[5] = {300000, 400000, 500000, 200000, 240000};
  static const int Km[5] = {3, 4, 5, 5, 6};
  static const int Ppb[5] = {32, 24, 16, 16, 16};
  const int CNT_N = 5 * 100000 + NBATCH;  // 504096
  const int BUCKET_N = 3484400;           // gapped (capbase layout)

  char* ws = (char*)d_ws;
  size_t off = 0;
  auto alloc = [&](size_t nbytes) -> char* {
    char* p = ws + off;
    off = (off + nbytes + 255) & ~(size_t)255;
    return p;
  };
  f16* x = (f16*)alloc((size_t)NA * 64 * 2);   // f16 master
  __half* xp[5];
  for (int m = 0; m < 5; m++) xp[m] = (__half*)alloc((size_t)Em[m] * 64 * 2);
  float* g1 = (float*)alloc((size_t)NBATCH * 64 * 4);
  float* g2 = (float*)alloc((size_t)NBATCH * 64 * 4);
  int* cnt = (int*)alloc((size_t)CNT_N * 4);
  int* basea = (int*)alloc((size_t)CNT_N * 4);
  int* bucket = (int*)alloc((size_t)BUCKET_N * 4);
  unsigned* ccursor = (unsigned*)alloc((size_t)NBIN * 4);
  f16* Bp = (f16*)alloc((size_t)10 * 12288 * 2);
  f16* Wpk = (f16*)alloc((size_t)20 * 4096 * 2);
  f16* Tabs = (f16*)alloc((size_t)1664 * 2);
  // pairs array (~14 MB) aliases xp[2]: consumed by k_passB before k_fused writes xp[2].
  unsigned* pairs = (unsigned*)xp[2];

  if (ws_size < off) {
    k_zero_out<<<16, 256, 0, stream>>>((float*)d_out, out_size);
    return;
  }

  // ---- merged prep (atom_init + prepB + prepW + prepT + initc)
  {
    PrepParams q;
    q.xa = x_atom; q.e0 = aemb0; q.e1 = aemb1; q.e2 = aemb2; q.x = x;
    q.pK = pK; q.cK = cK; q.Bp = Bp;
    q.pW = pW_p2a; q.cW = cW_p2a; q.pWa = pW_a2p; q.cWa = cW_a2p; q.Wp = Wpk;
    q.path_emb = path_emb; q.cycle_emb = cycle_emb; q.T = Tabs;
    q.ccursor = ccursor;
    k_prep<<<7058, 256, 0, stream>>>(q);
  }

  // ---- CSR build: two-level counting sort (no scan; gapped bucket)
  PassAParams pp;
  {
    int s = 0;
    for (int m = 0; m < 5; m++) { pp.row[m] = rowm[m]; pp.start[m] = s; s += Em[m]; }
    pp.row[5] = batch; pp.start[5] = s;
    pp.total = s + NA;  // 1740000
  }
  k_passA<<<(1740000 + 8191) / 8192, 256, 0, stream>>>(pp, ccursor, pairs);
  k_passB<<<NBIN, 256, 0, stream>>>(ccursor, pairs, bucket, cnt, basea);

  int apply_blocks = (NA + 63) / 64;  // 1563

  auto p2aW = [&](int l, int m) -> const f16* {
    return (m < 3) ? Wpk + (size_t)(l * 3 + m) * 4096
                   : Wpk + (size_t)(6 + l * 2 + (m - 3)) * 4096;
  };
  auto p2aB = [&](int l, int m) -> const float* {
    return (m < 3) ? pb_p2a + (l * 3 + m) * 64 : cb_p2a + (l * 2 + (m - 3)) * 64;
  };

  for (int l = 0; l < 2; l++) {
    // === paths group (maps 0..2), non-cyclic
    {
      FusedParams fp{};
      fp.nseg = 3; fp.cyclic = 0; fp.xh = x; fp.use_tab = (l == 0) ? 1 : 0;
      int bs = 0;
      for (int m = 0; m < 3; m++) {
        fp.gidx[m] = rowm[m]; fp.xp[m] = xp[m];
        fp.vals[m] = vals[m]; fp.tab[m] = Tabs + (size_t)m * 384;
        fp.Wa[m] = Wpk + (size_t)(10 + l * 3 + m) * 4096;
        fp.ba[m] = pb_a2p + (l * 3 + m) * 64;
        fp.Bp[m] = Bp + (size_t)(l * 3 + m) * 12288;
        fp.Kb[m] = pKb + (l * 3 + m) * 64;
        fp.k[m] = Km[m]; fp.P[m] = Em[m] / Km[m]; fp.ppb[m] = Ppb[m];
        fp.blk_start[m] = bs;
        bs += (fp.P[m] + fp.ppb[m] - 1) / fp.ppb[m];
      }
      k_fused<<<bs, 256, 0, stream>>>(fp);

      Apply2Params ap{};
      ap.nm = 3; ap.bucket = bucket;
      for (int m = 0; m < 3; m++) {
        ap.xp[m] = (const f16*)xp[m];
        ap.cnt[m] = cnt + (size_t)m * 100000;
        ap.basea[m] = basea + (size_t)m * 100000;
        ap.Wp[m] = p2aW(l, m); ap.bias[m] = p2aB(l, m);
      }
      k_apply2<<<apply_blocks, 256, 0, stream>>>(ap, x);
    }
    // === cycles group (maps 3..4), cyclic
    {
      FusedParams fp{};
      fp.nseg = 2; fp.cyclic = 1; fp.xh = x; fp.use_tab = (l == 0) ? 1 : 0;
      int bs = 0;
      for (int m = 3; m < 5; m++) {
        int i = m - 3;
        fp.gidx[i] = rowm[m]; fp.xp[i] = xp[m];
        fp.vals[i] = vals[m]; fp.tab[i] = Tabs + 1152 + (size_t)i * 256;
        fp.Wa[i] = Wpk + (size_t)(16 + l * 2 + i) * 4096;
        fp.ba[i] = cb_a2p + (l * 2 + i) * 64;
        fp.Bp[i] = Bp + (size_t)(6 + l * 2 + i) * 12288;
        fp.Kb[i] = cKb + (l * 2 + i) * 64;
        fp.k[i] = Km[m]; fp.P[i] = Em[m] / Km[m]; fp.ppb[i] = Ppb[m];
        fp.blk_start[i] = bs;
        bs += (fp.P[i] + fp.ppb[i] - 1) / fp.ppb[i];
      }
      k_fused<<<bs, 256, 0, stream>>>(fp);

      Apply2Params ap{};
      ap.nm = 2; ap.bucket = bucket;
      for (int m = 3; m < 5; m++) {
        int i = m - 3;
        ap.xp[i] = (const f16*)xp[m];
        ap.cnt[i] = cnt + (size_t)m * 100000;
        ap.basea[i] = basea + (size_t)m * 100000;
        ap.Wp[i] = p2aW(l, m); ap.bias[i] = p2aB(l, m);
      }
      k_apply2<<<apply_blocks, 256, 0, stream>>>(ap, x);
    }
  }

  // ---- head (basea entries for the batch segment are GLOBAL bucket positions)
  k_meanscatter<<<NBATCH / 4, 256, 0, stream>>>(x, bucket, basea + 500000,
                                                cnt + 500000, g1, NBATCH);
  k_head<<<NBATCH / 32, 256, 0, stream>>>(g1, alW, alb, g2);
  k_final<<<NBATCH / 4, 256, 0, stream>>>(g2, linW, linb, (float*)d_out);
}

// Round 12
// 642.797 us; speedup vs baseline: 1.4652x; 1.0362x over previous
//
#include <hip/hip_runtime.h>
#include <hip/hip_fp16.h>

#define NA 100000
#define NBATCH 4096
#define NBIN 1971       // 5 maps * 391 atom-ranges + 16 batch-ranges
#define MAPS_BINS 1955  // 5 * 391

typedef _Float16 f16;
typedef f16 half8 __attribute__((ext_vector_type(8)));
typedef f16 half4 __attribute__((ext_vector_type(4)));
typedef float f32x4 __attribute__((ext_vector_type(4)));
union HU { uint4 u; half8 h; f16 s[8]; };

// ---------------- two-level counting sort CSR build (gapped bucket, no scan) ----------
// caps sized for TRUE counts + per-atom pad-to-4 (sentinel edges for k_apply2):
// m0=1792 m1=2304 m2=2816 m3=1536 m4=1536 batch=12500
__device__ __forceinline__ unsigned capbase_of(int b) {
  if (b < 391)  return 0u       + (unsigned)(b       ) * 1792u;
  if (b < 782)  return 700672u  + (unsigned)(b -  391) * 2304u;
  if (b < 1173) return 1601536u + (unsigned)(b -  782) * 2816u;
  if (b < 1564) return 2702592u + (unsigned)(b - 1173) * 1536u;
  if (b < 1955) return 3303168u + (unsigned)(b - 1564) * 1536u;
  return 3903744u + (unsigned)(b - 1955) * 12500u;
}
// total bucket/pairs slots = 4103744 (~16.4 MB)

struct PassAParams {
  const int* row[6];
  int start[6];
  int total;
};

__global__ __launch_bounds__(256) void k_passA(PassAParams pp, unsigned* ccursor,
                                               unsigned* pairs) {
  __shared__ int hist[NBIN];
  __shared__ unsigned hbase[NBIN];
  int t = threadIdx.x;
  for (int b = t; b < NBIN; b += 256) hist[b] = 0;
  __syncthreads();
  int g0 = blockIdx.x * 8192;
  unsigned keys[32];
#pragma unroll
  for (int i = 0; i < 32; i++) {
    int g = g0 + i * 256 + t;
    keys[i] = 0xFFFFFFFFu;
    if (g < pp.total) {
      int m = 0;
#pragma unroll
      for (int j = 1; j < 6; j++) if (g >= pp.start[j]) m = j;
      int e = g - pp.start[m];
      int a = pp.row[m][e];
      int bin = (m < 5) ? m * 391 + (a >> 8) : MAPS_BINS + (a >> 8);
      keys[i] = ((unsigned)bin << 8) | (unsigned)(a & 255);
      atomicAdd(&hist[bin], 1);
    }
  }
  __syncthreads();
  for (int b = t; b < NBIN; b += 256) {
    int h = hist[b];
    hbase[b] = h ? atomicAdd(&ccursor[b], (unsigned)h) : 0u;
  }
  __syncthreads();
#pragma unroll
  for (int i = 0; i < 32; i++) {
    unsigned kv = keys[i];
    if (kv == 0xFFFFFFFFu) continue;
    int bin = (int)(kv >> 8);
    int g = g0 + i * 256 + t;
    int m = 0;
#pragma unroll
    for (int j = 1; j < 6; j++) if (g >= pp.start[j]) m = j;
    int e = g - pp.start[m];
    unsigned pos = atomicAdd(&hbase[bin], 1u);
    pairs[pos] = ((unsigned)e << 8) | (kv & 255u);
  }
}

__global__ __launch_bounds__(256) void k_passB(const unsigned* ccursor,
                                               const unsigned* pairs, int* bucket,
                                               int* cnt, int* basea) {
  __shared__ int hist[256];
  __shared__ int scn[256];
  __shared__ unsigned cur[256];
  int b = blockIdx.x;
  int t = threadIdx.x;
  unsigned cb0 = capbase_of(b);
  int count = (int)(ccursor[b] - cb0);
  const unsigned* src = pairs + cb0;
  hist[t] = 0;
  __syncthreads();
  for (int i = t; i < count; i += 256) atomicAdd(&hist[src[i] & 255u], 1);
  __syncthreads();
  int h = hist[t];
  bool isMap = (b < MAPS_BINS);
  int hp = isMap ? ((h + 3) & ~3) : h;   // pad map lists to multiple of 4
  scn[t] = hp;
  __syncthreads();
  for (int d = 1; d < 256; d <<= 1) {
    int x = (t >= d) ? scn[t - d] : 0;
    __syncthreads();
    scn[t] += x;
    __syncthreads();
  }
  int excl = scn[t] - hp;
  unsigned base = cb0 + (unsigned)excl;
  int m, a0, off, amax;
  if (isMap) { m = b / 391; a0 = (b - m * 391) << 8; off = m * 100000; amax = 100000; }
  else { m = 5; a0 = (b - MAPS_BINS) << 8; off = 500000; amax = NBATCH; }
  if (a0 + t < amax) {
    cnt[off + a0 + t] = h;               // TRUE count (mean divisor)
    basea[off + a0 + t] = (int)base;     // padded-prefix base
  }
  cur[t] = base;
  __syncthreads();
  for (int i = t; i < count; i += 256) {
    unsigned v = src[i];
    unsigned pos = atomicAdd(&cur[v & 255u], 1u);
    bucket[pos] = (int)(v >> 8);
  }
  // sentinel pads (disjoint slots; sentinel row E_m is zeroed in k_prep)
  if (isMap && h > 0) {
    static const int EmS[5] = {300000, 400000, 500000, 200000, 240000};
    int sent = EmS[m];
    for (int j = h; j < hp; j++) bucket[base + j] = sent;
  }
}

// ---------------- merged prep kernel: atom_init + prepB + prepW + prepT + initc --------

struct PrepParams {
  const int* xa; const float *e0; const float *e1; const float *e2; f16* x;
  const float *pK; const float *cK; f16* Bp;
  const float *pW; const float *cW; const float *pWa; const float *cWa; f16* Wp;
  const float *path_emb; const float *cycle_emb; f16* T;
  unsigned* ccursor;
  f16* xpz[5];
};

__global__ __launch_bounds__(256) void k_prep(PrepParams q) {
  int bid = blockIdx.x, t = threadIdx.x;
  if (bid < 6250) {
    int idx = bid * 256 + t;
    int a = idx >> 4, qq = idx & 15;
    int f0 = q.xa[a * 3], f1 = q.xa[a * 3 + 1], f2 = q.xa[a * 3 + 2];
    float4 v0 = ((const float4*)q.e0)[f0 * 16 + qq];
    float4 v1 = ((const float4*)q.e1)[f1 * 16 + qq];
    float4 v2 = ((const float4*)q.e2)[f2 * 16 + qq];
    half4 h = {(f16)(v0.x + v1.x + v2.x), (f16)(v0.y + v1.y + v2.y),
               (f16)(v0.z + v1.z + v2.z), (f16)(v0.w + v1.w + v2.w)};
    ((half4*)q.x)[idx] = h;
  } else if (bid < 6730) {
    int tid = (bid - 6250) * 256 + t;
    int set = tid / 12288, pos = tid % 12288;
    int j = pos & 7, lane = (pos >> 3) & 63, kcnt = pos >> 9;
    int kc = kcnt % 6, nt = kcnt / 6;
    int k = kc * 32 + ((lane >> 4) << 3) + j;
    int n = (nt << 4) + (lane & 15);
    int w = k >> 6, ji = k & 63;
    const float* K = (set < 6) ? (q.pK + set * 3 * 4096) : (q.cK + (set - 6) * 3 * 4096);
    float v = K[w * 4096 + ji * 64 + n];
    if (set >= 6) v = 0.5f * (v + K[(2 - w) * 4096 + ji * 64 + n]);
    q.Bp[tid] = (f16)v;
  } else if (bid < 7050) {
    int tid = (bid - 6730) * 256 + t;
    int set = tid >> 12, pos = tid & 4095;
    int j = pos & 7, lane = (pos >> 3) & 63, ntkc = pos >> 9;
    int kc = ntkc & 1, nt = ntkc >> 1;
    int k = kc * 32 + ((lane >> 4) << 3) + j;
    int n = (nt << 4) + (lane & 15);
    const float* W;
    if (set < 6) W = q.pW + set * 4096;
    else if (set < 10) W = q.cW + (set - 6) * 4096;
    else if (set < 16) W = q.pWa + (set - 10) * 4096;
    else W = q.cWa + (set - 16) * 4096;
    q.Wp[tid] = (f16)W[k * 64 + n];
  } else {
    int idx = (bid - 7050) * 256 + t;
    if (idx < 1664) {
      float v = (idx < 1152) ? q.path_emb[idx] : q.cycle_emb[idx - 1152];
      q.T[idx] = (f16)v;
    }
    if (idx < NBIN) q.ccursor[idx] = capbase_of(idx);
    if (idx >= 2048 && idx < 2088) {
      static const int EmS[5] = {300000, 400000, 500000, 200000, 240000};
      int s = idx - 2048, m = s >> 3, c = s & 7;
      uint4 z; z.x = z.y = z.z = z.w = 0;
      ((uint4*)(q.xpz[m] + (size_t)EmS[m] * 64))[c] = z;  // zero sentinel row
    }
  }
}

// ---------------- fused a2p+conv (swapped-operand MFMA) ----------------
// R9/R11-measured body (40 VGPR): ridx staged in LDS, gather after barrier,
// spill-free 3-wide prefetch/copy-out, bias via acc init, pk-f16 epilogue RMW.

struct FusedParams {
  const f16* xh;
  const int* gidx[3];
  const int* vals[3];
  const f16* tab[3];
  __half* xp[3];
  const f16* Wa[3];
  const float* ba[3];
  const f16* Bp[3];
  const float* Kb[3];
  int k[3];
  int P[3];
  int ppb[3];
  int blk_start[3];
  int nseg;
  int cyclic;
  int use_tab;
};

__global__ __launch_bounds__(256) void k_fused(FusedParams p) {
  __shared__ uint4 xn4[873];     // 97 rows x 9 uint4 (72 f16/row, row 96 = zero pad)
  __shared__ float bl[64], kbl[64];
  __shared__ int ridx[96];
  __shared__ short prevs[96], nexts[96];
  int bid = blockIdx.x;
  int seg = 0;
#pragma unroll
  for (int i = 1; i < 3; i++) if (i < p.nseg && bid >= p.blk_start[i]) seg = i;
  int kk = p.k[seg], ppb = p.ppb[seg], P = p.P[seg];
  int cyc = p.cyclic;
  int t = threadIdx.x;
  int p0 = (bid - p.blk_start[seg]) * ppb;
  int np = min(ppb, P - p0);
  int R = np * kk;    // always a multiple of 16 for these ppb choices
  int mtb = R >> 4;
  long ebase = (long)p0 * kk;
  if (t < 64) { bl[t] = p.ba[seg][t]; kbl[t] = p.Kb[seg][t]; }
  if (t < 9) { uint4 z; z.x = z.y = z.z = z.w = 0; xn4[96 * 9 + t] = z; }
  if (t < R) ridx[t] = p.gidx[seg][ebase + t];
  if (t < 96) {
    int sm = t % kk;
    prevs[t] = (short)((sm >= 1) ? t - 1 : (cyc ? t + kk - 1 : 96));
    nexts[t] = (short)((sm + 1 < kk) ? t + 1 : (cyc ? t + 1 - kk : 96));
  }
  uint4* xg = (uint4*)(p.xp[seg] + (long)ebase * 64);
  int n8 = R * 8;   // 768 for full blocks (only one partial block exists, in map 1)
  int ch = t & 7;
  if (p.use_tab) {
    const uint4* tabu = (const uint4*)p.tab[seg];
    const int* vseg = p.vals[seg];
    if (n8 == 768) {
      int v0 = vseg[ebase + (t >> 3)];
      int v1 = vseg[ebase + ((t + 256) >> 3)];
      int v2 = vseg[ebase + ((t + 512) >> 3)];
      uint4 a0 = tabu[v0 * 8 + ch];
      uint4 a1 = tabu[v1 * 8 + ch];
      uint4 a2 = tabu[v2 * 8 + ch];
      xn4[(t >> 3) * 9 + ch] = a0;
      xn4[((t + 256) >> 3) * 9 + ch] = a1;
      xn4[((t + 512) >> 3) * 9 + ch] = a2;
    } else {
      for (int idx = t; idx < n8; idx += 256) {
        int row = idx >> 3;
        xn4[row * 9 + ch] = tabu[vseg[ebase + row] * 8 + ch];
      }
    }
  } else {
    if (n8 == 768) {
      uint4 a0 = xg[t];
      uint4 a1 = xg[t + 256];
      uint4 a2 = xg[t + 512];
      xn4[(t >> 3) * 9 + ch] = a0;
      xn4[((t + 256) >> 3) * 9 + ch] = a1;
      xn4[((t + 512) >> 3) * 9 + ch] = a2;
    } else {
      for (int idx = t; idx < n8; idx += 256)
        xn4[(idx >> 3) * 9 + ch] = xg[idx];
    }
  }
  __syncthreads();
  int lane = t & 63, wid = t >> 6;
  int wave_n = wid & 1, wave_m = wid >> 1;
  int mtA = (mtb + 1) >> 1;
  int m0 = wave_m ? mtA : 0;
  int mcnt = wave_m ? (mtb - mtA) : mtA;
  f16* xnh = (f16*)xn4;
  int chq0 = wave_n * 32 + ((lane >> 4) << 2);   // jn=0 channel quad
  int chq1 = chq0 + 16;                           // jn=1 channel quad
  // stage A: xn += relu(x_gather @ Wa + ba)  (bias via acc init; pk-f16 residual add)
  {
    f32x4 b0 = {bl[chq0], bl[chq0 + 1], bl[chq0 + 2], bl[chq0 + 3]};
    f32x4 b1 = {bl[chq1], bl[chq1 + 1], bl[chq1 + 2], bl[chq1 + 3]};
    f32x4 acc1[3][2];
#pragma unroll
    for (int i = 0; i < 3; i++) { acc1[i][0] = b0; acc1[i][1] = b1; }
    const uint4* Wau = (const uint4*)p.Wa[seg];
    HU w[2][2];
#pragma unroll
    for (int kc = 0; kc < 2; kc++)
#pragma unroll
      for (int jn = 0; jn < 2; jn++)
        w[kc][jn].u = Wau[(((wave_n * 2 + jn) << 1) + kc) * 64 + lane];
    const uint4* xh4 = (const uint4*)p.xh;
#pragma unroll
    for (int i = 0; i < 3; i++) {
      if (i >= mcnt) continue;
      int rowid = ridx[((m0 + i) << 4) + (lane & 15)];
      HU xa, xb;
      xa.u = xh4[(long)rowid * 8 + (lane >> 4)];
      xb.u = xh4[(long)rowid * 8 + 4 + (lane >> 4)];
#pragma unroll
      for (int jn = 0; jn < 2; jn++) {
        acc1[i][jn] = __builtin_amdgcn_mfma_f32_16x16x32_f16(w[0][jn].h, xa.h, acc1[i][jn], 0, 0, 0);
        acc1[i][jn] = __builtin_amdgcn_mfma_f32_16x16x32_f16(w[1][jn].h, xb.h, acc1[i][jn], 0, 0, 0);
      }
    }
#pragma unroll
    for (int i = 0; i < 3; i++) {
      if (i >= mcnt) continue;
      int r = ((m0 + i) << 4) + (lane & 15);
#pragma unroll
      for (int jn = 0; jn < 2; jn++) {
        int chq = jn ? chq1 : chq0;
        half4 cv;
#pragma unroll
        for (int reg = 0; reg < 4; reg++) {
          float v = acc1[i][jn][reg];
          cv[reg] = (f16)(v > 0.f ? v : 0.f);
        }
        half4* pxl = (half4*)(xnh + r * 72 + chq);
        *pxl = *pxl + cv;   // v_pk_add_f16 x2
      }
    }
  }
  __syncthreads();
  // conv MFMAs reading xn4 (neighbor rows via LDS tables); bias via acc init
  f32x4 k0 = {kbl[chq0], kbl[chq0 + 1], kbl[chq0 + 2], kbl[chq0 + 3]};
  f32x4 k1 = {kbl[chq1], kbl[chq1 + 1], kbl[chq1 + 2], kbl[chq1 + 3]};
  f32x4 acc2[3][2];
#pragma unroll
  for (int i = 0; i < 3; i++) { acc2[i][0] = k0; acc2[i][1] = k1; }
  int rdw[3][3];
#pragma unroll
  for (int i = 0; i < 3; i++) {
    if (i >= mcnt) continue;
    int mr = ((m0 + i) << 4) + (lane & 15);
    rdw[i][0] = prevs[mr];
    rdw[i][1] = mr;
    rdw[i][2] = nexts[mr];
  }
  const uint4* Bg = (const uint4*)p.Bp[seg];
  for (int kc = 0; kc < 6; kc++) {
    int w_ = kc >> 1;
    int chunk = ((kc & 1) << 2) + (lane >> 4);
    HU ak[2], xv[3];
#pragma unroll
    for (int jn = 0; jn < 2; jn++)
      ak[jn].u = Bg[((wave_n * 2 + jn) * 6 + kc) * 64 + lane];
#pragma unroll
    for (int i = 0; i < 3; i++)
      if (i < mcnt) xv[i].u = xn4[rdw[i][w_] * 9 + chunk];
#pragma unroll
    for (int i = 0; i < 3; i++)
      if (i < mcnt) {
#pragma unroll
        for (int jn = 0; jn < 2; jn++)
          acc2[i][jn] = __builtin_amdgcn_mfma_f32_16x16x32_f16(ak[jn].h, xv[i].h, acc2[i][jn], 0, 0, 0);
      }
  }
  __syncthreads();  // conv reads of xn4 complete before overwrite
  // epilogue 2: final = xn + relu(conv + Kb), pk-f16 RMW in LDS
#pragma unroll
  for (int i = 0; i < 3; i++) {
    if (i >= mcnt) continue;
    int r = ((m0 + i) << 4) + (lane & 15);
#pragma unroll
    for (int jn = 0; jn < 2; jn++) {
      int chq = jn ? chq1 : chq0;
      half4 cv;
#pragma unroll
      for (int reg = 0; reg < 4; reg++) {
        float v = acc2[i][jn][reg];
        cv[reg] = (f16)(v > 0.f ? v : 0.f);
      }
      half4* pxl = (half4*)(xnh + r * 72 + chq);
      *pxl = *pxl + cv;
    }
  }
  __syncthreads();
  // coalesced copy-out (named scalars; uniform fast path)
  if (n8 == 768) {
    uint4 c0 = xn4[(t >> 3) * 9 + ch];
    uint4 c1 = xn4[((t + 256) >> 3) * 9 + ch];
    uint4 c2 = xn4[((t + 512) >> 3) * 9 + ch];
    xg[t] = c0;
    xg[t + 256] = c1;
    xg[t + 512] = c2;
  } else {
    for (int idx = t; idx < n8; idx += 256)
      xg[idx] = xn4[(idx >> 3) * 9 + ch];
  }
}

// ---------------- p2a apply: CSR gather (padded-to-4 lists, no tail) --------

struct Apply2Params {
  const f16* xp[3];
  const int* cnt[3];
  const int* basea[3];
  const int* bucket;
  const f16* Wp[3];
  const float* bias[3];
  int nm;
};

__global__ __launch_bounds__(256) void k_apply2(Apply2Params p, f16* x) {
  __shared__ uint4 Af[512];
  __shared__ float bl[64];
  __shared__ f16 xf[64 * 72];   // 64 atoms x 64 cols, padded stride 72
  int t = threadIdx.x;
  int a0 = blockIdx.x * 64;
  int lane = t & 63, wid = t >> 6;
  int al = t >> 2, q = t & 3;
  int atom = a0 + al;
  f32x4 addv[4];
#pragma unroll
  for (int nt = 0; nt < 4; nt++) { f32x4 z = {0.f, 0.f, 0.f, 0.f}; addv[nt] = z; }
  for (int mi = 0; mi < p.nm; mi++) {
    __syncthreads();
    if (t < 64) bl[t] = p.bias[mi][t];
    float s[16];
#pragma unroll
    for (int i = 0; i < 16; i++) s[i] = 0.f;
    int cb = 0, base = 0;
    if (atom < NA) { cb = p.cnt[mi][atom]; base = p.basea[mi][atom]; }
    const uint4* xpu = (const uint4*)p.xp[mi];
    // lists are padded to a multiple of 4 with sentinel edges (zero rows):
    // uniform quad loop, 12 independent loads per iteration, no scalar tail.
    for (int i = 0; i < cb; i += 4) {
      int e0 = p.bucket[base + i],     e1 = p.bucket[base + i + 1];
      int e2 = p.bucket[base + i + 2], e3 = p.bucket[base + i + 3];
      HU va0, vb0, va1, vb1, va2, vb2, va3, vb3;
      va0.u = xpu[(long)e0 * 8 + q * 2]; vb0.u = xpu[(long)e0 * 8 + q * 2 + 1];
      va1.u = xpu[(long)e1 * 8 + q * 2]; vb1.u = xpu[(long)e1 * 8 + q * 2 + 1];
      va2.u = xpu[(long)e2 * 8 + q * 2]; vb2.u = xpu[(long)e2 * 8 + q * 2 + 1];
      va3.u = xpu[(long)e3 * 8 + q * 2]; vb3.u = xpu[(long)e3 * 8 + q * 2 + 1];
#pragma unroll
      for (int j = 0; j < 8; j++) {
        s[j] += ((float)va0.s[j] + (float)va1.s[j]) + ((float)va2.s[j] + (float)va3.s[j]);
        s[8 + j] += ((float)vb0.s[j] + (float)vb1.s[j]) + ((float)vb2.s[j] + (float)vb3.s[j]);
      }
    }
    float inv = 1.f / (float)(cb > 0 ? cb : 1);
    HU o0, o1;
#pragma unroll
    for (int j = 0; j < 8; j++) { o0.s[j] = (f16)(s[j] * inv); o1.s[j] = (f16)(s[8 + j] * inv); }
    int jb = ((al >> 4) * 2 + (q >> 1)) * 64 + (q & 1) * 32 + (al & 15);
    Af[jb] = o0.u;
    Af[jb + 16] = o1.u;
    __syncthreads();
    HU af0, af1;
    af0.u = Af[((wid << 1) + 0) * 64 + lane];
    af1.u = Af[((wid << 1) + 1) * 64 + lane];
    const uint4* Wu = (const uint4*)p.Wp[mi];
#pragma unroll
    for (int nt = 0; nt < 4; nt++) {
      HU b0, b1;
      b0.u = Wu[((nt << 1) + 0) * 64 + lane];
      b1.u = Wu[((nt << 1) + 1) * 64 + lane];
      float bv = bl[nt * 16 + (lane & 15)];
      f32x4 z = {bv, bv, bv, bv};
      z = __builtin_amdgcn_mfma_f32_16x16x32_f16(af0.h, b0.h, z, 0, 0, 0);
      z = __builtin_amdgcn_mfma_f32_16x16x32_f16(af1.h, b1.h, z, 0, 0, 0);
#pragma unroll
      for (int r = 0; r < 4; r++) {
        float vv = z[r];
        addv[nt][r] += vv > 0.f ? vv : 0.f;
      }
    }
  }
  // stash addv to LDS (owner-lane scalar writes), then vector RMW of x
  int arow_w = (wid << 4) + ((lane >> 4) << 2);
#pragma unroll
  for (int nt = 0; nt < 4; nt++) {
    int n = nt * 16 + (lane & 15);
#pragma unroll
    for (int r = 0; r < 4; r++)
      xf[(arow_w + r) * 72 + n] = (f16)addv[nt][r];
  }
  __syncthreads();
#pragma unroll
  for (int u = 0; u < 2; u++) {
    int idx = t + 256 * u;
    int arow = idx >> 3, ch8 = idx & 7;
    int atomw = a0 + arow;
    if (atomw < NA) {
      uint4* px = (uint4*)(x + (long)atomw * 64 + ch8 * 8);
      HU old; old.u = *px;
      HU ad; ad.h = *(half8*)(xf + arow * 72 + ch8 * 8);
      HU o; o.h = old.h + ad.h;   // v_pk_add_f16 x4
      *px = o.u;
    }
  }
}

// ---------------- batch mean over f16 x ----------------

__global__ __launch_bounds__(256) void k_meanscatter(const f16* src, const int* bucket,
                                                     const int* basea, const int* cnta,
                                                     float* dst, int nseg) {
  int wid = (blockIdx.x * 256 + threadIdx.x) >> 6;
  int lane = threadIdx.x & 63;
  if (wid >= nseg) return;
  int b0 = basea[wid], cnt = cnta[wid];
  float s = 0.f;
  for (int i = 0; i < cnt; i++) {
    int e = bucket[b0 + i];
    s += (float)src[(long)e * 64 + lane];
  }
  dst[(long)wid * 64 + lane] = s / (float)(cnt > 0 ? cnt : 1);
}

// ---------------- head gemm ----------------

__global__ __launch_bounds__(256) void k_head(const float* g1, const float* W,
                                              const float* bias, float* g2) {
  __shared__ float Wl[4096];
  __shared__ float inl[32 * 64];
  __shared__ float bl[64];
  int t = threadIdx.x;
  int brow = blockIdx.x * 32;
#pragma unroll
  for (int i = 0; i < 4; i++) ((float4*)Wl)[t + 256 * i] = ((const float4*)W)[t + 256 * i];
  if (t < 64) bl[t] = bias[t];
  __syncthreads();
#pragma unroll
  for (int i = 0; i < 2; i++) {
    int idx = t + 256 * i;
    int r = idx >> 4, q = idx & 15;
    ((float4*)inl)[idx] = ((const float4*)(g1 + (long)(brow + r) * 64))[q];
  }
  __syncthreads();
  int c = t & 63, rq = t >> 6;
  float acc[8];
#pragma unroll
  for (int i = 0; i < 8; i++) acc[i] = 0.f;
  for (int j = 0; j < 64; j += 4) {
    float w0 = Wl[(j + 0) * 64 + c], w1 = Wl[(j + 1) * 64 + c];
    float w2 = Wl[(j + 2) * 64 + c], w3 = Wl[(j + 3) * 64 + c];
#pragma unroll
    for (int i = 0; i < 8; i++) {
      int r = rq * 8 + i;
      float4 v = *(const float4*)&inl[r * 64 + j];
      acc[i] += v.x * w0 + v.y * w1 + v.z * w2 + v.w * w3;
    }
  }
#pragma unroll
  for (int i = 0; i < 8; i++) {
    long r = brow + rq * 8 + i;
    float v = acc[i] + bl[c];
    g2[r * 64 + c] = v > 0.f ? v : 0.f;
  }
}

__global__ __launch_bounds__(256) void k_final(const float* g2, const float* linW,
                                               const float* linb, float* out) {
  int wid = (blockIdx.x * 256 + threadIdx.x) >> 6;
  int lane = threadIdx.x & 63;
  if (wid >= NBATCH) return;
  float v = g2[(long)wid * 64 + lane] * linW[lane];
  for (int o = 32; o > 0; o >>= 1) v += __shfl_down(v, o, 64);
  if (lane == 0) out[wid] = v + linb[0];
}

__global__ __launch_bounds__(256) void k_zero_out(float* out, int n) {
  for (int i = blockIdx.x * 256 + threadIdx.x; i < n; i += gridDim.x * 256) out[i] = 0.f;
}

// ---------------- launcher ----------------

extern "C" void kernel_launch(void* const* d_in, const int* in_sizes, int n_in,
                              void* d_out, int out_size, void* d_ws, size_t ws_size,
                              hipStream_t stream) {
  (void)in_sizes; (void)n_in;

  const int* x_atom = (const int*)d_in[0];
  const int* vals[5] = {(const int*)d_in[1], (const int*)d_in[4], (const int*)d_in[7],
                        (const int*)d_in[10], (const int*)d_in[13]};
  const int* rowm[5] = {(const int*)d_in[2], (const int*)d_in[5], (const int*)d_in[8],
                        (const int*)d_in[11], (const int*)d_in[14]};
  const int* batch = (const int*)d_in[16];
  const float* aemb0 = (const float*)d_in[17];
  const float* aemb1 = (const float*)d_in[18];
  const float* aemb2 = (const float*)d_in[19];
  const float* path_emb = (const float*)d_in[20];
  const float* cycle_emb = (const float*)d_in[21];
  const float* pW_a2p = (const float*)d_in[22];
  const float* pb_a2p = (const float*)d_in[23];
  const float* pW_p2a = (const float*)d_in[24];
  const float* pb_p2a = (const float*)d_in[25];
  const float* pK = (const float*)d_in[26];
  const float* pKb = (const float*)d_in[27];
  const float* cW_a2p = (const float*)d_in[28];
  const float* cb_a2p = (const float*)d_in[29];
  const float* cW_p2a = (const float*)d_in[30];
  const float* cb_p2a = (const float*)d_in[31];
  const float* cK = (const float*)d_in[32];
  const float* cKb = (const float*)d_in[33];
  const float* alW = (const float*)d_in[34];
  const float* alb = (const float*)d_in[35];
  const float* linW = (const float*)d_in[36];
  const float* linb = (const float*)d_in[37];

  static const int Em[5] = {300000, 400000, 500000, 200000, 240000};
  static const int Km[5] = {3, 4, 5, 5, 6};
  static const int Ppb[5] = {32, 24, 16, 16, 16};
  const int CNT_N = 5 * 100000 + NBATCH;  // 504096
  const int BUCKET_N = 4103744;           // gapped + pad slack (capbase layout)

  char* ws = (char*)d_ws;
  size_t off = 0;
  auto alloc = [&](size_t nbytes) -> char* {
    char* p = ws + off;
    off = (off + nbytes + 255) & ~(size_t)255;
    return p;
  };
  f16* x = (f16*)alloc((size_t)NA * 64 * 2);   // f16 master
  __half* xp[5];
  for (int m = 0; m < 5; m++) xp[m] = (__half*)alloc(((size_t)Em[m] + 8) * 64 * 2);
  float* g1 = (float*)alloc((size_t)NBATCH * 64 * 4);
  float* g2 = (float*)alloc((size_t)NBATCH * 64 * 4);
  int* cnt = (int*)alloc((size_t)CNT_N * 4);
  int* basea = (int*)alloc((size_t)CNT_N * 4);
  int* bucket = (int*)alloc((size_t)BUCKET_N * 4);
  unsigned* ccursor = (unsigned*)alloc((size_t)NBIN * 4);
  f16* Bp = (f16*)alloc((size_t)10 * 12288 * 2);
  f16* Wpk = (f16*)alloc((size_t)20 * 4096 * 2);
  f16* Tabs = (f16*)alloc((size_t)1664 * 2);
  // pairs array (~16.4 MB) aliases xp[2]: consumed by k_passB before k_fused writes
  // xp[2]; sentinel row at xp[2]+64MB is beyond the pairs region.
  unsigned* pairs = (unsigned*)xp[2];

  if (ws_size < off) {
    k_zero_out<<<16, 256, 0, stream>>>((float*)d_out, out_size);
    return;
  }

  // ---- merged prep (atom_init + prepB + prepW + prepT + initc + sentinel zeroing)
  {
    PrepParams q;
    q.xa = x_atom; q.e0 = aemb0; q.e1 = aemb1; q.e2 = aemb2; q.x = x;
    q.pK = pK; q.cK = cK; q.Bp = Bp;
    q.pW = pW_p2a; q.cW = cW_p2a; q.pWa = pW_a2p; q.cWa = cW_a2p; q.Wp = Wpk;
    q.path_emb = path_emb; q.cycle_emb = cycle_emb; q.T = Tabs;
    q.ccursor = ccursor;
    for (int m = 0; m < 5; m++) q.xpz[m] = (f16*)xp[m];
    k_prep<<<7059, 256, 0, stream>>>(q);
  }

  // ---- CSR build: two-level counting sort (no scan; gapped + padded bucket)
  PassAParams pp;
  {
    int s = 0;
    for (int m = 0; m < 5; m++) { pp.row[m] = rowm[m]; pp.start[m] = s; s += Em[m]; }
    pp.row[5] = batch; pp.start[5] = s;
    pp.total = s + NA;  // 1740000
  }
  k_passA<<<(1740000 + 8191) / 8192, 256, 0, stream>>>(pp, ccursor, pairs);
  k_passB<<<NBIN, 256, 0, stream>>>(ccursor, pairs, bucket, cnt, basea);

  int apply_blocks = (NA + 63) / 64;  // 1563

  auto p2aW = [&](int l, int m) -> const f16* {
    return (m < 3) ? Wpk + (size_t)(l * 3 + m) * 4096
                   : Wpk + (size_t)(6 + l * 2 + (m - 3)) * 4096;
  };
  auto p2aB = [&](int l, int m) -> const float* {
    return (m < 3) ? pb_p2a + (l * 3 + m) * 64 : cb_p2a + (l * 2 + (m - 3)) * 64;
  };

  for (int l = 0; l < 2; l++) {
    // === paths group (maps 0..2), non-cyclic
    {
      FusedParams fp{};
      fp.nseg = 3; fp.cyclic = 0; fp.xh = x; fp.use_tab = (l == 0) ? 1 : 0;
      int bs = 0;
      for (int m = 0; m < 3; m++) {
        fp.gidx[m] = rowm[m]; fp.xp[m] = xp[m];
        fp.vals[m] = vals[m]; fp.tab[m] = Tabs + (size_t)m * 384;
        fp.Wa[m] = Wpk + (size_t)(10 + l * 3 + m) * 4096;
        fp.ba[m] = pb_a2p + (l * 3 + m) * 64;
        fp.Bp[m] = Bp + (size_t)(l * 3 + m) * 12288;
        fp.Kb[m] = pKb + (l * 3 + m) * 64;
        fp.k[m] = Km[m]; fp.P[m] = Em[m] / Km[m]; fp.ppb[m] = Ppb[m];
        fp.blk_start[m] = bs;
        bs += (fp.P[m] + fp.ppb[m] - 1) / fp.ppb[m];
      }
      k_fused<<<bs, 256, 0, stream>>>(fp);

      Apply2Params ap{};
      ap.nm = 3; ap.bucket = bucket;
      for (int m = 0; m < 3; m++) {
        ap.xp[m] = (const f16*)xp[m];
        ap.cnt[m] = cnt + (size_t)m * 100000;
        ap.basea[m] = basea + (size_t)m * 100000;
        ap.Wp[m] = p2aW(l, m); ap.bias[m] = p2aB(l, m);
      }
      k_apply2<<<apply_blocks, 256, 0, stream>>>(ap, x);
    }
    // === cycles group (maps 3..4), cyclic
    {
      FusedParams fp{};
      fp.nseg = 2; fp.cyclic = 1; fp.xh = x; fp.use_tab = (l == 0) ? 1 : 0;
      int bs = 0;
      for (int m = 3; m < 5; m++) {
        int i = m - 3;
        fp.gidx[i] = rowm[m]; fp.xp[i] = xp[m];
        fp.vals[i] = vals[m]; fp.tab[i] = Tabs + 1152 + (size_t)i * 256;
        fp.Wa[i] = Wpk + (size_t)(16 + l * 2 + i) * 4096;
        fp.ba[i] = cb_a2p + (l * 2 + i) * 64;
        fp.Bp[i] = Bp + (size_t)(6 + l * 2 + i) * 12288;
        fp.Kb[i] = cKb + (l * 2 + i) * 64;
        fp.k[i] = Km[m]; fp.P[i] = Em[m] / Km[m]; fp.ppb[i] = Ppb[m];
        fp.blk_start[i] = bs;
        bs += (fp.P[i] + fp.ppb[i] - 1) / fp.ppb[i];
      }
      k_fused<<<bs, 256, 0, stream>>>(fp);

      Apply2Params ap{};
      ap.nm = 2; ap.bucket = bucket;
      for (int m = 3; m < 5; m++) {
        int i = m - 3;
        ap.xp[i] = (const f16*)xp[m];
        ap.cnt[i] = cnt + (size_t)m * 100000;
        ap.basea[i] = basea + (size_t)m * 100000;
        ap.Wp[i] = p2aW(l, m); ap.bias[i] = p2aB(l, m);
      }
      k_apply2<<<apply_blocks, 256, 0, stream>>>(ap, x);
    }
  }

  // ---- head (basea entries for the batch segment are GLOBAL bucket positions)
  k_meanscatter<<<NBATCH / 4, 256, 0, stream>>>(x, bucket, basea + 500000,
                                                cnt + 500000, g1, NBATCH);
  k_head<<<NBATCH / 32, 256, 0, stream>>>(g1, alW, alb, g2);
  k_final<<<NBATCH / 4, 256, 0, stream>>>(g2, linW, linb, (float*)d_out);
}

// Round 13
// 642.531 us; speedup vs baseline: 1.4658x; 1.0004x over previous
//
#include <hip/hip_runtime.h>
#include <hip/hip_fp16.h>

#define NA 100000
#define NBATCH 4096
#define NBIN 1971       // 5 maps * 391 atom-ranges + 16 batch-ranges
#define MAPS_BINS 1955  // 5 * 391

typedef _Float16 f16;
typedef f16 half8 __attribute__((ext_vector_type(8)));
typedef f16 half4 __attribute__((ext_vector_type(4)));
typedef float f32x4 __attribute__((ext_vector_type(4)));
union HU { uint4 u; half8 h; f16 s[8]; };

// ---------------- two-level counting sort CSR build (gapped bucket, no scan) ----------
// caps sized for TRUE counts + per-atom pad-to-4 (sentinel edges for k_apply2):
// m0=1792 m1=2304 m2=2816 m3=1536 m4=1536 batch=12500
__device__ __forceinline__ unsigned capbase_of(int b) {
  if (b < 391)  return 0u       + (unsigned)(b       ) * 1792u;
  if (b < 782)  return 700672u  + (unsigned)(b -  391) * 2304u;
  if (b < 1173) return 1601536u + (unsigned)(b -  782) * 2816u;
  if (b < 1564) return 2702592u + (unsigned)(b - 1173) * 1536u;
  if (b < 1955) return 3303168u + (unsigned)(b - 1564) * 1536u;
  return 3903744u + (unsigned)(b - 1955) * 12500u;
}
// total bucket/pairs slots = 4103744 (~16.4 MB)

struct PassAParams {
  const int* row[6];
  int start[6];
  int total;
};

__global__ __launch_bounds__(256) void k_passA(PassAParams pp, unsigned* ccursor,
                                               unsigned* pairs) {
  __shared__ int hist[NBIN];
  __shared__ unsigned hbase[NBIN];
  int t = threadIdx.x;
  for (int b = t; b < NBIN; b += 256) hist[b] = 0;
  __syncthreads();
  int g0 = blockIdx.x * 8192;
  unsigned keys[32];
#pragma unroll
  for (int i = 0; i < 32; i++) {
    int g = g0 + i * 256 + t;
    keys[i] = 0xFFFFFFFFu;
    if (g < pp.total) {
      int m = 0;
#pragma unroll
      for (int j = 1; j < 6; j++) if (g >= pp.start[j]) m = j;
      int e = g - pp.start[m];
      int a = pp.row[m][e];
      int bin = (m < 5) ? m * 391 + (a >> 8) : MAPS_BINS + (a >> 8);
      keys[i] = ((unsigned)bin << 8) | (unsigned)(a & 255);
      atomicAdd(&hist[bin], 1);
    }
  }
  __syncthreads();
  for (int b = t; b < NBIN; b += 256) {
    int h = hist[b];
    hbase[b] = h ? atomicAdd(&ccursor[b], (unsigned)h) : 0u;
  }
  __syncthreads();
#pragma unroll
  for (int i = 0; i < 32; i++) {
    unsigned kv = keys[i];
    if (kv == 0xFFFFFFFFu) continue;
    int bin = (int)(kv >> 8);
    int g = g0 + i * 256 + t;
    int m = 0;
#pragma unroll
    for (int j = 1; j < 6; j++) if (g >= pp.start[j]) m = j;
    int e = g - pp.start[m];
    unsigned pos = atomicAdd(&hbase[bin], 1u);
    pairs[pos] = ((unsigned)e << 8) | (kv & 255u);
  }
}

__global__ __launch_bounds__(256) void k_passB(const unsigned* ccursor,
                                               const unsigned* pairs, int* bucket,
                                               int* cnt, int* basea) {
  __shared__ int hist[256];
  __shared__ int scn[256];
  __shared__ unsigned cur[256];
  int b = blockIdx.x;
  int t = threadIdx.x;
  unsigned cb0 = capbase_of(b);
  int count = (int)(ccursor[b] - cb0);
  const unsigned* src = pairs + cb0;
  hist[t] = 0;
  __syncthreads();
  for (int i = t; i < count; i += 256) atomicAdd(&hist[src[i] & 255u], 1);
  __syncthreads();
  int h = hist[t];
  bool isMap = (b < MAPS_BINS);
  int hp = isMap ? ((h + 3) & ~3) : h;   // pad map lists to multiple of 4
  scn[t] = hp;
  __syncthreads();
  for (int d = 1; d < 256; d <<= 1) {
    int x = (t >= d) ? scn[t - d] : 0;
    __syncthreads();
    scn[t] += x;
    __syncthreads();
  }
  int excl = scn[t] - hp;
  unsigned base = cb0 + (unsigned)excl;
  int m, a0, off, amax;
  if (isMap) { m = b / 391; a0 = (b - m * 391) << 8; off = m * 100000; amax = 100000; }
  else { m = 5; a0 = (b - MAPS_BINS) << 8; off = 500000; amax = NBATCH; }
  if (a0 + t < amax) {
    cnt[off + a0 + t] = h;               // TRUE count (mean divisor)
    basea[off + a0 + t] = (int)base;     // padded-prefix base
  }
  cur[t] = base;
  __syncthreads();
  for (int i = t; i < count; i += 256) {
    unsigned v = src[i];
    unsigned pos = atomicAdd(&cur[v & 255u], 1u);
    bucket[pos] = (int)(v >> 8);
  }
  // sentinel pads (disjoint slots; sentinel row E_m is zeroed in k_prep)
  if (isMap && h > 0) {
    static const int EmS[5] = {300000, 400000, 500000, 200000, 240000};
    int sent = EmS[m];
    for (int j = h; j < hp; j++) bucket[base + j] = sent;
  }
}

// ---------------- merged prep kernel: atom_init + prepB + prepW + prepT + initc --------

struct PrepParams {
  const int* xa; const float *e0; const float *e1; const float *e2; f16* x;
  const float *pK; const float *cK; f16* Bp;
  const float *pW; const float *cW; const float *pWa; const float *cWa; f16* Wp;
  const float *path_emb; const float *cycle_emb; f16* T;
  unsigned* ccursor;
  f16* xpz[5];
};

__global__ __launch_bounds__(256) void k_prep(PrepParams q) {
  int bid = blockIdx.x, t = threadIdx.x;
  if (bid < 6250) {
    int idx = bid * 256 + t;
    int a = idx >> 4, qq = idx & 15;
    int f0 = q.xa[a * 3], f1 = q.xa[a * 3 + 1], f2 = q.xa[a * 3 + 2];
    float4 v0 = ((const float4*)q.e0)[f0 * 16 + qq];
    float4 v1 = ((const float4*)q.e1)[f1 * 16 + qq];
    float4 v2 = ((const float4*)q.e2)[f2 * 16 + qq];
    half4 h = {(f16)(v0.x + v1.x + v2.x), (f16)(v0.y + v1.y + v2.y),
               (f16)(v0.z + v1.z + v2.z), (f16)(v0.w + v1.w + v2.w)};
    ((half4*)q.x)[idx] = h;
  } else if (bid < 6730) {
    int tid = (bid - 6250) * 256 + t;
    int set = tid / 12288, pos = tid % 12288;
    int j = pos & 7, lane = (pos >> 3) & 63, kcnt = pos >> 9;
    int kc = kcnt % 6, nt = kcnt / 6;
    int k = kc * 32 + ((lane >> 4) << 3) + j;
    int n = (nt << 4) + (lane & 15);
    int w = k >> 6, ji = k & 63;
    const float* K = (set < 6) ? (q.pK + set * 3 * 4096) : (q.cK + (set - 6) * 3 * 4096);
    float v = K[w * 4096 + ji * 64 + n];
    if (set >= 6) v = 0.5f * (v + K[(2 - w) * 4096 + ji * 64 + n]);
    q.Bp[tid] = (f16)v;
  } else if (bid < 7050) {
    int tid = (bid - 6730) * 256 + t;
    int set = tid >> 12, pos = tid & 4095;
    int j = pos & 7, lane = (pos >> 3) & 63, ntkc = pos >> 9;
    int kc = ntkc & 1, nt = ntkc >> 1;
    int k = kc * 32 + ((lane >> 4) << 3) + j;
    int n = (nt << 4) + (lane & 15);
    const float* W;
    if (set < 6) W = q.pW + set * 4096;
    else if (set < 10) W = q.cW + (set - 6) * 4096;
    else if (set < 16) W = q.pWa + (set - 10) * 4096;
    else W = q.cWa + (set - 16) * 4096;
    q.Wp[tid] = (f16)W[k * 64 + n];
  } else {
    int idx = (bid - 7050) * 256 + t;
    if (idx < 1664) {
      float v = (idx < 1152) ? q.path_emb[idx] : q.cycle_emb[idx - 1152];
      q.T[idx] = (f16)v;
    }
    if (idx < NBIN) q.ccursor[idx] = capbase_of(idx);
    if (idx >= 2048 && idx < 2088) {
      static const int EmS[5] = {300000, 400000, 500000, 200000, 240000};
      int s = idx - 2048, m = s >> 3, c = s & 7;
      uint4 z; z.x = z.y = z.z = z.w = 0;
      ((uint4*)(q.xpz[m] + (size_t)EmS[m] * 64))[c] = z;  // zero sentinel row
    }
  }
}

// ---------------- fused a2p+conv (swapped-operand MFMA) ----------------
// R11/R12 body + n8==640 uniform fast path (maps with kk=5 have R=80 tiles — 46% of
// paths blocks, 50% of cycles blocks — previously fell to the 3x-serialized rolled loop).

struct FusedParams {
  const f16* xh;
  const int* gidx[3];
  const int* vals[3];
  const f16* tab[3];
  __half* xp[3];
  const f16* Wa[3];
  const float* ba[3];
  const f16* Bp[3];
  const float* Kb[3];
  int k[3];
  int P[3];
  int ppb[3];
  int blk_start[3];
  int nseg;
  int cyclic;
  int use_tab;
};

__global__ __launch_bounds__(256) void k_fused(FusedParams p) {
  __shared__ uint4 xn4[873];     // 97 rows x 9 uint4 (72 f16/row, row 96 = zero pad)
  __shared__ float bl[64], kbl[64];
  __shared__ int ridx[96];
  __shared__ short prevs[96], nexts[96];
  int bid = blockIdx.x;
  int seg = 0;
#pragma unroll
  for (int i = 1; i < 3; i++) if (i < p.nseg && bid >= p.blk_start[i]) seg = i;
  int kk = p.k[seg], ppb = p.ppb[seg], P = p.P[seg];
  int cyc = p.cyclic;
  int t = threadIdx.x;
  int p0 = (bid - p.blk_start[seg]) * ppb;
  int np = min(ppb, P - p0);
  int R = np * kk;    // always a multiple of 16 for these ppb choices
  int mtb = R >> 4;
  long ebase = (long)p0 * kk;
  if (t < 64) { bl[t] = p.ba[seg][t]; kbl[t] = p.Kb[seg][t]; }
  if (t < 9) { uint4 z; z.x = z.y = z.z = z.w = 0; xn4[96 * 9 + t] = z; }
  if (t < R) ridx[t] = p.gidx[seg][ebase + t];
  if (t < 96) {
    int sm = t % kk;
    prevs[t] = (short)((sm >= 1) ? t - 1 : (cyc ? t + kk - 1 : 96));
    nexts[t] = (short)((sm + 1 < kk) ? t + 1 : (cyc ? t + 1 - kk : 96));
  }
  uint4* xg = (uint4*)(p.xp[seg] + (long)ebase * 64);
  int n8 = R * 8;   // 768 (R=96) or 640 (R=80) for full blocks
  int ch = t & 7;
  // residual prefetch into xn4 (named scalars; uniform fast paths = no scratch)
  if (p.use_tab) {
    const uint4* tabu = (const uint4*)p.tab[seg];
    const int* vseg = p.vals[seg];
    if (n8 == 768) {
      int v0 = vseg[ebase + (t >> 3)];
      int v1 = vseg[ebase + ((t + 256) >> 3)];
      int v2 = vseg[ebase + ((t + 512) >> 3)];
      uint4 a0 = tabu[v0 * 8 + ch];
      uint4 a1 = tabu[v1 * 8 + ch];
      uint4 a2 = tabu[v2 * 8 + ch];
      xn4[(t >> 3) * 9 + ch] = a0;
      xn4[((t + 256) >> 3) * 9 + ch] = a1;
      xn4[((t + 512) >> 3) * 9 + ch] = a2;
    } else if (n8 == 640) {
      int v0 = vseg[ebase + (t >> 3)];
      int v1 = vseg[ebase + ((t + 256) >> 3)];
      uint4 a0 = tabu[v0 * 8 + ch];
      uint4 a1 = tabu[v1 * 8 + ch];
      xn4[(t >> 3) * 9 + ch] = a0;
      xn4[((t + 256) >> 3) * 9 + ch] = a1;
      if (t < 128) {
        int v2 = vseg[ebase + ((t + 512) >> 3)];
        uint4 a2 = tabu[v2 * 8 + ch];
        xn4[((t + 512) >> 3) * 9 + ch] = a2;
      }
    } else {
      for (int idx = t; idx < n8; idx += 256) {
        int row = idx >> 3;
        xn4[row * 9 + ch] = tabu[vseg[ebase + row] * 8 + ch];
      }
    }
  } else {
    if (n8 == 768) {
      uint4 a0 = xg[t];
      uint4 a1 = xg[t + 256];
      uint4 a2 = xg[t + 512];
      xn4[(t >> 3) * 9 + ch] = a0;
      xn4[((t + 256) >> 3) * 9 + ch] = a1;
      xn4[((t + 512) >> 3) * 9 + ch] = a2;
    } else if (n8 == 640) {
      uint4 a0 = xg[t];
      uint4 a1 = xg[t + 256];
      xn4[(t >> 3) * 9 + ch] = a0;
      xn4[((t + 256) >> 3) * 9 + ch] = a1;
      if (t < 128) {
        uint4 a2 = xg[t + 512];
        xn4[((t + 512) >> 3) * 9 + ch] = a2;
      }
    } else {
      for (int idx = t; idx < n8; idx += 256)
        xn4[(idx >> 3) * 9 + ch] = xg[idx];
    }
  }
  __syncthreads();
  int lane = t & 63, wid = t >> 6;
  int wave_n = wid & 1, wave_m = wid >> 1;
  int mtA = (mtb + 1) >> 1;
  int m0 = wave_m ? mtA : 0;
  int mcnt = wave_m ? (mtb - mtA) : mtA;
  f16* xnh = (f16*)xn4;
  int chq0 = wave_n * 32 + ((lane >> 4) << 2);   // jn=0 channel quad
  int chq1 = chq0 + 16;                           // jn=1 channel quad
  // stage A: xn += relu(x_gather @ Wa + ba)  (bias via acc init; pk-f16 residual add)
  {
    f32x4 b0 = {bl[chq0], bl[chq0 + 1], bl[chq0 + 2], bl[chq0 + 3]};
    f32x4 b1 = {bl[chq1], bl[chq1 + 1], bl[chq1 + 2], bl[chq1 + 3]};
    f32x4 acc1[3][2];
#pragma unroll
    for (int i = 0; i < 3; i++) { acc1[i][0] = b0; acc1[i][1] = b1; }
    const uint4* Wau = (const uint4*)p.Wa[seg];
    HU w[2][2];
#pragma unroll
    for (int kc = 0; kc < 2; kc++)
#pragma unroll
      for (int jn = 0; jn < 2; jn++)
        w[kc][jn].u = Wau[(((wave_n * 2 + jn) << 1) + kc) * 64 + lane];
    const uint4* xh4 = (const uint4*)p.xh;
#pragma unroll
    for (int i = 0; i < 3; i++) {
      if (i >= mcnt) continue;
      int rowid = ridx[((m0 + i) << 4) + (lane & 15)];
      HU xa, xb;
      xa.u = xh4[(long)rowid * 8 + (lane >> 4)];
      xb.u = xh4[(long)rowid * 8 + 4 + (lane >> 4)];
#pragma unroll
      for (int jn = 0; jn < 2; jn++) {
        acc1[i][jn] = __builtin_amdgcn_mfma_f32_16x16x32_f16(w[0][jn].h, xa.h, acc1[i][jn], 0, 0, 0);
        acc1[i][jn] = __builtin_amdgcn_mfma_f32_16x16x32_f16(w[1][jn].h, xb.h, acc1[i][jn], 0, 0, 0);
      }
    }
#pragma unroll
    for (int i = 0; i < 3; i++) {
      if (i >= mcnt) continue;
      int r = ((m0 + i) << 4) + (lane & 15);
#pragma unroll
      for (int jn = 0; jn < 2; jn++) {
        int chq = jn ? chq1 : chq0;
        half4 cv;
#pragma unroll
        for (int reg = 0; reg < 4; reg++) {
          float v = acc1[i][jn][reg];
          cv[reg] = (f16)(v > 0.f ? v : 0.f);
        }
        half4* pxl = (half4*)(xnh + r * 72 + chq);
        *pxl = *pxl + cv;   // v_pk_add_f16 x2
      }
    }
  }
  __syncthreads();
  // conv MFMAs reading xn4 (neighbor rows via LDS tables); bias via acc init
  f32x4 k0 = {kbl[chq0], kbl[chq0 + 1], kbl[chq0 + 2], kbl[chq0 + 3]};
  f32x4 k1 = {kbl[chq1], kbl[chq1 + 1], kbl[chq1 + 2], kbl[chq1 + 3]};
  f32x4 acc2[3][2];
#pragma unroll
  for (int i = 0; i < 3; i++) { acc2[i][0] = k0; acc2[i][1] = k1; }
  int rdw[3][3];
#pragma unroll
  for (int i = 0; i < 3; i++) {
    if (i >= mcnt) continue;
    int mr = ((m0 + i) << 4) + (lane & 15);
    rdw[i][0] = prevs[mr];
    rdw[i][1] = mr;
    rdw[i][2] = nexts[mr];
  }
  const uint4* Bg = (const uint4*)p.Bp[seg];
  for (int kc = 0; kc < 6; kc++) {
    int w_ = kc >> 1;
    int chunk = ((kc & 1) << 2) + (lane >> 4);
    HU ak[2], xv[3];
#pragma unroll
    for (int jn = 0; jn < 2; jn++)
      ak[jn].u = Bg[((wave_n * 2 + jn) * 6 + kc) * 64 + lane];
#pragma unroll
    for (int i = 0; i < 3; i++)
      if (i < mcnt) xv[i].u = xn4[rdw[i][w_] * 9 + chunk];
#pragma unroll
    for (int i = 0; i < 3; i++)
      if (i < mcnt) {
#pragma unroll
        for (int jn = 0; jn < 2; jn++)
          acc2[i][jn] = __builtin_amdgcn_mfma_f32_16x16x32_f16(ak[jn].h, xv[i].h, acc2[i][jn], 0, 0, 0);
      }
  }
  __syncthreads();  // conv reads of xn4 complete before overwrite
  // epilogue 2: final = xn + relu(conv + Kb), pk-f16 RMW in LDS
#pragma unroll
  for (int i = 0; i < 3; i++) {
    if (i >= mcnt) continue;
    int r = ((m0 + i) << 4) + (lane & 15);
#pragma unroll
    for (int jn = 0; jn < 2; jn++) {
      int chq = jn ? chq1 : chq0;
      half4 cv;
#pragma unroll
      for (int reg = 0; reg < 4; reg++) {
        float v = acc2[i][jn][reg];
        cv[reg] = (f16)(v > 0.f ? v : 0.f);
      }
      half4* pxl = (half4*)(xnh + r * 72 + chq);
      *pxl = *pxl + cv;
    }
  }
  __syncthreads();
  // coalesced copy-out (named scalars; uniform fast paths)
  if (n8 == 768) {
    uint4 c0 = xn4[(t >> 3) * 9 + ch];
    uint4 c1 = xn4[((t + 256) >> 3) * 9 + ch];
    uint4 c2 = xn4[((t + 512) >> 3) * 9 + ch];
    xg[t] = c0;
    xg[t + 256] = c1;
    xg[t + 512] = c2;
  } else if (n8 == 640) {
    uint4 c0 = xn4[(t >> 3) * 9 + ch];
    uint4 c1 = xn4[((t + 256) >> 3) * 9 + ch];
    xg[t] = c0;
    xg[t + 256] = c1;
    if (t < 128) {
      uint4 c2 = xn4[((t + 512) >> 3) * 9 + ch];
      xg[t + 512] = c2;
    }
  } else {
    for (int idx = t; idx < n8; idx += 256)
      xg[idx] = xn4[(idx >> 3) * 9 + ch];
  }
}

// ---------------- p2a apply: CSR gather (padded-to-4 lists, no tail) --------

struct Apply2Params {
  const f16* xp[3];
  const int* cnt[3];
  const int* basea[3];
  const int* bucket;
  const f16* Wp[3];
  const float* bias[3];
  int nm;
};

__global__ __launch_bounds__(256) void k_apply2(Apply2Params p, f16* x) {
  __shared__ uint4 Af[512];
  __shared__ float bl[64];
  __shared__ f16 xf[64 * 72];   // 64 atoms x 64 cols, padded stride 72
  int t = threadIdx.x;
  int a0 = blockIdx.x * 64;
  int lane = t & 63, wid = t >> 6;
  int al = t >> 2, q = t & 3;
  int atom = a0 + al;
  f32x4 addv[4];
#pragma unroll
  for (int nt = 0; nt < 4; nt++) { f32x4 z = {0.f, 0.f, 0.f, 0.f}; addv[nt] = z; }
  for (int mi = 0; mi < p.nm; mi++) {
    __syncthreads();
    if (t < 64) bl[t] = p.bias[mi][t];
    float s[16];
#pragma unroll
    for (int i = 0; i < 16; i++) s[i] = 0.f;
    int cb = 0, base = 0;
    if (atom < NA) { cb = p.cnt[mi][atom]; base = p.basea[mi][atom]; }
    const uint4* xpu = (const uint4*)p.xp[mi];
    for (int i = 0; i < cb; i += 4) {
      int e0 = p.bucket[base + i],     e1 = p.bucket[base + i + 1];
      int e2 = p.bucket[base + i + 2], e3 = p.bucket[base + i + 3];
      HU va0, vb0, va1, vb1, va2, vb2, va3, vb3;
      va0.u = xpu[(long)e0 * 8 + q * 2]; vb0.u = xpu[(long)e0 * 8 + q * 2 + 1];
      va1.u = xpu[(long)e1 * 8 + q * 2]; vb1.u = xpu[(long)e1 * 8 + q * 2 + 1];
      va2.u = xpu[(long)e2 * 8 + q * 2]; vb2.u = xpu[(long)e2 * 8 + q * 2 + 1];
      va3.u = xpu[(long)e3 * 8 + q * 2]; vb3.u = xpu[(long)e3 * 8 + q * 2 + 1];
#pragma unroll
      for (int j = 0; j < 8; j++) {
        s[j] += ((float)va0.s[j] + (float)va1.s[j]) + ((float)va2.s[j] + (float)va3.s[j]);
        s[8 + j] += ((float)vb0.s[j] + (float)vb1.s[j]) + ((float)vb2.s[j] + (float)vb3.s[j]);
      }
    }
    float inv = 1.f / (float)(cb > 0 ? cb : 1);
    HU o0, o1;
#pragma unroll
    for (int j = 0; j < 8; j++) { o0.s[j] = (f16)(s[j] * inv); o1.s[j] = (f16)(s[8 + j] * inv); }
    int jb = ((al >> 4) * 2 + (q >> 1)) * 64 + (q & 1) * 32 + (al & 15);
    Af[jb] = o0.u;
    Af[jb + 16] = o1.u;
    __syncthreads();
    HU af0, af1;
    af0.u = Af[((wid << 1) + 0) * 64 + lane];
    af1.u = Af[((wid << 1) + 1) * 64 + lane];
    const uint4* Wu = (const uint4*)p.Wp[mi];
#pragma unroll
    for (int nt = 0; nt < 4; nt++) {
      HU b0, b1;
      b0.u = Wu[((nt << 1) + 0) * 64 + lane];
      b1.u = Wu[((nt << 1) + 1) * 64 + lane];
      float bv = bl[nt * 16 + (lane & 15)];
      f32x4 z = {bv, bv, bv, bv};
      z = __builtin_amdgcn_mfma_f32_16x16x32_f16(af0.h, b0.h, z, 0, 0, 0);
      z = __builtin_amdgcn_mfma_f32_16x16x32_f16(af1.h, b1.h, z, 0, 0, 0);
#pragma unroll
      for (int r = 0; r < 4; r++) {
        float vv = z[r];
        addv[nt][r] += vv > 0.f ? vv : 0.f;
      }
    }
  }
  // stash addv to LDS (owner-lane scalar writes), then vector RMW of x
  int arow_w = (wid << 4) + ((lane >> 4) << 2);
#pragma unroll
  for (int nt = 0; nt < 4; nt++) {
    int n = nt * 16 + (lane & 15);
#pragma unroll
    for (int r = 0; r < 4; r++)
      xf[(arow_w + r) * 72 + n] = (f16)addv[nt][r];
  }
  __syncthreads();
#pragma unroll
  for (int u = 0; u < 2; u++) {
    int idx = t + 256 * u;
    int arow = idx >> 3, ch8 = idx & 7;
    int atomw = a0 + arow;
    if (atomw < NA) {
      uint4* px = (uint4*)(x + (long)atomw * 64 + ch8 * 8);
      HU old; old.u = *px;
      HU ad; ad.h = *(half8*)(xf + arow * 72 + ch8 * 8);
      HU o; o.h = old.h + ad.h;   // v_pk_add_f16 x4
      *px = o.u;
    }
  }
}

// ---------------- batch mean over f16 x ----------------

__global__ __launch_bounds__(256) void k_meanscatter(const f16* src, const int* bucket,
                                                     const int* basea, const int* cnta,
                                                     float* dst, int nseg) {
  int wid = (blockIdx.x * 256 + threadIdx.x) >> 6;
  int lane = threadIdx.x & 63;
  if (wid >= nseg) return;
  int b0 = basea[wid], cnt = cnta[wid];
  float s = 0.f;
  for (int i = 0; i < cnt; i++) {
    int e = bucket[b0 + i];
    s += (float)src[(long)e * 64 + lane];
  }
  dst[(long)wid * 64 + lane] = s / (float)(cnt > 0 ? cnt : 1);
}

// ---------------- head gemm ----------------

__global__ __launch_bounds__(256) void k_head(const float* g1, const float* W,
                                              const float* bias, float* g2) {
  __shared__ float Wl[4096];
  __shared__ float inl[32 * 64];
  __shared__ float bl[64];
  int t = threadIdx.x;
  int brow = blockIdx.x * 32;
#pragma unroll
  for (int i = 0; i < 4; i++) ((float4*)Wl)[t + 256 * i] = ((const float4*)W)[t + 256 * i];
  if (t < 64) bl[t] = bias[t];
  __syncthreads();
#pragma unroll
  for (int i = 0; i < 2; i++) {
    int idx = t + 256 * i;
    int r = idx >> 4, q = idx & 15;
    ((float4*)inl)[idx] = ((const float4*)(g1 + (long)(brow + r) * 64))[q];
  }
  __syncthreads();
  int c = t & 63, rq = t >> 6;
  float acc[8];
#pragma unroll
  for (int i = 0; i < 8; i++) acc[i] = 0.f;
  for (int j = 0; j < 64; j += 4) {
    float w0 = Wl[(j + 0) * 64 + c], w1 = Wl[(j + 1) * 64 + c];
    float w2 = Wl[(j + 2) * 64 + c], w3 = Wl[(j + 3) * 64 + c];
#pragma unroll
    for (int i = 0; i < 8; i++) {
      int r = rq * 8 + i;
      float4 v = *(const float4*)&inl[r * 64 + j];
      acc[i] += v.x * w0 + v.y * w1 + v.z * w2 + v.w * w3;
    }
  }
#pragma unroll
  for (int i = 0; i < 8; i++) {
    long r = brow + rq * 8 + i;
    float v = acc[i] + bl[c];
    g2[r * 64 + c] = v > 0.f ? v : 0.f;
  }
}

__global__ __launch_bounds__(256) void k_final(const float* g2, const float* linW,
                                               const float* linb, float* out) {
  int wid = (blockIdx.x * 256 + threadIdx.x) >> 6;
  int lane = threadIdx.x & 63;
  if (wid >= NBATCH) return;
  float v = g2[(long)wid * 64 + lane] * linW[lane];
  for (int o = 32; o > 0; o >>= 1) v += __shfl_down(v, o, 64);
  if (lane == 0) out[wid] = v + linb[0];
}

__global__ __launch_bounds__(256) void k_zero_out(float* out, int n) {
  for (int i = blockIdx.x * 256 + threadIdx.x; i < n; i += gridDim.x * 256) out[i] = 0.f;
}

// ---------------- launcher ----------------

extern "C" void kernel_launch(void* const* d_in, const int* in_sizes, int n_in,
                              void* d_out, int out_size, void* d_ws, size_t ws_size,
                              hipStream_t stream) {
  (void)in_sizes; (void)n_in;

  const int* x_atom = (const int*)d_in[0];
  const int* vals[5] = {(const int*)d_in[1], (const int*)d_in[4], (const int*)d_in[7],
                        (const int*)d_in[10], (const int*)d_in[13]};
  const int* rowm[5] = {(const int*)d_in[2], (const int*)d_in[5], (const int*)d_in[8],
                        (const int*)d_in[11], (const int*)d_in[14]};
  const int* batch = (const int*)d_in[16];
  const float* aemb0 = (const float*)d_in[17];
  const float* aemb1 = (const float*)d_in[18];
  const float* aemb2 = (const float*)d_in[19];
  const float* path_emb = (const float*)d_in[20];
  const float* cycle_emb = (const float*)d_in[21];
  const float* pW_a2p = (const float*)d_in[22];
  const float* pb_a2p = (const float*)d_in[23];
  const float* pW_p2a = (const float*)d_in[24];
  const float* pb_p2a = (const float*)d_in[25];
  const float* pK = (const float*)d_in[26];
  const float* pKb = (const float*)d_in[27];
  const float* cW_a2p = (const float*)d_in[28];
  const float* cb_a2p = (const float*)d_in[29];
  const float* cW_p2a = (const float*)d_in[30];
  const float* cb_p2a = (const float*)d_in[31];
  const float* cK = (const float*)d_in[32];
  const float* cKb = (const float*)d_in[33];
  const float* alW = (const float*)d_in[34];
  const float* alb = (const float*)d_in[35];
  const float* linW = (const float*)d_in[36];
  const float* linb = (const float*)d_in[37];

  static const int Em[5] = {300000, 400000, 500000, 200000, 240000};
  static const int Km[5] = {3, 4, 5, 5, 6};
  static const int Ppb[5] = {32, 24, 16, 16, 16};
  const int CNT_N = 5 * 100000 + NBATCH;  // 504096
  const int BUCKET_N = 4103744;           // gapped + pad slack (capbase layout)

  char* ws = (char*)d_ws;
  size_t off = 0;
  auto alloc = [&](size_t nbytes) -> char* {
    char* p = ws + off;
    off = (off + nbytes + 255) & ~(size_t)255;
    return p;
  };
  f16* x = (f16*)alloc((size_t)NA * 64 * 2);   // f16 master
  __half* xp[5];
  for (int m = 0; m < 5; m++) xp[m] = (__half*)alloc(((size_t)Em[m] + 8) * 64 * 2);
  float* g1 = (float*)alloc((size_t)NBATCH * 64 * 4);
  float* g2 = (float*)alloc((size_t)NBATCH * 64 * 4);
  int* cnt = (int*)alloc((size_t)CNT_N * 4);
  int* basea = (int*)alloc((size_t)CNT_N * 4);
  int* bucket = (int*)alloc((size_t)BUCKET_N * 4);
  unsigned* ccursor = (unsigned*)alloc((size_t)NBIN * 4);
  f16* Bp = (f16*)alloc((size_t)10 * 12288 * 2);
  f16* Wpk = (f16*)alloc((size_t)20 * 4096 * 2);
  f16* Tabs = (f16*)alloc((size_t)1664 * 2);
  // pairs array (~16.4 MB) aliases xp[2]: consumed by k_passB before k_fused writes
  // xp[2]; sentinel row at xp[2]+64MB is beyond the pairs region.
  unsigned* pairs = (unsigned*)xp[2];

  if (ws_size < off) {
    k_zero_out<<<16, 256, 0, stream>>>((float*)d_out, out_size);
    return;
  }

  // ---- merged prep (atom_init + prepB + prepW + prepT + initc + sentinel zeroing)
  {
    PrepParams q;
    q.xa = x_atom; q.e0 = aemb0; q.e1 = aemb1; q.e2 = aemb2; q.x = x;
    q.pK = pK; q.cK = cK; q.Bp = Bp;
    q.pW = pW_p2a; q.cW = cW_p2a; q.pWa = pW_a2p; q.cWa = cW_a2p; q.Wp = Wpk;
    q.path_emb = path_emb; q.cycle_emb = cycle_emb; q.T = Tabs;
    q.ccursor = ccursor;
    for (int m = 0; m < 5; m++) q.xpz[m] = (f16*)xp[m];
    k_prep<<<7059, 256, 0, stream>>>(q);
  }

  // ---- CSR build: two-level counting sort (no scan; gapped + padded bucket)
  PassAParams pp;
  {
    int s = 0;
    for (int m = 0; m < 5; m++) { pp.row[m] = rowm[m]; pp.start[m] = s; s += Em[m]; }
    pp.row[5] = batch; pp.start[5] = s;
    pp.total = s + NA;  // 1740000
  }
  k_passA<<<(1740000 + 8191) / 8192, 256, 0, stream>>>(pp, ccursor, pairs);
  k_passB<<<NBIN, 256, 0, stream>>>(ccursor, pairs, bucket, cnt, basea);

  int apply_blocks = (NA + 63) / 64;  // 1563

  auto p2aW = [&](int l, int m) -> const f16* {
    return (m < 3) ? Wpk + (size_t)(l * 3 + m) * 4096
                   : Wpk + (size_t)(6 + l * 2 + (m - 3)) * 4096;
  };
  auto p2aB = [&](int l, int m) -> const float* {
    return (m < 3) ? pb_p2a + (l * 3 + m) * 64 : cb_p2a + (l * 2 + (m - 3)) * 64;
  };

  for (int l = 0; l < 2; l++) {
    // === paths group (maps 0..2), non-cyclic
    {
      FusedParams fp{};
      fp.nseg = 3; fp.cyclic = 0; fp.xh = x; fp.use_tab = (l == 0) ? 1 : 0;
      int bs = 0;
      for (int m = 0; m < 3; m++) {
        fp.gidx[m] = rowm[m]; fp.xp[m] = xp[m];
        fp.vals[m] = vals[m]; fp.tab[m] = Tabs + (size_t)m * 384;
        fp.Wa[m] = Wpk + (size_t)(10 + l * 3 + m) * 4096;
        fp.ba[m] = pb_a2p + (l * 3 + m) * 64;
        fp.Bp[m] = Bp + (size_t)(l * 3 + m) * 12288;
        fp.Kb[m] = pKb + (l * 3 + m) * 64;
        fp.k[m] = Km[m]; fp.P[m] = Em[m] / Km[m]; fp.ppb[m] = Ppb[m];
        fp.blk_start[m] = bs;
        bs += (fp.P[m] + fp.ppb[m] - 1) / fp.ppb[m];
      }
      k_fused<<<bs, 256, 0, stream>>>(fp);

      Apply2Params ap{};
      ap.nm = 3; ap.bucket = bucket;
      for (int m = 0; m < 3; m++) {
        ap.xp[m] = (const f16*)xp[m];
        ap.cnt[m] = cnt + (size_t)m * 100000;
        ap.basea[m] = basea + (size_t)m * 100000;
        ap.Wp[m] = p2aW(l, m); ap.bias[m] = p2aB(l, m);
      }
      k_apply2<<<apply_blocks, 256, 0, stream>>>(ap, x);
    }
    // === cycles group (maps 3..4), cyclic
    {
      FusedParams fp{};
      fp.nseg = 2; fp.cyclic = 1; fp.xh = x; fp.use_tab = (l == 0) ? 1 : 0;
      int bs = 0;
      for (int m = 3; m < 5; m++) {
        int i = m - 3;
        fp.gidx[i] = rowm[m]; fp.xp[i] = xp[m];
        fp.vals[i] = vals[m]; fp.tab[i] = Tabs + 1152 + (size_t)i * 256;
        fp.Wa[i] = Wpk + (size_t)(16 + l * 2 + i) * 4096;
        fp.ba[i] = cb_a2p + (l * 2 + i) * 64;
        fp.Bp[i] = Bp + (size_t)(6 + l * 2 + i) * 12288;
        fp.Kb[i] = cKb + (l * 2 + i) * 64;
        fp.k[i] = Km[m]; fp.P[i] = Em[m] / Km[m]; fp.ppb[i] = Ppb[m];
        fp.blk_start[i] = bs;
        bs += (fp.P[i] + fp.ppb[i] - 1) / fp.ppb[i];
      }
      k_fused<<<bs, 256, 0, stream>>>(fp);

      Apply2Params ap{};
      ap.nm = 2; ap.bucket = bucket;
      for (int m = 3; m < 5; m++) {
        int i = m - 3;
        ap.xp[i] = (const f16*)xp[m];
        ap.cnt[i] = cnt + (size_t)m * 100000;
        ap.basea[i] = basea + (size_t)m * 100000;
        ap.Wp[i] = p2aW(l, m); ap.bias[i] = p2aB(l, m);
      }
      k_apply2<<<apply_blocks, 256, 0, stream>>>(ap, x);
    }
  }

  // ---- head (basea entries for the batch segment are GLOBAL bucket positions)
  k_meanscatter<<<NBATCH / 4, 256, 0, stream>>>(x, bucket, basea + 500000,
                                                cnt + 500000, g1, NBATCH);
  k_head<<<NBATCH / 32, 256, 0, stream>>>(g1, alW, alb, g2);
  k_final<<<NBATCH / 4, 256, 0, stream>>>(g2, linW, linb, (float*)d_out);
}

// Round 14
// 616.008 us; speedup vs baseline: 1.5290x; 1.0431x over previous
//
#include <hip/hip_runtime.h>
#include <hip/hip_fp16.h>

#define NA 100000
#define NBATCH 4096
#define NBIN 1971       // 5 maps * 391 atom-ranges + 16 batch-ranges
#define MAPS_BINS 1955  // 5 * 391

typedef _Float16 f16;
typedef f16 half8 __attribute__((ext_vector_type(8)));
typedef f16 half4 __attribute__((ext_vector_type(4)));
typedef float f32x4 __attribute__((ext_vector_type(4)));
union HU { uint4 u; half8 h; f16 s[8]; };

// ---------------- two-level counting sort CSR build (gapped bucket, no scan) ----------
// caps sized for TRUE counts + per-atom pad-to-4 (sentinel edges for k_apply2):
// m0=1792 m1=2304 m2=2816 m3=1536 m4=1536 batch=12500
__device__ __forceinline__ unsigned capbase_of(int b) {
  if (b < 391)  return 0u       + (unsigned)(b       ) * 1792u;
  if (b < 782)  return 700672u  + (unsigned)(b -  391) * 2304u;
  if (b < 1173) return 1601536u + (unsigned)(b -  782) * 2816u;
  if (b < 1564) return 2702592u + (unsigned)(b - 1173) * 1536u;
  if (b < 1955) return 3303168u + (unsigned)(b - 1564) * 1536u;
  return 3903744u + (unsigned)(b - 1955) * 12500u;
}
// total bucket/pairs slots = 4103744 (~16.4 MB)

struct PassAParams {
  const int* row[6];
  int start[6];
  int total;
};

__global__ __launch_bounds__(256) void k_passA(PassAParams pp, unsigned* ccursor,
                                               unsigned* pairs) {
  __shared__ int hist[NBIN];
  __shared__ unsigned hbase[NBIN];
  int t = threadIdx.x;
  for (int b = t; b < NBIN; b += 256) hist[b] = 0;
  __syncthreads();
  int g0 = blockIdx.x * 8192;
  unsigned keys[32];
#pragma unroll
  for (int i = 0; i < 32; i++) {
    int g = g0 + i * 256 + t;
    keys[i] = 0xFFFFFFFFu;
    if (g < pp.total) {
      int m = 0;
#pragma unroll
      for (int j = 1; j < 6; j++) if (g >= pp.start[j]) m = j;
      int e = g - pp.start[m];
      int a = pp.row[m][e];
      int bin = (m < 5) ? m * 391 + (a >> 8) : MAPS_BINS + (a >> 8);
      keys[i] = ((unsigned)bin << 8) | (unsigned)(a & 255);
      atomicAdd(&hist[bin], 1);
    }
  }
  __syncthreads();
  for (int b = t; b < NBIN; b += 256) {
    int h = hist[b];
    hbase[b] = h ? atomicAdd(&ccursor[b], (unsigned)h) : 0u;
  }
  __syncthreads();
#pragma unroll
  for (int i = 0; i < 32; i++) {
    unsigned kv = keys[i];
    if (kv == 0xFFFFFFFFu) continue;
    int bin = (int)(kv >> 8);
    int g = g0 + i * 256 + t;
    int m = 0;
#pragma unroll
    for (int j = 1; j < 6; j++) if (g >= pp.start[j]) m = j;
    int e = g - pp.start[m];
    unsigned pos = atomicAdd(&hbase[bin], 1u);
    pairs[pos] = ((unsigned)e << 8) | (kv & 255u);
  }
}

__global__ __launch_bounds__(256) void k_passB(const unsigned* ccursor,
                                               const unsigned* pairs, int* bucket,
                                               int* cnt, int* basea) {
  __shared__ int hist[256];
  __shared__ int scn[256];
  __shared__ unsigned cur[256];
  int b = blockIdx.x;
  int t = threadIdx.x;
  unsigned cb0 = capbase_of(b);
  int count = (int)(ccursor[b] - cb0);
  const unsigned* src = pairs + cb0;
  hist[t] = 0;
  __syncthreads();
  for (int i = t; i < count; i += 256) atomicAdd(&hist[src[i] & 255u], 1);
  __syncthreads();
  int h = hist[t];
  bool isMap = (b < MAPS_BINS);
  int hp = isMap ? ((h + 3) & ~3) : h;   // pad map lists to multiple of 4
  scn[t] = hp;
  __syncthreads();
  for (int d = 1; d < 256; d <<= 1) {
    int x = (t >= d) ? scn[t - d] : 0;
    __syncthreads();
    scn[t] += x;
    __syncthreads();
  }
  int excl = scn[t] - hp;
  unsigned base = cb0 + (unsigned)excl;
  int m, a0, off, amax;
  if (isMap) { m = b / 391; a0 = (b - m * 391) << 8; off = m * 100000; amax = 100000; }
  else { m = 5; a0 = (b - MAPS_BINS) << 8; off = 500000; amax = NBATCH; }
  if (a0 + t < amax) {
    cnt[off + a0 + t] = h;               // TRUE count (mean divisor)
    basea[off + a0 + t] = (int)base;     // padded-prefix base
  }
  cur[t] = base;
  __syncthreads();
  for (int i = t; i < count; i += 256) {
    unsigned v = src[i];
    unsigned pos = atomicAdd(&cur[v & 255u], 1u);
    bucket[pos] = (int)(v >> 8);
  }
  // sentinel pads (disjoint slots; sentinel row E_m is zeroed in k_prep)
  if (isMap && h > 0) {
    static const int EmS[5] = {300000, 400000, 500000, 200000, 240000};
    int sent = EmS[m];
    for (int j = h; j < hp; j++) bucket[base + j] = sent;
  }
}

// ---------------- merged prep kernel: atom_init + prepB + prepW + prepT + initc --------

struct PrepParams {
  const int* xa; const float *e0; const float *e1; const float *e2; f16* x;
  const float *pK; const float *cK; f16* Bp;
  const float *pW; const float *cW; const float *pWa; const float *cWa; f16* Wp;
  const float *path_emb; const float *cycle_emb; f16* T;
  unsigned* ccursor;
  f16* xpz[5];
};

__global__ __launch_bounds__(256) void k_prep(PrepParams q) {
  int bid = blockIdx.x, t = threadIdx.x;
  if (bid < 6250) {
    int idx = bid * 256 + t;
    int a = idx >> 4, qq = idx & 15;
    int f0 = q.xa[a * 3], f1 = q.xa[a * 3 + 1], f2 = q.xa[a * 3 + 2];
    float4 v0 = ((const float4*)q.e0)[f0 * 16 + qq];
    float4 v1 = ((const float4*)q.e1)[f1 * 16 + qq];
    float4 v2 = ((const float4*)q.e2)[f2 * 16 + qq];
    half4 h = {(f16)(v0.x + v1.x + v2.x), (f16)(v0.y + v1.y + v2.y),
               (f16)(v0.z + v1.z + v2.z), (f16)(v0.w + v1.w + v2.w)};
    ((half4*)q.x)[idx] = h;
  } else if (bid < 6730) {
    int tid = (bid - 6250) * 256 + t;
    int set = tid / 12288, pos = tid % 12288;
    int j = pos & 7, lane = (pos >> 3) & 63, kcnt = pos >> 9;
    int kc = kcnt % 6, nt = kcnt / 6;
    int k = kc * 32 + ((lane >> 4) << 3) + j;
    int n = (nt << 4) + (lane & 15);
    int w = k >> 6, ji = k & 63;
    const float* K = (set < 6) ? (q.pK + set * 3 * 4096) : (q.cK + (set - 6) * 3 * 4096);
    float v = K[w * 4096 + ji * 64 + n];
    if (set >= 6) v = 0.5f * (v + K[(2 - w) * 4096 + ji * 64 + n]);
    q.Bp[tid] = (f16)v;
  } else if (bid < 7050) {
    int tid = (bid - 6730) * 256 + t;
    int set = tid >> 12, pos = tid & 4095;
    int j = pos & 7, lane = (pos >> 3) & 63, ntkc = pos >> 9;
    int kc = ntkc & 1, nt = ntkc >> 1;
    int k = kc * 32 + ((lane >> 4) << 3) + j;
    int n = (nt << 4) + (lane & 15);
    const float* W;
    if (set < 6) W = q.pW + set * 4096;
    else if (set < 10) W = q.cW + (set - 6) * 4096;
    else if (set < 16) W = q.pWa + (set - 10) * 4096;
    else W = q.cWa + (set - 16) * 4096;
    q.Wp[tid] = (f16)W[k * 64 + n];
  } else {
    int idx = (bid - 7050) * 256 + t;
    if (idx < 1664) {
      float v = (idx < 1152) ? q.path_emb[idx] : q.cycle_emb[idx - 1152];
      q.T[idx] = (f16)v;
    }
    if (idx < NBIN) q.ccursor[idx] = capbase_of(idx);
    if (idx >= 2048 && idx < 2088) {
      static const int EmS[5] = {300000, 400000, 500000, 200000, 240000};
      int s = idx - 2048, m = s >> 3, c = s & 7;
      uint4 z; z.x = z.y = z.z = z.w = 0;
      ((uint4*)(q.xpz[m] + (size_t)EmS[m] * 64))[c] = z;  // zero sentinel row
    }
  }
}

// ---------------- fused a2p+conv (swapped-operand MFMA) ----------------
// R12/R13-measured body: ridx staged in LDS, gather after barrier, spill-free
// uniform fast paths (n8=768/640), bias via acc init, pk-f16 epilogue RMW.

struct FusedParams {
  const f16* xh;
  const int* gidx[3];
  const int* vals[3];
  const f16* tab[3];
  __half* xp[3];
  const f16* Wa[3];
  const float* ba[3];
  const f16* Bp[3];
  const float* Kb[3];
  int k[3];
  int P[3];
  int ppb[3];
  int blk_start[3];
  int nseg;
  int cyclic;
  int use_tab;
};

__global__ __launch_bounds__(256) void k_fused(FusedParams p) {
  __shared__ uint4 xn4[873];     // 97 rows x 9 uint4 (72 f16/row, row 96 = zero pad)
  __shared__ float bl[64], kbl[64];
  __shared__ int ridx[96];
  __shared__ short prevs[96], nexts[96];
  int bid = blockIdx.x;
  int seg = 0;
#pragma unroll
  for (int i = 1; i < 3; i++) if (i < p.nseg && bid >= p.blk_start[i]) seg = i;
  int kk = p.k[seg], ppb = p.ppb[seg], P = p.P[seg];
  int cyc = p.cyclic;
  int t = threadIdx.x;
  int p0 = (bid - p.blk_start[seg]) * ppb;
  int np = min(ppb, P - p0);
  int R = np * kk;    // always a multiple of 16 for these ppb choices
  int mtb = R >> 4;
  long ebase = (long)p0 * kk;
  if (t < 64) { bl[t] = p.ba[seg][t]; kbl[t] = p.Kb[seg][t]; }
  if (t < 9) { uint4 z; z.x = z.y = z.z = z.w = 0; xn4[96 * 9 + t] = z; }
  if (t < R) ridx[t] = p.gidx[seg][ebase + t];
  if (t < 96) {
    int sm = t % kk;
    prevs[t] = (short)((sm >= 1) ? t - 1 : (cyc ? t + kk - 1 : 96));
    nexts[t] = (short)((sm + 1 < kk) ? t + 1 : (cyc ? t + 1 - kk : 96));
  }
  uint4* xg = (uint4*)(p.xp[seg] + (long)ebase * 64);
  int n8 = R * 8;   // 768 (R=96) or 640 (R=80) for full blocks
  int ch = t & 7;
  // residual prefetch into xn4 (named scalars; uniform fast paths = no scratch)
  if (p.use_tab) {
    const uint4* tabu = (const uint4*)p.tab[seg];
    const int* vseg = p.vals[seg];
    if (n8 == 768) {
      int v0 = vseg[ebase + (t >> 3)];
      int v1 = vseg[ebase + ((t + 256) >> 3)];
      int v2 = vseg[ebase + ((t + 512) >> 3)];
      uint4 a0 = tabu[v0 * 8 + ch];
      uint4 a1 = tabu[v1 * 8 + ch];
      uint4 a2 = tabu[v2 * 8 + ch];
      xn4[(t >> 3) * 9 + ch] = a0;
      xn4[((t + 256) >> 3) * 9 + ch] = a1;
      xn4[((t + 512) >> 3) * 9 + ch] = a2;
    } else if (n8 == 640) {
      int v0 = vseg[ebase + (t >> 3)];
      int v1 = vseg[ebase + ((t + 256) >> 3)];
      uint4 a0 = tabu[v0 * 8 + ch];
      uint4 a1 = tabu[v1 * 8 + ch];
      xn4[(t >> 3) * 9 + ch] = a0;
      xn4[((t + 256) >> 3) * 9 + ch] = a1;
      if (t < 128) {
        int v2 = vseg[ebase + ((t + 512) >> 3)];
        uint4 a2 = tabu[v2 * 8 + ch];
        xn4[((t + 512) >> 3) * 9 + ch] = a2;
      }
    } else {
      for (int idx = t; idx < n8; idx += 256) {
        int row = idx >> 3;
        xn4[row * 9 + ch] = tabu[vseg[ebase + row] * 8 + ch];
      }
    }
  } else {
    if (n8 == 768) {
      uint4 a0 = xg[t];
      uint4 a1 = xg[t + 256];
      uint4 a2 = xg[t + 512];
      xn4[(t >> 3) * 9 + ch] = a0;
      xn4[((t + 256) >> 3) * 9 + ch] = a1;
      xn4[((t + 512) >> 3) * 9 + ch] = a2;
    } else if (n8 == 640) {
      uint4 a0 = xg[t];
      uint4 a1 = xg[t + 256];
      xn4[(t >> 3) * 9 + ch] = a0;
      xn4[((t + 256) >> 3) * 9 + ch] = a1;
      if (t < 128) {
        uint4 a2 = xg[t + 512];
        xn4[((t + 512) >> 3) * 9 + ch] = a2;
      }
    } else {
      for (int idx = t; idx < n8; idx += 256)
        xn4[(idx >> 3) * 9 + ch] = xg[idx];
    }
  }
  __syncthreads();
  int lane = t & 63, wid = t >> 6;
  int wave_n = wid & 1, wave_m = wid >> 1;
  int mtA = (mtb + 1) >> 1;
  int m0 = wave_m ? mtA : 0;
  int mcnt = wave_m ? (mtb - mtA) : mtA;
  f16* xnh = (f16*)xn4;
  int chq0 = wave_n * 32 + ((lane >> 4) << 2);   // jn=0 channel quad
  int chq1 = chq0 + 16;                           // jn=1 channel quad
  // stage A: xn += relu(x_gather @ Wa + ba)  (bias via acc init; pk-f16 residual add)
  {
    f32x4 b0 = {bl[chq0], bl[chq0 + 1], bl[chq0 + 2], bl[chq0 + 3]};
    f32x4 b1 = {bl[chq1], bl[chq1 + 1], bl[chq1 + 2], bl[chq1 + 3]};
    f32x4 acc1[3][2];
#pragma unroll
    for (int i = 0; i < 3; i++) { acc1[i][0] = b0; acc1[i][1] = b1; }
    const uint4* Wau = (const uint4*)p.Wa[seg];
    HU w[2][2];
#pragma unroll
    for (int kc = 0; kc < 2; kc++)
#pragma unroll
      for (int jn = 0; jn < 2; jn++)
        w[kc][jn].u = Wau[(((wave_n * 2 + jn) << 1) + kc) * 64 + lane];
    const uint4* xh4 = (const uint4*)p.xh;
#pragma unroll
    for (int i = 0; i < 3; i++) {
      if (i >= mcnt) continue;
      int rowid = ridx[((m0 + i) << 4) + (lane & 15)];
      HU xa, xb;
      xa.u = xh4[(long)rowid * 8 + (lane >> 4)];
      xb.u = xh4[(long)rowid * 8 + 4 + (lane >> 4)];
#pragma unroll
      for (int jn = 0; jn < 2; jn++) {
        acc1[i][jn] = __builtin_amdgcn_mfma_f32_16x16x32_f16(w[0][jn].h, xa.h, acc1[i][jn], 0, 0, 0);
        acc1[i][jn] = __builtin_amdgcn_mfma_f32_16x16x32_f16(w[1][jn].h, xb.h, acc1[i][jn], 0, 0, 0);
      }
    }
#pragma unroll
    for (int i = 0; i < 3; i++) {
      if (i >= mcnt) continue;
      int r = ((m0 + i) << 4) + (lane & 15);
#pragma unroll
      for (int jn = 0; jn < 2; jn++) {
        int chq = jn ? chq1 : chq0;
        half4 cv;
#pragma unroll
        for (int reg = 0; reg < 4; reg++) {
          float v = acc1[i][jn][reg];
          cv[reg] = (f16)(v > 0.f ? v : 0.f);
        }
        half4* pxl = (half4*)(xnh + r * 72 + chq);
        *pxl = *pxl + cv;   // v_pk_add_f16 x2
      }
    }
  }
  __syncthreads();
  // conv MFMAs reading xn4 (neighbor rows via LDS tables); bias via acc init
  f32x4 k0 = {kbl[chq0], kbl[chq0 + 1], kbl[chq0 + 2], kbl[chq0 + 3]};
  f32x4 k1 = {kbl[chq1], kbl[chq1 + 1], kbl[chq1 + 2], kbl[chq1 + 3]};
  f32x4 acc2[3][2];
#pragma unroll
  for (int i = 0; i < 3; i++) { acc2[i][0] = k0; acc2[i][1] = k1; }
  int rdw[3][3];
#pragma unroll
  for (int i = 0; i < 3; i++) {
    if (i >= mcnt) continue;
    int mr = ((m0 + i) << 4) + (lane & 15);
    rdw[i][0] = prevs[mr];
    rdw[i][1] = mr;
    rdw[i][2] = nexts[mr];
  }
  const uint4* Bg = (const uint4*)p.Bp[seg];
  for (int kc = 0; kc < 6; kc++) {
    int w_ = kc >> 1;
    int chunk = ((kc & 1) << 2) + (lane >> 4);
    HU ak[2], xv[3];
#pragma unroll
    for (int jn = 0; jn < 2; jn++)
      ak[jn].u = Bg[((wave_n * 2 + jn) * 6 + kc) * 64 + lane];
#pragma unroll
    for (int i = 0; i < 3; i++)
      if (i < mcnt) xv[i].u = xn4[rdw[i][w_] * 9 + chunk];
#pragma unroll
    for (int i = 0; i < 3; i++)
      if (i < mcnt) {
#pragma unroll
        for (int jn = 0; jn < 2; jn++)
          acc2[i][jn] = __builtin_amdgcn_mfma_f32_16x16x32_f16(ak[jn].h, xv[i].h, acc2[i][jn], 0, 0, 0);
      }
  }
  __syncthreads();  // conv reads of xn4 complete before overwrite
  // epilogue 2: final = xn + relu(conv + Kb), pk-f16 RMW in LDS
#pragma unroll
  for (int i = 0; i < 3; i++) {
    if (i >= mcnt) continue;
    int r = ((m0 + i) << 4) + (lane & 15);
#pragma unroll
    for (int jn = 0; jn < 2; jn++) {
      int chq = jn ? chq1 : chq0;
      half4 cv;
#pragma unroll
      for (int reg = 0; reg < 4; reg++) {
        float v = acc2[i][jn][reg];
        cv[reg] = (f16)(v > 0.f ? v : 0.f);
      }
      half4* pxl = (half4*)(xnh + r * 72 + chq);
      *pxl = *pxl + cv;
    }
  }
  __syncthreads();
  // coalesced copy-out (named scalars; uniform fast paths)
  if (n8 == 768) {
    uint4 c0 = xn4[(t >> 3) * 9 + ch];
    uint4 c1 = xn4[((t + 256) >> 3) * 9 + ch];
    uint4 c2 = xn4[((t + 512) >> 3) * 9 + ch];
    xg[t] = c0;
    xg[t + 256] = c1;
    xg[t + 512] = c2;
  } else if (n8 == 640) {
    uint4 c0 = xn4[(t >> 3) * 9 + ch];
    uint4 c1 = xn4[((t + 256) >> 3) * 9 + ch];
    xg[t] = c0;
    xg[t + 256] = c1;
    if (t < 128) {
      uint4 c2 = xn4[((t + 512) >> 3) * 9 + ch];
      xg[t + 512] = c2;
    }
  } else {
    for (int idx = t; idx < n8; idx += 256)
      xg[idx] = xn4[(idx >> 3) * 9 + ch];
  }
}

// ---------------- p2a apply: CSR gather (padded lists) + double-buffered Af ----------
// One barrier per map (Af[2] ping-pong; write->barrier->MFMA->gather(next)); the next
// map's gather overlaps the current map's MFMA+epilogue instead of sitting between
// two block-wide barriers. Correctness: a write to Af[b] and the prior read of Af[b]
// (two iterations earlier) are separated by the intervening iteration's barrier.

struct Apply2Params {
  const f16* xp[3];
  const int* cnt[3];
  const int* basea[3];
  const int* bucket;
  const f16* Wp[3];
  const float* bias[3];
  int nm;
};

__global__ __launch_bounds__(256) void k_apply2(Apply2Params p, f16* x) {
  __shared__ uint4 Af[2][512];
  __shared__ float bl[3][64];
  __shared__ f16 xf[64 * 72];   // 64 atoms x 64 cols, padded stride 72
  int t = threadIdx.x;
  int a0 = blockIdx.x * 64;
  int lane = t & 63, wid = t >> 6;
  int al = t >> 2, q = t & 3;
  int atom = a0 + al;
  int nm = p.nm;
  if (t < 64 * nm) bl[t >> 6][t & 63] = p.bias[t >> 6][t & 63];
  f32x4 addv[4];
#pragma unroll
  for (int nt = 0; nt < 4; nt++) { f32x4 z = {0.f, 0.f, 0.f, 0.f}; addv[nt] = z; }
  float s[16];
  auto gather = [&](int mi) {
#pragma unroll
    for (int i = 0; i < 16; i++) s[i] = 0.f;
    int cb = 0, base = 0;
    if (atom < NA) { cb = p.cnt[mi][atom]; base = p.basea[mi][atom]; }
    const uint4* xpu = (const uint4*)p.xp[mi];
    // lists padded to multiple of 4 with sentinel (zero-row) edges: no scalar tail
    for (int i = 0; i < cb; i += 4) {
      int e0 = p.bucket[base + i],     e1 = p.bucket[base + i + 1];
      int e2 = p.bucket[base + i + 2], e3 = p.bucket[base + i + 3];
      HU va0, vb0, va1, vb1, va2, vb2, va3, vb3;
      va0.u = xpu[(long)e0 * 8 + q * 2]; vb0.u = xpu[(long)e0 * 8 + q * 2 + 1];
      va1.u = xpu[(long)e1 * 8 + q * 2]; vb1.u = xpu[(long)e1 * 8 + q * 2 + 1];
      va2.u = xpu[(long)e2 * 8 + q * 2]; vb2.u = xpu[(long)e2 * 8 + q * 2 + 1];
      va3.u = xpu[(long)e3 * 8 + q * 2]; vb3.u = xpu[(long)e3 * 8 + q * 2 + 1];
#pragma unroll
      for (int j = 0; j < 8; j++) {
        s[j] += ((float)va0.s[j] + (float)va1.s[j]) + ((float)va2.s[j] + (float)va3.s[j]);
        s[8 + j] += ((float)vb0.s[j] + (float)vb1.s[j]) + ((float)vb2.s[j] + (float)vb3.s[j]);
      }
    }
  };
  gather(0);
  int jb = ((al >> 4) * 2 + (q >> 1)) * 64 + (q & 1) * 32 + (al & 15);
  for (int mi = 0; mi < nm; mi++) {
    int cur = mi & 1;
    int cbi = (atom < NA) ? p.cnt[mi][atom] : 0;
    float inv = 1.f / (float)(cbi > 0 ? cbi : 1);
    HU o0, o1;
#pragma unroll
    for (int j = 0; j < 8; j++) { o0.s[j] = (f16)(s[j] * inv); o1.s[j] = (f16)(s[8 + j] * inv); }
    Af[cur][jb] = o0.u;
    Af[cur][jb + 16] = o1.u;
    __syncthreads();
    HU af0, af1;
    af0.u = Af[cur][((wid << 1) + 0) * 64 + lane];
    af1.u = Af[cur][((wid << 1) + 1) * 64 + lane];
    const uint4* Wu = (const uint4*)p.Wp[mi];
#pragma unroll
    for (int nt = 0; nt < 4; nt++) {
      HU b0, b1;
      b0.u = Wu[((nt << 1) + 0) * 64 + lane];
      b1.u = Wu[((nt << 1) + 1) * 64 + lane];
      float bv = bl[mi][nt * 16 + (lane & 15)];
      f32x4 z = {bv, bv, bv, bv};
      z = __builtin_amdgcn_mfma_f32_16x16x32_f16(af0.h, b0.h, z, 0, 0, 0);
      z = __builtin_amdgcn_mfma_f32_16x16x32_f16(af1.h, b1.h, z, 0, 0, 0);
#pragma unroll
      for (int r = 0; r < 4; r++) {
        float vv = z[r];
        addv[nt][r] += vv > 0.f ? vv : 0.f;
      }
    }
    if (mi + 1 < nm) gather(mi + 1);   // overlaps this map's MFMA/epilogue latency
  }
  // stash addv to LDS (owner-lane scalar writes), then vector RMW of x
  int arow_w = (wid << 4) + ((lane >> 4) << 2);
#pragma unroll
  for (int nt = 0; nt < 4; nt++) {
    int n = nt * 16 + (lane & 15);
#pragma unroll
    for (int r = 0; r < 4; r++)
      xf[(arow_w + r) * 72 + n] = (f16)addv[nt][r];
  }
  __syncthreads();
#pragma unroll
  for (int u = 0; u < 2; u++) {
    int idx = t + 256 * u;
    int arow = idx >> 3, ch8 = idx & 7;
    int atomw = a0 + arow;
    if (atomw < NA) {
      uint4* px = (uint4*)(x + (long)atomw * 64 + ch8 * 8);
      HU old; old.u = *px;
      HU ad; ad.h = *(half8*)(xf + arow * 72 + ch8 * 8);
      HU o; o.h = old.h + ad.h;   // v_pk_add_f16 x4
      *px = o.u;
    }
  }
}

// ---------------- batch mean over f16 x ----------------

__global__ __launch_bounds__(256) void k_meanscatter(const f16* src, const int* bucket,
                                                     const int* basea, const int* cnta,
                                                     float* dst, int nseg) {
  int wid = (blockIdx.x * 256 + threadIdx.x) >> 6;
  int lane = threadIdx.x & 63;
  if (wid >= nseg) return;
  int b0 = basea[wid], cnt = cnta[wid];
  float s = 0.f;
  for (int i = 0; i < cnt; i++) {
    int e = bucket[b0 + i];
    s += (float)src[(long)e * 64 + lane];
  }
  dst[(long)wid * 64 + lane] = s / (float)(cnt > 0 ? cnt : 1);
}

// ---------------- head gemm ----------------

__global__ __launch_bounds__(256) void k_head(const float* g1, const float* W,
                                              const float* bias, float* g2) {
  __shared__ float Wl[4096];
  __shared__ float inl[32 * 64];
  __shared__ float bl[64];
  int t = threadIdx.x;
  int brow = blockIdx.x * 32;
#pragma unroll
  for (int i = 0; i < 4; i++) ((float4*)Wl)[t + 256 * i] = ((const float4*)W)[t + 256 * i];
  if (t < 64) bl[t] = bias[t];
  __syncthreads();
#pragma unroll
  for (int i = 0; i < 2; i++) {
    int idx = t + 256 * i;
    int r = idx >> 4, q = idx & 15;
    ((float4*)inl)[idx] = ((const float4*)(g1 + (long)(brow + r) * 64))[q];
  }
  __syncthreads();
  int c = t & 63, rq = t >> 6;
  float acc[8];
#pragma unroll
  for (int i = 0; i < 8; i++) acc[i] = 0.f;
  for (int j = 0; j < 64; j += 4) {
    float w0 = Wl[(j + 0) * 64 + c], w1 = Wl[(j + 1) * 64 + c];
    float w2 = Wl[(j + 2) * 64 + c], w3 = Wl[(j + 3) * 64 + c];
#pragma unroll
    for (int i = 0; i < 8; i++) {
      int r = rq * 8 + i;
      float4 v = *(const float4*)&inl[r * 64 + j];
      acc[i] += v.x * w0 + v.y * w1 + v.z * w2 + v.w * w3;
    }
  }
#pragma unroll
  for (int i = 0; i < 8; i++) {
    long r = brow + rq * 8 + i;
    float v = acc[i] + bl[c];
    g2[r * 64 + c] = v > 0.f ? v : 0.f;
  }
}

__global__ __launch_bounds__(256) void k_final(const float* g2, const float* linW,
                                               const float* linb, float* out) {
  int wid = (blockIdx.x * 256 + threadIdx.x) >> 6;
  int lane = threadIdx.x & 63;
  if (wid >= NBATCH) return;
  float v = g2[(long)wid * 64 + lane] * linW[lane];
  for (int o = 32; o > 0; o >>= 1) v += __shfl_down(v, o, 64);
  if (lane == 0) out[wid] = v + linb[0];
}

__global__ __launch_bounds__(256) void k_zero_out(float* out, int n) {
  for (int i = blockIdx.x * 256 + threadIdx.x; i < n; i += gridDim.x * 256) out[i] = 0.f;
}

// ---------------- launcher ----------------

extern "C" void kernel_launch(void* const* d_in, const int* in_sizes, int n_in,
                              void* d_out, int out_size, void* d_ws, size_t ws_size,
                              hipStream_t stream) {
  (void)in_sizes; (void)n_in;

  const int* x_atom = (const int*)d_in[0];
  const int* vals[5] = {(const int*)d_in[1], (const int*)d_in[4], (const int*)d_in[7],
                        (const int*)d_in[10], (const int*)d_in[13]};
  const int* rowm[5] = {(const int*)d_in[2], (const int*)d_in[5], (const int*)d_in[8],
                        (const int*)d_in[11], (const int*)d_in[14]};
  const int* batch = (const int*)d_in[16];
  const float* aemb0 = (const float*)d_in[17];
  const float* aemb1 = (const float*)d_in[18];
  const float* aemb2 = (const float*)d_in[19];
  const float* path_emb = (const float*)d_in[20];
  const float* cycle_emb = (const float*)d_in[21];
  const float* pW_a2p = (const float*)d_in[22];
  const float* pb_a2p = (const float*)d_in[23];
  const float* pW_p2a = (const float*)d_in[24];
  const float* pb_p2a = (const float*)d_in[25];
  const float* pK = (const float*)d_in[26];
  const float* pKb = (const float*)d_in[27];
  const float* cW_a2p = (const float*)d_in[28];
  const float* cb_a2p = (const float*)d_in[29];
  const float* cW_p2a = (const float*)d_in[30];
  const float* cb_p2a = (const float*)d_in[31];
  const float* cK = (const float*)d_in[32];
  const float* cKb = (const float*)d_in[33];
  const float* alW = (const float*)d_in[34];
  const float* alb = (const float*)d_in[35];
  const float* linW = (const float*)d_in[36];
  const float* linb = (const float*)d_in[37];

  static const int Em[5] = {300000, 400000, 500000, 200000, 240000};
  static const int Km[5] = {3, 4, 5, 5, 6};
  static const int Ppb[5] = {32, 24, 16, 16, 16};
  const int CNT_N = 5 * 100000 + NBATCH;  // 504096
  const int BUCKET_N = 4103744;           // gapped + pad slack (capbase layout)

  char* ws = (char*)d_ws;
  size_t off = 0;
  auto alloc = [&](size_t nbytes) -> char* {
    char* p = ws + off;
    off = (off + nbytes + 255) & ~(size_t)255;
    return p;
  };
  f16* x = (f16*)alloc((size_t)NA * 64 * 2);   // f16 master
  __half* xp[5];
  for (int m = 0; m < 5; m++) xp[m] = (__half*)alloc(((size_t)Em[m] + 8) * 64 * 2);
  float* g1 = (float*)alloc((size_t)NBATCH * 64 * 4);
  float* g2 = (float*)alloc((size_t)NBATCH * 64 * 4);
  int* cnt = (int*)alloc((size_t)CNT_N * 4);
  int* basea = (int*)alloc((size_t)CNT_N * 4);
  int* bucket = (int*)alloc((size_t)BUCKET_N * 4);
  unsigned* ccursor = (unsigned*)alloc((size_t)NBIN * 4);
  f16* Bp = (f16*)alloc((size_t)10 * 12288 * 2);
  f16* Wpk = (f16*)alloc((size_t)20 * 4096 * 2);
  f16* Tabs = (f16*)alloc((size_t)1664 * 2);
  // pairs array (~16.4 MB) aliases xp[2]: consumed by k_passB before k_fused writes
  // xp[2]; sentinel row at xp[2]+64MB is beyond the pairs region.
  unsigned* pairs = (unsigned*)xp[2];

  if (ws_size < off) {
    k_zero_out<<<16, 256, 0, stream>>>((float*)d_out, out_size);
    return;
  }

  // ---- merged prep (atom_init + prepB + prepW + prepT + initc + sentinel zeroing)
  {
    PrepParams q;
    q.xa = x_atom; q.e0 = aemb0; q.e1 = aemb1; q.e2 = aemb2; q.x = x;
    q.pK = pK; q.cK = cK; q.Bp = Bp;
    q.pW = pW_p2a; q.cW = cW_p2a; q.pWa = pW_a2p; q.cWa = cW_a2p; q.Wp = Wpk;
    q.path_emb = path_emb; q.cycle_emb = cycle_emb; q.T = Tabs;
    q.ccursor = ccursor;
    for (int m = 0; m < 5; m++) q.xpz[m] = (f16*)xp[m];
    k_prep<<<7059, 256, 0, stream>>>(q);
  }

  // ---- CSR build: two-level counting sort (no scan; gapped + padded bucket)
  PassAParams pp;
  {
    int s = 0;
    for (int m = 0; m < 5; m++) { pp.row[m] = rowm[m]; pp.start[m] = s; s += Em[m]; }
    pp.row[5] = batch; pp.start[5] = s;
    pp.total = s + NA;  // 1740000
  }
  k_passA<<<(1740000 + 8191) / 8192, 256, 0, stream>>>(pp, ccursor, pairs);
  k_passB<<<NBIN, 256, 0, stream>>>(ccursor, pairs, bucket, cnt, basea);

  int apply_blocks = (NA + 63) / 64;  // 1563

  auto p2aW = [&](int l, int m) -> const f16* {
    return (m < 3) ? Wpk + (size_t)(l * 3 + m) * 4096
                   : Wpk + (size_t)(6 + l * 2 + (m - 3)) * 4096;
  };
  auto p2aB = [&](int l, int m) -> const float* {
    return (m < 3) ? pb_p2a + (l * 3 + m) * 64 : cb_p2a + (l * 2 + (m - 3)) * 64;
  };

  for (int l = 0; l < 2; l++) {
    // === paths group (maps 0..2), non-cyclic
    {
      FusedParams fp{};
      fp.nseg = 3; fp.cyclic = 0; fp.xh = x; fp.use_tab = (l == 0) ? 1 : 0;
      int bs = 0;
      for (int m = 0; m < 3; m++) {
        fp.gidx[m] = rowm[m]; fp.xp[m] = xp[m];
        fp.vals[m] = vals[m]; fp.tab[m] = Tabs + (size_t)m * 384;
        fp.Wa[m] = Wpk + (size_t)(10 + l * 3 + m) * 4096;
        fp.ba[m] = pb_a2p + (l * 3 + m) * 64;
        fp.Bp[m] = Bp + (size_t)(l * 3 + m) * 12288;
        fp.Kb[m] = pKb + (l * 3 + m) * 64;
        fp.k[m] = Km[m]; fp.P[m] = Em[m] / Km[m]; fp.ppb[m] = Ppb[m];
        fp.blk_start[m] = bs;
        bs += (fp.P[m] + fp.ppb[m] - 1) / fp.ppb[m];
      }
      k_fused<<<bs, 256, 0, stream>>>(fp);

      Apply2Params ap{};
      ap.nm = 3; ap.bucket = bucket;
      for (int m = 0; m < 3; m++) {
        ap.xp[m] = (const f16*)xp[m];
        ap.cnt[m] = cnt + (size_t)m * 100000;
        ap.basea[m] = basea + (size_t)m * 100000;
        ap.Wp[m] = p2aW(l, m); ap.bias[m] = p2aB(l, m);
      }
      k_apply2<<<apply_blocks, 256, 0, stream>>>(ap, x);
    }
    // === cycles group (maps 3..4), cyclic
    {
      FusedParams fp{};
      fp.nseg = 2; fp.cyclic = 1; fp.xh = x; fp.use_tab = (l == 0) ? 1 : 0;
      int bs = 0;
      for (int m = 3; m < 5; m++) {
        int i = m - 3;
        fp.gidx[i] = rowm[m]; fp.xp[i] = xp[m];
        fp.vals[i] = vals[m]; fp.tab[i] = Tabs + 1152 + (size_t)i * 256;
        fp.Wa[i] = Wpk + (size_t)(16 + l * 2 + i) * 4096;
        fp.ba[i] = cb_a2p + (l * 2 + i) * 64;
        fp.Bp[i] = Bp + (size_t)(6 + l * 2 + i) * 12288;
        fp.Kb[i] = cKb + (l * 2 + i) * 64;
        fp.k[i] = Km[m]; fp.P[i] = Em[m] / Km[m]; fp.ppb[i] = Ppb[m];
        fp.blk_start[i] = bs;
        bs += (fp.P[i] + fp.ppb[i] - 1) / fp.ppb[i];
      }
      k_fused<<<bs, 256, 0, stream>>>(fp);

      Apply2Params ap{};
      ap.nm = 2; ap.bucket = bucket;
      for (int m = 3; m < 5; m++) {
        int i = m - 3;
        ap.xp[i] = (const f16*)xp[m];
        ap.cnt[i] = cnt + (size_t)m * 100000;
        ap.basea[i] = basea + (size_t)m * 100000;
        ap.Wp[i] = p2aW(l, m); ap.bias[i] = p2aB(l, m);
      }
      k_apply2<<<apply_blocks, 256, 0, stream>>>(ap, x);
    }
  }

  // ---- head (basea entries for the batch segment are GLOBAL bucket positions)
  k_meanscatter<<<NBATCH / 4, 256, 0, stream>>>(x, bucket, basea + 500000,
                                                cnt + 500000, g1, NBATCH);
  k_head<<<NBATCH / 32, 256, 0, stream>>>(g1, alW, alb, g2);
  k_final<<<NBATCH / 4, 256, 0, stream>>>(g2, linW, linb, (float*)d_out);
}

// Round 15
// 610.675 us; speedup vs baseline: 1.5423x; 1.0087x over previous
//
#include <hip/hip_runtime.h>
#include <hip/hip_fp16.h>

#define NA 100000
#define NBATCH 4096
#define NBIN 1971       // 5 maps * 391 atom-ranges + 16 batch-ranges
#define MAPS_BINS 1955  // 5 * 391

typedef _Float16 f16;
typedef f16 half8 __attribute__((ext_vector_type(8)));
typedef f16 half4 __attribute__((ext_vector_type(4)));
typedef float f32x4 __attribute__((ext_vector_type(4)));
union HU { uint4 u; half8 h; f16 s[8]; };

// ---------------- two-level counting sort CSR build (gapped bucket, no scan) ----------
// caps sized for TRUE counts + per-atom pad-to-4 (sentinel edges):
// m0=1792 m1=2304 m2=2816 m3=1536 m4=1536 batch=12500  (all divisible by 4)
__device__ __forceinline__ unsigned capbase_of(int b) {
  if (b < 391)  return 0u       + (unsigned)(b       ) * 1792u;
  if (b < 782)  return 700672u  + (unsigned)(b -  391) * 2304u;
  if (b < 1173) return 1601536u + (unsigned)(b -  782) * 2816u;
  if (b < 1564) return 2702592u + (unsigned)(b - 1173) * 1536u;
  if (b < 1955) return 3303168u + (unsigned)(b - 1564) * 1536u;
  return 3903744u + (unsigned)(b - 1955) * 12500u;
}
// total bucket/pairs slots = 4103744 (~16.4 MB)

struct PassAParams {
  const int* row[6];
  int start[6];
  int total;
};

__global__ __launch_bounds__(256) void k_passA(PassAParams pp, unsigned* ccursor,
                                               unsigned* pairs) {
  __shared__ int hist[NBIN];
  __shared__ unsigned hbase[NBIN];
  int t = threadIdx.x;
  for (int b = t; b < NBIN; b += 256) hist[b] = 0;
  __syncthreads();
  int g0 = blockIdx.x * 8192;
  unsigned keys[32];
#pragma unroll
  for (int i = 0; i < 32; i++) {
    int g = g0 + i * 256 + t;
    keys[i] = 0xFFFFFFFFu;
    if (g < pp.total) {
      int m = 0;
#pragma unroll
      for (int j = 1; j < 6; j++) if (g >= pp.start[j]) m = j;
      int e = g - pp.start[m];
      int a = pp.row[m][e];
      int bin = (m < 5) ? m * 391 + (a >> 8) : MAPS_BINS + (a >> 8);
      keys[i] = ((unsigned)bin << 8) | (unsigned)(a & 255);
      atomicAdd(&hist[bin], 1);
    }
  }
  __syncthreads();
  for (int b = t; b < NBIN; b += 256) {
    int h = hist[b];
    hbase[b] = h ? atomicAdd(&ccursor[b], (unsigned)h) : 0u;
  }
  __syncthreads();
#pragma unroll
  for (int i = 0; i < 32; i++) {
    unsigned kv = keys[i];
    if (kv == 0xFFFFFFFFu) continue;
    int bin = (int)(kv >> 8);
    int g = g0 + i * 256 + t;
    int m = 0;
#pragma unroll
    for (int j = 1; j < 6; j++) if (g >= pp.start[j]) m = j;
    int e = g - pp.start[m];
    unsigned pos = atomicAdd(&hbase[bin], 1u);
    pairs[pos] = ((unsigned)e << 8) | (kv & 255u);
  }
}

__global__ __launch_bounds__(256) void k_passB(const unsigned* ccursor,
                                               const unsigned* pairs, int* bucket,
                                               int* cnt, int* basea) {
  __shared__ int hist[256];
  __shared__ int scn[256];
  __shared__ unsigned cur[256];
  int b = blockIdx.x;
  int t = threadIdx.x;
  unsigned cb0 = capbase_of(b);
  int count = (int)(ccursor[b] - cb0);
  const unsigned* src = pairs + cb0;
  hist[t] = 0;
  __syncthreads();
  for (int i = t; i < count; i += 256) atomicAdd(&hist[src[i] & 255u], 1);
  __syncthreads();
  int h = hist[t];
  bool isMap = (b < MAPS_BINS);
  int hp = (h + 3) & ~3;   // pad ALL lists to multiple of 4 (4-aligned bases)
  scn[t] = hp;
  __syncthreads();
  for (int d = 1; d < 256; d <<= 1) {
    int x = (t >= d) ? scn[t - d] : 0;
    __syncthreads();
    scn[t] += x;
    __syncthreads();
  }
  int excl = scn[t] - hp;
  unsigned base = cb0 + (unsigned)excl;
  int m, a0, off, amax;
  if (isMap) { m = b / 391; a0 = (b - m * 391) << 8; off = m * 100000; amax = 100000; }
  else { m = 5; a0 = (b - MAPS_BINS) << 8; off = 500000; amax = NBATCH; }
  if (a0 + t < amax) {
    cnt[off + a0 + t] = h;               // TRUE count (mean divisor)
    basea[off + a0 + t] = (int)base;     // padded-prefix base (4-aligned)
  }
  cur[t] = base;
  __syncthreads();
  for (int i = t; i < count; i += 256) {
    unsigned v = src[i];
    unsigned pos = atomicAdd(&cur[v & 255u], 1u);
    bucket[pos] = (int)(v >> 8);
  }
  // sentinel pads (disjoint slots; sentinel rows are zeroed in k_prep)
  if (h > 0) {
    static const int EmS[5] = {300000, 400000, 500000, 200000, 240000};
    int sent = isMap ? EmS[m] : NA;      // batch sentinel -> zeroed x[NA] row
    for (int j = h; j < hp; j++) bucket[base + j] = sent;
  }
}

// ---------------- merged prep kernel: atom_init + prepB + prepW + prepT + initc --------

struct PrepParams {
  const int* xa; const float *e0; const float *e1; const float *e2; f16* x;
  const float *pK; const float *cK; f16* Bp;
  const float *pW; const float *cW; const float *pWa; const float *cWa; f16* Wp;
  const float *path_emb; const float *cycle_emb; f16* T;
  unsigned* ccursor;
  f16* xpz[5];
};

__global__ __launch_bounds__(256) void k_prep(PrepParams q) {
  int bid = blockIdx.x, t = threadIdx.x;
  if (bid < 6250) {
    int idx = bid * 256 + t;
    int a = idx >> 4, qq = idx & 15;
    int f0 = q.xa[a * 3], f1 = q.xa[a * 3 + 1], f2 = q.xa[a * 3 + 2];
    float4 v0 = ((const float4*)q.e0)[f0 * 16 + qq];
    float4 v1 = ((const float4*)q.e1)[f1 * 16 + qq];
    float4 v2 = ((const float4*)q.e2)[f2 * 16 + qq];
    half4 h = {(f16)(v0.x + v1.x + v2.x), (f16)(v0.y + v1.y + v2.y),
               (f16)(v0.z + v1.z + v2.z), (f16)(v0.w + v1.w + v2.w)};
    ((half4*)q.x)[idx] = h;
  } else if (bid < 6730) {
    int tid = (bid - 6250) * 256 + t;
    int set = tid / 12288, pos = tid % 12288;
    int j = pos & 7, lane = (pos >> 3) & 63, kcnt = pos >> 9;
    int kc = kcnt % 6, nt = kcnt / 6;
    int k = kc * 32 + ((lane >> 4) << 3) + j;
    int n = (nt << 4) + (lane & 15);
    int w = k >> 6, ji = k & 63;
    const float* K = (set < 6) ? (q.pK + set * 3 * 4096) : (q.cK + (set - 6) * 3 * 4096);
    float v = K[w * 4096 + ji * 64 + n];
    if (set >= 6) v = 0.5f * (v + K[(2 - w) * 4096 + ji * 64 + n]);
    q.Bp[tid] = (f16)v;
  } else if (bid < 7050) {
    int tid = (bid - 6730) * 256 + t;
    int set = tid >> 12, pos = tid & 4095;
    int j = pos & 7, lane = (pos >> 3) & 63, ntkc = pos >> 9;
    int kc = ntkc & 1, nt = ntkc >> 1;
    int k = kc * 32 + ((lane >> 4) << 3) + j;
    int n = (nt << 4) + (lane & 15);
    const float* W;
    if (set < 6) W = q.pW + set * 4096;
    else if (set < 10) W = q.cW + (set - 6) * 4096;
    else if (set < 16) W = q.pWa + (set - 10) * 4096;
    else W = q.cWa + (set - 16) * 4096;
    q.Wp[tid] = (f16)W[k * 64 + n];
  } else {
    int idx = (bid - 7050) * 256 + t;
    if (idx < 1664) {
      float v = (idx < 1152) ? q.path_emb[idx] : q.cycle_emb[idx - 1152];
      q.T[idx] = (f16)v;
    }
    if (idx < NBIN) q.ccursor[idx] = capbase_of(idx);
    if (idx >= 2048 && idx < 2088) {
      static const int EmS[5] = {300000, 400000, 500000, 200000, 240000};
      int s = idx - 2048, m = s >> 3, c = s & 7;
      uint4 z; z.x = z.y = z.z = z.w = 0;
      ((uint4*)(q.xpz[m] + (size_t)EmS[m] * 64))[c] = z;  // zero xp sentinel rows
    }
    if (idx >= 2088 && idx < 2096) {
      uint4 z; z.x = z.y = z.z = z.w = 0;
      ((uint4*)(q.x + (size_t)NA * 64))[idx - 2088] = z;  // zero x sentinel row
    }
  }
}

// ---------------- fused a2p+conv (swapped-operand MFMA) ----------------
// R14-measured body: ridx staged in LDS, gather after barrier, spill-free
// uniform fast paths (n8=768/640), bias via acc init, pk-f16 epilogue RMW.

struct FusedParams {
  const f16* xh;
  const int* gidx[3];
  const int* vals[3];
  const f16* tab[3];
  __half* xp[3];
  const f16* Wa[3];
  const float* ba[3];
  const f16* Bp[3];
  const float* Kb[3];
  int k[3];
  int P[3];
  int ppb[3];
  int blk_start[3];
  int nseg;
  int cyclic;
  int use_tab;
};

__global__ __launch_bounds__(256) void k_fused(FusedParams p) {
  __shared__ uint4 xn4[873];     // 97 rows x 9 uint4 (72 f16/row, row 96 = zero pad)
  __shared__ float bl[64], kbl[64];
  __shared__ int ridx[96];
  __shared__ short prevs[96], nexts[96];
  int bid = blockIdx.x;
  int seg = 0;
#pragma unroll
  for (int i = 1; i < 3; i++) if (i < p.nseg && bid >= p.blk_start[i]) seg = i;
  int kk = p.k[seg], ppb = p.ppb[seg], P = p.P[seg];
  int cyc = p.cyclic;
  int t = threadIdx.x;
  int p0 = (bid - p.blk_start[seg]) * ppb;
  int np = min(ppb, P - p0);
  int R = np * kk;    // always a multiple of 16 for these ppb choices
  int mtb = R >> 4;
  long ebase = (long)p0 * kk;
  if (t < 64) { bl[t] = p.ba[seg][t]; kbl[t] = p.Kb[seg][t]; }
  if (t < 9) { uint4 z; z.x = z.y = z.z = z.w = 0; xn4[96 * 9 + t] = z; }
  if (t < R) ridx[t] = p.gidx[seg][ebase + t];
  if (t < 96) {
    int sm = t % kk;
    prevs[t] = (short)((sm >= 1) ? t - 1 : (cyc ? t + kk - 1 : 96));
    nexts[t] = (short)((sm + 1 < kk) ? t + 1 : (cyc ? t + 1 - kk : 96));
  }
  uint4* xg = (uint4*)(p.xp[seg] + (long)ebase * 64);
  int n8 = R * 8;   // 768 (R=96) or 640 (R=80) for full blocks
  int ch = t & 7;
  // residual prefetch into xn4 (named scalars; uniform fast paths = no scratch)
  if (p.use_tab) {
    const uint4* tabu = (const uint4*)p.tab[seg];
    const int* vseg = p.vals[seg];
    if (n8 == 768) {
      int v0 = vseg[ebase + (t >> 3)];
      int v1 = vseg[ebase + ((t + 256) >> 3)];
      int v2 = vseg[ebase + ((t + 512) >> 3)];
      uint4 a0 = tabu[v0 * 8 + ch];
      uint4 a1 = tabu[v1 * 8 + ch];
      uint4 a2 = tabu[v2 * 8 + ch];
      xn4[(t >> 3) * 9 + ch] = a0;
      xn4[((t + 256) >> 3) * 9 + ch] = a1;
      xn4[((t + 512) >> 3) * 9 + ch] = a2;
    } else if (n8 == 640) {
      int v0 = vseg[ebase + (t >> 3)];
      int v1 = vseg[ebase + ((t + 256) >> 3)];
      uint4 a0 = tabu[v0 * 8 + ch];
      uint4 a1 = tabu[v1 * 8 + ch];
      xn4[(t >> 3) * 9 + ch] = a0;
      xn4[((t + 256) >> 3) * 9 + ch] = a1;
      if (t < 128) {
        int v2 = vseg[ebase + ((t + 512) >> 3)];
        uint4 a2 = tabu[v2 * 8 + ch];
        xn4[((t + 512) >> 3) * 9 + ch] = a2;
      }
    } else {
      for (int idx = t; idx < n8; idx += 256) {
        int row = idx >> 3;
        xn4[row * 9 + ch] = tabu[vseg[ebase + row] * 8 + ch];
      }
    }
  } else {
    if (n8 == 768) {
      uint4 a0 = xg[t];
      uint4 a1 = xg[t + 256];
      uint4 a2 = xg[t + 512];
      xn4[(t >> 3) * 9 + ch] = a0;
      xn4[((t + 256) >> 3) * 9 + ch] = a1;
      xn4[((t + 512) >> 3) * 9 + ch] = a2;
    } else if (n8 == 640) {
      uint4 a0 = xg[t];
      uint4 a1 = xg[t + 256];
      xn4[(t >> 3) * 9 + ch] = a0;
      xn4[((t + 256) >> 3) * 9 + ch] = a1;
      if (t < 128) {
        uint4 a2 = xg[t + 512];
        xn4[((t + 512) >> 3) * 9 + ch] = a2;
      }
    } else {
      for (int idx = t; idx < n8; idx += 256)
        xn4[(idx >> 3) * 9 + ch] = xg[idx];
    }
  }
  __syncthreads();
  int lane = t & 63, wid = t >> 6;
  int wave_n = wid & 1, wave_m = wid >> 1;
  int mtA = (mtb + 1) >> 1;
  int m0 = wave_m ? mtA : 0;
  int mcnt = wave_m ? (mtb - mtA) : mtA;
  f16* xnh = (f16*)xn4;
  int chq0 = wave_n * 32 + ((lane >> 4) << 2);   // jn=0 channel quad
  int chq1 = chq0 + 16;                           // jn=1 channel quad
  // stage A: xn += relu(x_gather @ Wa + ba)  (bias via acc init; pk-f16 residual add)
  {
    f32x4 b0 = {bl[chq0], bl[chq0 + 1], bl[chq0 + 2], bl[chq0 + 3]};
    f32x4 b1 = {bl[chq1], bl[chq1 + 1], bl[chq1 + 2], bl[chq1 + 3]};
    f32x4 acc1[3][2];
#pragma unroll
    for (int i = 0; i < 3; i++) { acc1[i][0] = b0; acc1[i][1] = b1; }
    const uint4* Wau = (const uint4*)p.Wa[seg];
    HU w[2][2];
#pragma unroll
    for (int kc = 0; kc < 2; kc++)
#pragma unroll
      for (int jn = 0; jn < 2; jn++)
        w[kc][jn].u = Wau[(((wave_n * 2 + jn) << 1) + kc) * 64 + lane];
    const uint4* xh4 = (const uint4*)p.xh;
#pragma unroll
    for (int i = 0; i < 3; i++) {
      if (i >= mcnt) continue;
      int rowid = ridx[((m0 + i) << 4) + (lane & 15)];
      HU xa, xb;
      xa.u = xh4[(long)rowid * 8 + (lane >> 4)];
      xb.u = xh4[(long)rowid * 8 + 4 + (lane >> 4)];
#pragma unroll
      for (int jn = 0; jn < 2; jn++) {
        acc1[i][jn] = __builtin_amdgcn_mfma_f32_16x16x32_f16(w[0][jn].h, xa.h, acc1[i][jn], 0, 0, 0);
        acc1[i][jn] = __builtin_amdgcn_mfma_f32_16x16x32_f16(w[1][jn].h, xb.h, acc1[i][jn], 0, 0, 0);
      }
    }
#pragma unroll
    for (int i = 0; i < 3; i++) {
      if (i >= mcnt) continue;
      int r = ((m0 + i) << 4) + (lane & 15);
#pragma unroll
      for (int jn = 0; jn < 2; jn++) {
        int chq = jn ? chq1 : chq0;
        half4 cv;
#pragma unroll
        for (int reg = 0; reg < 4; reg++) {
          float v = acc1[i][jn][reg];
          cv[reg] = (f16)(v > 0.f ? v : 0.f);
        }
        half4* pxl = (half4*)(xnh + r * 72 + chq);
        *pxl = *pxl + cv;   // v_pk_add_f16 x2
      }
    }
  }
  __syncthreads();
  // conv MFMAs reading xn4 (neighbor rows via LDS tables); bias via acc init
  f32x4 k0 = {kbl[chq0], kbl[chq0 + 1], kbl[chq0 + 2], kbl[chq0 + 3]};
  f32x4 k1 = {kbl[chq1], kbl[chq1 + 1], kbl[chq1 + 2], kbl[chq1 + 3]};
  f32x4 acc2[3][2];
#pragma unroll
  for (int i = 0; i < 3; i++) { acc2[i][0] = k0; acc2[i][1] = k1; }
  int rdw[3][3];
#pragma unroll
  for (int i = 0; i < 3; i++) {
    if (i >= mcnt) continue;
    int mr = ((m0 + i) << 4) + (lane & 15);
    rdw[i][0] = prevs[mr];
    rdw[i][1] = mr;
    rdw[i][2] = nexts[mr];
  }
  const uint4* Bg = (const uint4*)p.Bp[seg];
  for (int kc = 0; kc < 6; kc++) {
    int w_ = kc >> 1;
    int chunk = ((kc & 1) << 2) + (lane >> 4);
    HU ak[2], xv[3];
#pragma unroll
    for (int jn = 0; jn < 2; jn++)
      ak[jn].u = Bg[((wave_n * 2 + jn) * 6 + kc) * 64 + lane];
#pragma unroll
    for (int i = 0; i < 3; i++)
      if (i < mcnt) xv[i].u = xn4[rdw[i][w_] * 9 + chunk];
#pragma unroll
    for (int i = 0; i < 3; i++)
      if (i < mcnt) {
#pragma unroll
        for (int jn = 0; jn < 2; jn++)
          acc2[i][jn] = __builtin_amdgcn_mfma_f32_16x16x32_f16(ak[jn].h, xv[i].h, acc2[i][jn], 0, 0, 0);
      }
  }
  __syncthreads();  // conv reads of xn4 complete before overwrite
  // epilogue 2: final = xn + relu(conv + Kb), pk-f16 RMW in LDS
#pragma unroll
  for (int i = 0; i < 3; i++) {
    if (i >= mcnt) continue;
    int r = ((m0 + i) << 4) + (lane & 15);
#pragma unroll
    for (int jn = 0; jn < 2; jn++) {
      int chq = jn ? chq1 : chq0;
      half4 cv;
#pragma unroll
      for (int reg = 0; reg < 4; reg++) {
        float v = acc2[i][jn][reg];
        cv[reg] = (f16)(v > 0.f ? v : 0.f);
      }
      half4* pxl = (half4*)(xnh + r * 72 + chq);
      *pxl = *pxl + cv;
    }
  }
  __syncthreads();
  // coalesced copy-out (named scalars; uniform fast paths)
  if (n8 == 768) {
    uint4 c0 = xn4[(t >> 3) * 9 + ch];
    uint4 c1 = xn4[((t + 256) >> 3) * 9 + ch];
    uint4 c2 = xn4[((t + 512) >> 3) * 9 + ch];
    xg[t] = c0;
    xg[t + 256] = c1;
    xg[t + 512] = c2;
  } else if (n8 == 640) {
    uint4 c0 = xn4[(t >> 3) * 9 + ch];
    uint4 c1 = xn4[((t + 256) >> 3) * 9 + ch];
    xg[t] = c0;
    xg[t + 256] = c1;
    if (t < 128) {
      uint4 c2 = xn4[((t + 512) >> 3) * 9 + ch];
      xg[t + 512] = c2;
    }
  } else {
    for (int idx = t; idx < n8; idx += 256)
      xg[idx] = xn4[(idx >> 3) * 9 + ch];
  }
}

// ---------------- p2a apply: CSR gather (padded lists, int4 bucket loads) ------------
// Af[2] ping-pong, one barrier/map; gather(next) overlaps MFMA(cur).

struct Apply2Params {
  const f16* xp[3];
  const int* cnt[3];
  const int* basea[3];
  const int* bucket;
  const f16* Wp[3];
  const float* bias[3];
  int nm;
};

__global__ __launch_bounds__(256) void k_apply2(Apply2Params p, f16* x) {
  __shared__ uint4 Af[2][512];
  __shared__ float bl[3][64];
  __shared__ f16 xf[64 * 72];   // 64 atoms x 64 cols, padded stride 72
  int t = threadIdx.x;
  int a0 = blockIdx.x * 64;
  int lane = t & 63, wid = t >> 6;
  int al = t >> 2, q = t & 3;
  int atom = a0 + al;
  int nm = p.nm;
  if (t < 64 * nm) bl[t >> 6][t & 63] = p.bias[t >> 6][t & 63];
  f32x4 addv[4];
#pragma unroll
  for (int nt = 0; nt < 4; nt++) { f32x4 z = {0.f, 0.f, 0.f, 0.f}; addv[nt] = z; }
  float s[16];
  auto gather = [&](int mi) {
#pragma unroll
    for (int i = 0; i < 16; i++) s[i] = 0.f;
    int cb = 0, base = 0;
    if (atom < NA) { cb = p.cnt[mi][atom]; base = p.basea[mi][atom]; }
    const uint4* xpu = (const uint4*)p.xp[mi];
    // lists padded to multiple of 4 with sentinel (zero-row) edges; base 16B-aligned
    for (int i = 0; i < cb; i += 4) {
      int4 e4 = *(const int4*)(p.bucket + base + i);
      HU va0, vb0, va1, vb1, va2, vb2, va3, vb3;
      va0.u = xpu[(long)e4.x * 8 + q * 2]; vb0.u = xpu[(long)e4.x * 8 + q * 2 + 1];
      va1.u = xpu[(long)e4.y * 8 + q * 2]; vb1.u = xpu[(long)e4.y * 8 + q * 2 + 1];
      va2.u = xpu[(long)e4.z * 8 + q * 2]; vb2.u = xpu[(long)e4.z * 8 + q * 2 + 1];
      va3.u = xpu[(long)e4.w * 8 + q * 2]; vb3.u = xpu[(long)e4.w * 8 + q * 2 + 1];
#pragma unroll
      for (int j = 0; j < 8; j++) {
        s[j] += ((float)va0.s[j] + (float)va1.s[j]) + ((float)va2.s[j] + (float)va3.s[j]);
        s[8 + j] += ((float)vb0.s[j] + (float)vb1.s[j]) + ((float)vb2.s[j] + (float)vb3.s[j]);
      }
    }
  };
  gather(0);
  int jb = ((al >> 4) * 2 + (q >> 1)) * 64 + (q & 1) * 32 + (al & 15);
  for (int mi = 0; mi < nm; mi++) {
    int cur = mi & 1;
    int cbi = (atom < NA) ? p.cnt[mi][atom] : 0;
    float inv = 1.f / (float)(cbi > 0 ? cbi : 1);
    HU o0, o1;
#pragma unroll
    for (int j = 0; j < 8; j++) { o0.s[j] = (f16)(s[j] * inv); o1.s[j] = (f16)(s[8 + j] * inv); }
    Af[cur][jb] = o0.u;
    Af[cur][jb + 16] = o1.u;
    __syncthreads();
    HU af0, af1;
    af0.u = Af[cur][((wid << 1) + 0) * 64 + lane];
    af1.u = Af[cur][((wid << 1) + 1) * 64 + lane];
    const uint4* Wu = (const uint4*)p.Wp[mi];
#pragma unroll
    for (int nt = 0; nt < 4; nt++) {
      HU b0, b1;
      b0.u = Wu[((nt << 1) + 0) * 64 + lane];
      b1.u = Wu[((nt << 1) + 1) * 64 + lane];
      float bv = bl[mi][nt * 16 + (lane & 15)];
      f32x4 z = {bv, bv, bv, bv};
      z = __builtin_amdgcn_mfma_f32_16x16x32_f16(af0.h, b0.h, z, 0, 0, 0);
      z = __builtin_amdgcn_mfma_f32_16x16x32_f16(af1.h, b1.h, z, 0, 0, 0);
#pragma unroll
      for (int r = 0; r < 4; r++) {
        float vv = z[r];
        addv[nt][r] += vv > 0.f ? vv : 0.f;
      }
    }
    if (mi + 1 < nm) gather(mi + 1);   // overlaps this map's MFMA/epilogue latency
  }
  // stash addv to LDS (owner-lane scalar writes), then vector RMW of x
  int arow_w = (wid << 4) + ((lane >> 4) << 2);
#pragma unroll
  for (int nt = 0; nt < 4; nt++) {
    int n = nt * 16 + (lane & 15);
#pragma unroll
    for (int r = 0; r < 4; r++)
      xf[(arow_w + r) * 72 + n] = (f16)addv[nt][r];
  }
  __syncthreads();
#pragma unroll
  for (int u = 0; u < 2; u++) {
    int idx = t + 256 * u;
    int arow = idx >> 3, ch8 = idx & 7;
    int atomw = a0 + arow;
    if (atomw < NA) {
      uint4* px = (uint4*)(x + (long)atomw * 64 + ch8 * 8);
      HU old; old.u = *px;
      HU ad; ad.h = *(half8*)(xf + arow * 72 + ch8 * 8);
      HU o; o.h = old.h + ad.h;   // v_pk_add_f16 x4
      *px = o.u;
    }
  }
}

// ---------------- batch mean over f16 x (padded lists: quad gather, no tail) ----------

__global__ __launch_bounds__(256) void k_meanscatter(const f16* src, const int* bucket,
                                                     const int* basea, const int* cnta,
                                                     float* dst, int nseg) {
  int wid = (blockIdx.x * 256 + threadIdx.x) >> 6;
  int lane = threadIdx.x & 63;
  if (wid >= nseg) return;
  int b0 = basea[wid], cnt = cnta[wid];
  float s = 0.f;
  // list padded to multiple of 4 with sentinel atom NA (zeroed x row); b0 16B-aligned
  for (int i = 0; i < cnt; i += 4) {
    int4 e4 = *(const int4*)(bucket + b0 + i);
    float s0 = (float)src[(long)e4.x * 64 + lane];
    float s1 = (float)src[(long)e4.y * 64 + lane];
    float s2 = (float)src[(long)e4.z * 64 + lane];
    float s3 = (float)src[(long)e4.w * 64 + lane];
    s += (s0 + s1) + (s2 + s3);
  }
  dst[(long)wid * 64 + lane] = s / (float)(cnt > 0 ? cnt : 1);
}

// ---------------- head gemm ----------------

__global__ __launch_bounds__(256) void k_head(const float* g1, const float* W,
                                              const float* bias, float* g2) {
  __shared__ float Wl[4096];
  __shared__ float inl[32 * 64];
  __shared__ float bl[64];
  int t = threadIdx.x;
  int brow = blockIdx.x * 32;
#pragma unroll
  for (int i = 0; i < 4; i++) ((float4*)Wl)[t + 256 * i] = ((const float4*)W)[t + 256 * i];
  if (t < 64) bl[t] = bias[t];
  __syncthreads();
#pragma unroll
  for (int i = 0; i < 2; i++) {
    int idx = t + 256 * i;
    int r = idx >> 4, q = idx & 15;
    ((float4*)inl)[idx] = ((const float4*)(g1 + (long)(brow + r) * 64))[q];
  }
  __syncthreads();
  int c = t & 63, rq = t >> 6;
  float acc[8];
#pragma unroll
  for (int i = 0; i < 8; i++) acc[i] = 0.f;
  for (int j = 0; j < 64; j += 4) {
    float w0 = Wl[(j + 0) * 64 + c], w1 = Wl[(j + 1) * 64 + c];
    float w2 = Wl[(j + 2) * 64 + c], w3 = Wl[(j + 3) * 64 + c];
#pragma unroll
    for (int i = 0; i < 8; i++) {
      int r = rq * 8 + i;
      float4 v = *(const float4*)&inl[r * 64 + j];
      acc[i] += v.x * w0 + v.y * w1 + v.z * w2 + v.w * w3;
    }
  }
#pragma unroll
  for (int i = 0; i < 8; i++) {
    long r = brow + rq * 8 + i;
    float v = acc[i] + bl[c];
    g2[r * 64 + c] = v > 0.f ? v : 0.f;
  }
}

__global__ __launch_bounds__(256) void k_final(const float* g2, const float* linW,
                                               const float* linb, float* out) {
  int wid = (blockIdx.x * 256 + threadIdx.x) >> 6;
  int lane = threadIdx.x & 63;
  if (wid >= NBATCH) return;
  float v = g2[(long)wid * 64 + lane] * linW[lane];
  for (int o = 32; o > 0; o >>= 1) v += __shfl_down(v, o, 64);
  if (lane == 0) out[wid] = v + linb[0];
}

__global__ __launch_bounds__(256) void k_zero_out(float* out, int n) {
  for (int i = blockIdx.x * 256 + threadIdx.x; i < n; i += gridDim.x * 256) out[i] = 0.f;
}

// ---------------- launcher ----------------

extern "C" void kernel_launch(void* const* d_in, const int* in_sizes, int n_in,
                              void* d_out, int out_size, void* d_ws, size_t ws_size,
                              hipStream_t stream) {
  (void)in_sizes; (void)n_in;

  const int* x_atom = (const int*)d_in[0];
  const int* vals[5] = {(const int*)d_in[1], (const int*)d_in[4], (const int*)d_in[7],
                        (const int*)d_in[10], (const int*)d_in[13]};
  const int* rowm[5] = {(const int*)d_in[2], (const int*)d_in[5], (const int*)d_in[8],
                        (const int*)d_in[11], (const int*)d_in[14]};
  const int* batch = (const int*)d_in[16];
  const float* aemb0 = (const float*)d_in[17];
  const float* aemb1 = (const float*)d_in[18];
  const float* aemb2 = (const float*)d_in[19];
  const float* path_emb = (const float*)d_in[20];
  const float* cycle_emb = (const float*)d_in[21];
  const float* pW_a2p = (const float*)d_in[22];
  const float* pb_a2p = (const float*)d_in[23];
  const float* pW_p2a = (const float*)d_in[24];
  const float* pb_p2a = (const float*)d_in[25];
  const float* pK = (const float*)d_in[26];
  const float* pKb = (const float*)d_in[27];
  const float* cW_a2p = (const float*)d_in[28];
  const float* cb_a2p = (const float*)d_in[29];
  const float* cW_p2a = (const float*)d_in[30];
  const float* cb_p2a = (const float*)d_in[31];
  const float* cK = (const float*)d_in[32];
  const float* cKb = (const float*)d_in[33];
  const float* alW = (const float*)d_in[34];
  const float* alb = (const float*)d_in[35];
  const float* linW = (const float*)d_in[36];
  const float* linb = (const float*)d_in[37];

  static const int Em[5] = {300000, 400000, 500000, 200000, 240000};
  static const int Km[5] = {3, 4, 5, 5, 6};
  static const int Ppb[5] = {32, 24, 16, 16, 16};
  const int CNT_N = 5 * 100000 + NBATCH;  // 504096
  const int BUCKET_N = 4103744;           // gapped + pad slack (capbase layout)

  char* ws = (char*)d_ws;
  size_t off = 0;
  auto alloc = [&](size_t nbytes) -> char* {
    char* p = ws + off;
    off = (off + nbytes + 255) & ~(size_t)255;
    return p;
  };
  f16* x = (f16*)alloc(((size_t)NA + 8) * 64 * 2);   // f16 master (+ zero sentinel row)
  __half* xp[5];
  for (int m = 0; m < 5; m++) xp[m] = (__half*)alloc(((size_t)Em[m] + 8) * 64 * 2);
  float* g1 = (float*)alloc((size_t)NBATCH * 64 * 4);
  float* g2 = (float*)alloc((size_t)NBATCH * 64 * 4);
  int* cnt = (int*)alloc((size_t)CNT_N * 4);
  int* basea = (int*)alloc((size_t)CNT_N * 4);
  int* bucket = (int*)alloc((size_t)BUCKET_N * 4);
  unsigned* ccursor = (unsigned*)alloc((size_t)NBIN * 4);
  f16* Bp = (f16*)alloc((size_t)10 * 12288 * 2);
  f16* Wpk = (f16*)alloc((size_t)20 * 4096 * 2);
  f16* Tabs = (f16*)alloc((size_t)1664 * 2);
  // pairs array (~16.4 MB) aliases xp[2]: consumed by k_passB before k_fused writes
  // xp[2]; sentinel row at xp[2]+64MB is beyond the pairs region.
  unsigned* pairs = (unsigned*)xp[2];

  if (ws_size < off) {
    k_zero_out<<<16, 256, 0, stream>>>((float*)d_out, out_size);
    return;
  }

  // ---- merged prep (atom_init + prepB + prepW + prepT + initc + sentinel zeroing)
  {
    PrepParams q;
    q.xa = x_atom; q.e0 = aemb0; q.e1 = aemb1; q.e2 = aemb2; q.x = x;
    q.pK = pK; q.cK = cK; q.Bp = Bp;
    q.pW = pW_p2a; q.cW = cW_p2a; q.pWa = pW_a2p; q.cWa = cW_a2p; q.Wp = Wpk;
    q.path_emb = path_emb; q.cycle_emb = cycle_emb; q.T = Tabs;
    q.ccursor = ccursor;
    for (int m = 0; m < 5; m++) q.xpz[m] = (f16*)xp[m];
    k_prep<<<7059, 256, 0, stream>>>(q);
  }

  // ---- CSR build: two-level counting sort (no scan; gapped + padded bucket)
  PassAParams pp;
  {
    int s = 0;
    for (int m = 0; m < 5; m++) { pp.row[m] = rowm[m]; pp.start[m] = s; s += Em[m]; }
    pp.row[5] = batch; pp.start[5] = s;
    pp.total = s + NA;  // 1740000
  }
  k_passA<<<(1740000 + 8191) / 8192, 256, 0, stream>>>(pp, ccursor, pairs);
  k_passB<<<NBIN, 256, 0, stream>>>(ccursor, pairs, bucket, cnt, basea);

  int apply_blocks = (NA + 63) / 64;  // 1563

  auto p2aW = [&](int l, int m) -> const f16* {
    return (m < 3) ? Wpk + (size_t)(l * 3 + m) * 4096
                   : Wpk + (size_t)(6 + l * 2 + (m - 3)) * 4096;
  };
  auto p2aB = [&](int l, int m) -> const float* {
    return (m < 3) ? pb_p2a + (l * 3 + m) * 64 : cb_p2a + (l * 2 + (m - 3)) * 64;
  };

  for (int l = 0; l < 2; l++) {
    // === paths group (maps 0..2), non-cyclic
    {
      FusedParams fp{};
      fp.nseg = 3; fp.cyclic = 0; fp.xh = x; fp.use_tab = (l == 0) ? 1 : 0;
      int bs = 0;
      for (int m = 0; m < 3; m++) {
        fp.gidx[m] = rowm[m]; fp.xp[m] = xp[m];
        fp.vals[m] = vals[m]; fp.tab[m] = Tabs + (size_t)m * 384;
        fp.Wa[m] = Wpk + (size_t)(10 + l * 3 + m) * 4096;
        fp.ba[m] = pb_a2p + (l * 3 + m) * 64;
        fp.Bp[m] = Bp + (size_t)(l * 3 + m) * 12288;
        fp.Kb[m] = pKb + (l * 3 + m) * 64;
        fp.k[m] = Km[m]; fp.P[m] = Em[m] / Km[m]; fp.ppb[m] = Ppb[m];
        fp.blk_start[m] = bs;
        bs += (fp.P[m] + fp.ppb[m] - 1) / fp.ppb[m];
      }
      k_fused<<<bs, 256, 0, stream>>>(fp);

      Apply2Params ap{};
      ap.nm = 3; ap.bucket = bucket;
      for (int m = 0; m < 3; m++) {
        ap.xp[m] = (const f16*)xp[m];
        ap.cnt[m] = cnt + (size_t)m * 100000;
        ap.basea[m] = basea + (size_t)m * 100000;
        ap.Wp[m] = p2aW(l, m); ap.bias[m] = p2aB(l, m);
      }
      k_apply2<<<apply_blocks, 256, 0, stream>>>(ap, x);
    }
    // === cycles group (maps 3..4), cyclic
    {
      FusedParams fp{};
      fp.nseg = 2; fp.cyclic = 1; fp.xh = x; fp.use_tab = (l == 0) ? 1 : 0;
      int bs = 0;
      for (int m = 3; m < 5; m++) {
        int i = m - 3;
        fp.gidx[i] = rowm[m]; fp.xp[i] = xp[m];
        fp.vals[i] = vals[m]; fp.tab[i] = Tabs + 1152 + (size_t)i * 256;
        fp.Wa[i] = Wpk + (size_t)(16 + l * 2 + i) * 4096;
        fp.ba[i] = cb_a2p + (l * 2 + i) * 64;
        fp.Bp[i] = Bp + (size_t)(6 + l * 2 + i) * 12288;
        fp.Kb[i] = cKb + (l * 2 + i) * 64;
        fp.k[i] = Km[m]; fp.P[i] = Em[m] / Km[m]; fp.ppb[i] = Ppb[m];
        fp.blk_start[i] = bs;
        bs += (fp.P[i] + fp.ppb[i] - 1) / fp.ppb[i];
      }
      k_fused<<<bs, 256, 0, stream>>>(fp);

      Apply2Params ap{};
      ap.nm = 2; ap.bucket = bucket;
      for (int m = 3; m < 5; m++) {
        int i = m - 3;
        ap.xp[i] = (const f16*)xp[m];
        ap.cnt[i] = cnt + (size_t)m * 100000;
        ap.basea[i] = basea + (size_t)m * 100000;
        ap.Wp[i] = p2aW(l, m); ap.bias[i] = p2aB(l, m);
      }
      k_apply2<<<apply_blocks, 256, 0, stream>>>(ap, x);
    }
  }

  // ---- head (basea entries for the batch segment are GLOBAL bucket positions)
  k_meanscatter<<<NBATCH / 4, 256, 0, stream>>>(x, bucket, basea + 500000,
                                                cnt + 500000, g1, NBATCH);
  k_head<<<NBATCH / 32, 256, 0, stream>>>(g1, alW, alb, g2);
  k_final<<<NBATCH / 4, 256, 0, stream>>>(g2, linW, linb, (float*)d_out);
}

// Round 16
// 608.110 us; speedup vs baseline: 1.5488x; 1.0042x over previous
//
#include <hip/hip_runtime.h>
#include <hip/hip_fp16.h>

#define NA 100000
#define NBATCH 4096
#define NBIN 1971       // 5 maps * 391 atom-ranges + 16 batch-ranges
#define MAPS_BINS 1955  // 5 * 391

typedef _Float16 f16;
typedef f16 half8 __attribute__((ext_vector_type(8)));
typedef f16 half4 __attribute__((ext_vector_type(4)));
typedef float f32x4 __attribute__((ext_vector_type(4)));
union HU { uint4 u; half8 h; f16 s[8]; };

// ---------------- two-level counting sort CSR build (gapped bucket, no scan) ----------
// caps sized for TRUE counts + per-atom pad-to-4 (sentinel edges):
// m0=1792 m1=2304 m2=2816 m3=1536 m4=1536 batch=12500  (all divisible by 4)
__device__ __forceinline__ unsigned capbase_of(int b) {
  if (b < 391)  return 0u       + (unsigned)(b       ) * 1792u;
  if (b < 782)  return 700672u  + (unsigned)(b -  391) * 2304u;
  if (b < 1173) return 1601536u + (unsigned)(b -  782) * 2816u;
  if (b < 1564) return 2702592u + (unsigned)(b - 1173) * 1536u;
  if (b < 1955) return 3303168u + (unsigned)(b - 1564) * 1536u;
  return 3903744u + (unsigned)(b - 1955) * 12500u;
}
// total bucket/pairs slots = 4103744 (~16.4 MB)

struct PassAParams {
  const int* row[6];
  int start[6];
  int total;
};

__global__ __launch_bounds__(256) void k_passA(PassAParams pp, unsigned* ccursor,
                                               unsigned* pairs) {
  __shared__ int hist[NBIN];
  __shared__ unsigned hbase[NBIN];
  int t = threadIdx.x;
  for (int b = t; b < NBIN; b += 256) hist[b] = 0;
  __syncthreads();
  int g0 = blockIdx.x * 8192;
  unsigned keys[32];
#pragma unroll
  for (int i = 0; i < 32; i++) {
    int g = g0 + i * 256 + t;
    keys[i] = 0xFFFFFFFFu;
    if (g < pp.total) {
      int m = 0;
#pragma unroll
      for (int j = 1; j < 6; j++) if (g >= pp.start[j]) m = j;
      int e = g - pp.start[m];
      int a = pp.row[m][e];
      int bin = (m < 5) ? m * 391 + (a >> 8) : MAPS_BINS + (a >> 8);
      keys[i] = ((unsigned)bin << 8) | (unsigned)(a & 255);
      atomicAdd(&hist[bin], 1);
    }
  }
  __syncthreads();
  for (int b = t; b < NBIN; b += 256) {
    int h = hist[b];
    hbase[b] = h ? atomicAdd(&ccursor[b], (unsigned)h) : 0u;
  }
  __syncthreads();
#pragma unroll
  for (int i = 0; i < 32; i++) {
    unsigned kv = keys[i];
    if (kv == 0xFFFFFFFFu) continue;
    int bin = (int)(kv >> 8);
    int g = g0 + i * 256 + t;
    int m = 0;
#pragma unroll
    for (int j = 1; j < 6; j++) if (g >= pp.start[j]) m = j;
    int e = g - pp.start[m];
    unsigned pos = atomicAdd(&hbase[bin], 1u);
    pairs[pos] = ((unsigned)e << 8) | (kv & 255u);
  }
}

__global__ __launch_bounds__(256) void k_passB(const unsigned* ccursor,
                                               const unsigned* pairs, int* bucket,
                                               int* cnt, int* basea) {
  __shared__ int hist[256];
  __shared__ int scn[256];
  __shared__ unsigned cur[256];
  int b = blockIdx.x;
  int t = threadIdx.x;
  unsigned cb0 = capbase_of(b);
  int count = (int)(ccursor[b] - cb0);
  const unsigned* src = pairs + cb0;
  hist[t] = 0;
  __syncthreads();
  for (int i = t; i < count; i += 256) atomicAdd(&hist[src[i] & 255u], 1);
  __syncthreads();
  int h = hist[t];
  bool isMap = (b < MAPS_BINS);
  int hp = (h + 3) & ~3;   // pad ALL lists to multiple of 4 (4-aligned bases)
  scn[t] = hp;
  __syncthreads();
  for (int d = 1; d < 256; d <<= 1) {
    int x = (t >= d) ? scn[t - d] : 0;
    __syncthreads();
    scn[t] += x;
    __syncthreads();
  }
  int excl = scn[t] - hp;
  unsigned base = cb0 + (unsigned)excl;
  int m, a0, off, amax;
  if (isMap) { m = b / 391; a0 = (b - m * 391) << 8; off = m * 100000; amax = 100000; }
  else { m = 5; a0 = (b - MAPS_BINS) << 8; off = 500000; amax = NBATCH; }
  if (a0 + t < amax) {
    cnt[off + a0 + t] = h;               // TRUE count (mean divisor)
    basea[off + a0 + t] = (int)base;     // padded-prefix base (4-aligned)
  }
  cur[t] = base;
  __syncthreads();
  for (int i = t; i < count; i += 256) {
    unsigned v = src[i];
    unsigned pos = atomicAdd(&cur[v & 255u], 1u);
    bucket[pos] = (int)(v >> 8);
  }
  // sentinel pads (disjoint slots; sentinel rows are zeroed in k_prep)
  if (h > 0) {
    static const int EmS[5] = {300000, 400000, 500000, 200000, 240000};
    int sent = isMap ? EmS[m] : NA;      // batch sentinel -> zeroed x[NA] row
    for (int j = h; j < hp; j++) bucket[base + j] = sent;
  }
}

// ---------------- merged prep kernel: atom_init + prepB + prepW + prepT + initc --------

struct PrepParams {
  const int* xa; const float *e0; const float *e1; const float *e2; f16* x;
  const float *pK; const float *cK; f16* Bp;
  const float *pW; const float *cW; const float *pWa; const float *cWa; f16* Wp;
  const float *path_emb; const float *cycle_emb; f16* T;
  unsigned* ccursor;
  f16* xpz[5];
};

__global__ __launch_bounds__(256) void k_prep(PrepParams q) {
  int bid = blockIdx.x, t = threadIdx.x;
  if (bid < 6250) {
    int idx = bid * 256 + t;
    int a = idx >> 4, qq = idx & 15;
    int f0 = q.xa[a * 3], f1 = q.xa[a * 3 + 1], f2 = q.xa[a * 3 + 2];
    float4 v0 = ((const float4*)q.e0)[f0 * 16 + qq];
    float4 v1 = ((const float4*)q.e1)[f1 * 16 + qq];
    float4 v2 = ((const float4*)q.e2)[f2 * 16 + qq];
    half4 h = {(f16)(v0.x + v1.x + v2.x), (f16)(v0.y + v1.y + v2.y),
               (f16)(v0.z + v1.z + v2.z), (f16)(v0.w + v1.w + v2.w)};
    ((half4*)q.x)[idx] = h;
  } else if (bid < 6730) {
    int tid = (bid - 6250) * 256 + t;
    int set = tid / 12288, pos = tid % 12288;
    int j = pos & 7, lane = (pos >> 3) & 63, kcnt = pos >> 9;
    int kc = kcnt % 6, nt = kcnt / 6;
    int k = kc * 32 + ((lane >> 4) << 3) + j;
    int n = (nt << 4) + (lane & 15);
    int w = k >> 6, ji = k & 63;
    const float* K = (set < 6) ? (q.pK + set * 3 * 4096) : (q.cK + (set - 6) * 3 * 4096);
    float v = K[w * 4096 + ji * 64 + n];
    if (set >= 6) v = 0.5f * (v + K[(2 - w) * 4096 + ji * 64 + n]);
    q.Bp[tid] = (f16)v;
  } else if (bid < 7050) {
    int tid = (bid - 6730) * 256 + t;
    int set = tid >> 12, pos = tid & 4095;
    int j = pos & 7, lane = (pos >> 3) & 63, ntkc = pos >> 9;
    int kc = ntkc & 1, nt = ntkc >> 1;
    int k = kc * 32 + ((lane >> 4) << 3) + j;
    int n = (nt << 4) + (lane & 15);
    const float* W;
    if (set < 6) W = q.pW + set * 4096;
    else if (set < 10) W = q.cW + (set - 6) * 4096;
    else if (set < 16) W = q.pWa + (set - 10) * 4096;
    else W = q.cWa + (set - 16) * 4096;
    q.Wp[tid] = (f16)W[k * 64 + n];
  } else {
    int idx = (bid - 7050) * 256 + t;
    if (idx < 1664) {
      float v = (idx < 1152) ? q.path_emb[idx] : q.cycle_emb[idx - 1152];
      q.T[idx] = (f16)v;
    }
    if (idx < NBIN) q.ccursor[idx] = capbase_of(idx);
    if (idx >= 2048 && idx < 2088) {
      static const int EmS[5] = {300000, 400000, 500000, 200000, 240000};
      int s = idx - 2048, m = s >> 3, c = s & 7;
      uint4 z; z.x = z.y = z.z = z.w = 0;
      ((uint4*)(q.xpz[m] + (size_t)EmS[m] * 64))[c] = z;  // zero xp sentinel rows
    }
    if (idx >= 2088 && idx < 2096) {
      uint4 z; z.x = z.y = z.z = z.w = 0;
      ((uint4*)(q.x + (size_t)NA * 64))[idx - 2088] = z;  // zero x sentinel row
    }
  }
}

// ---------------- fused a2p+conv (swapped-operand MFMA) ----------------
// R14/R15-measured body + s_setprio(1) around the conv MFMA cluster (T5: co-resident
// blocks at different phases -> scheduler can favor MFMA waves).

struct FusedParams {
  const f16* xh;
  const int* gidx[3];
  const int* vals[3];
  const f16* tab[3];
  __half* xp[3];
  const f16* Wa[3];
  const float* ba[3];
  const f16* Bp[3];
  const float* Kb[3];
  int k[3];
  int P[3];
  int ppb[3];
  int blk_start[3];
  int nseg;
  int cyclic;
  int use_tab;
};

__global__ __launch_bounds__(256) void k_fused(FusedParams p) {
  __shared__ uint4 xn4[873];     // 97 rows x 9 uint4 (72 f16/row, row 96 = zero pad)
  __shared__ float bl[64], kbl[64];
  __shared__ int ridx[96];
  __shared__ short prevs[96], nexts[96];
  int bid = blockIdx.x;
  int seg = 0;
#pragma unroll
  for (int i = 1; i < 3; i++) if (i < p.nseg && bid >= p.blk_start[i]) seg = i;
  int kk = p.k[seg], ppb = p.ppb[seg], P = p.P[seg];
  int cyc = p.cyclic;
  int t = threadIdx.x;
  int p0 = (bid - p.blk_start[seg]) * ppb;
  int np = min(ppb, P - p0);
  int R = np * kk;    // always a multiple of 16 for these ppb choices
  int mtb = R >> 4;
  long ebase = (long)p0 * kk;
  if (t < 64) { bl[t] = p.ba[seg][t]; kbl[t] = p.Kb[seg][t]; }
  if (t < 9) { uint4 z; z.x = z.y = z.z = z.w = 0; xn4[96 * 9 + t] = z; }
  if (t < R) ridx[t] = p.gidx[seg][ebase + t];
  if (t < 96) {
    int sm = t % kk;
    prevs[t] = (short)((sm >= 1) ? t - 1 : (cyc ? t + kk - 1 : 96));
    nexts[t] = (short)((sm + 1 < kk) ? t + 1 : (cyc ? t + 1 - kk : 96));
  }
  uint4* xg = (uint4*)(p.xp[seg] + (long)ebase * 64);
  int n8 = R * 8;   // 768 (R=96) or 640 (R=80) for full blocks
  int ch = t & 7;
  // residual prefetch into xn4 (named scalars; uniform fast paths = no scratch)
  if (p.use_tab) {
    const uint4* tabu = (const uint4*)p.tab[seg];
    const int* vseg = p.vals[seg];
    if (n8 == 768) {
      int v0 = vseg[ebase + (t >> 3)];
      int v1 = vseg[ebase + ((t + 256) >> 3)];
      int v2 = vseg[ebase + ((t + 512) >> 3)];
      uint4 a0 = tabu[v0 * 8 + ch];
      uint4 a1 = tabu[v1 * 8 + ch];
      uint4 a2 = tabu[v2 * 8 + ch];
      xn4[(t >> 3) * 9 + ch] = a0;
      xn4[((t + 256) >> 3) * 9 + ch] = a1;
      xn4[((t + 512) >> 3) * 9 + ch] = a2;
    } else if (n8 == 640) {
      int v0 = vseg[ebase + (t >> 3)];
      int v1 = vseg[ebase + ((t + 256) >> 3)];
      uint4 a0 = tabu[v0 * 8 + ch];
      uint4 a1 = tabu[v1 * 8 + ch];
      xn4[(t >> 3) * 9 + ch] = a0;
      xn4[((t + 256) >> 3) * 9 + ch] = a1;
      if (t < 128) {
        int v2 = vseg[ebase + ((t + 512) >> 3)];
        uint4 a2 = tabu[v2 * 8 + ch];
        xn4[((t + 512) >> 3) * 9 + ch] = a2;
      }
    } else {
      for (int idx = t; idx < n8; idx += 256) {
        int row = idx >> 3;
        xn4[row * 9 + ch] = tabu[vseg[ebase + row] * 8 + ch];
      }
    }
  } else {
    if (n8 == 768) {
      uint4 a0 = xg[t];
      uint4 a1 = xg[t + 256];
      uint4 a2 = xg[t + 512];
      xn4[(t >> 3) * 9 + ch] = a0;
      xn4[((t + 256) >> 3) * 9 + ch] = a1;
      xn4[((t + 512) >> 3) * 9 + ch] = a2;
    } else if (n8 == 640) {
      uint4 a0 = xg[t];
      uint4 a1 = xg[t + 256];
      xn4[(t >> 3) * 9 + ch] = a0;
      xn4[((t + 256) >> 3) * 9 + ch] = a1;
      if (t < 128) {
        uint4 a2 = xg[t + 512];
        xn4[((t + 512) >> 3) * 9 + ch] = a2;
      }
    } else {
      for (int idx = t; idx < n8; idx += 256)
        xn4[(idx >> 3) * 9 + ch] = xg[idx];
    }
  }
  __syncthreads();
  int lane = t & 63, wid = t >> 6;
  int wave_n = wid & 1, wave_m = wid >> 1;
  int mtA = (mtb + 1) >> 1;
  int m0 = wave_m ? mtA : 0;
  int mcnt = wave_m ? (mtb - mtA) : mtA;
  f16* xnh = (f16*)xn4;
  int chq0 = wave_n * 32 + ((lane >> 4) << 2);   // jn=0 channel quad
  int chq1 = chq0 + 16;                           // jn=1 channel quad
  // stage A: xn += relu(x_gather @ Wa + ba)  (bias via acc init; pk-f16 residual add)
  {
    f32x4 b0 = {bl[chq0], bl[chq0 + 1], bl[chq0 + 2], bl[chq0 + 3]};
    f32x4 b1 = {bl[chq1], bl[chq1 + 1], bl[chq1 + 2], bl[chq1 + 3]};
    f32x4 acc1[3][2];
#pragma unroll
    for (int i = 0; i < 3; i++) { acc1[i][0] = b0; acc1[i][1] = b1; }
    const uint4* Wau = (const uint4*)p.Wa[seg];
    HU w[2][2];
#pragma unroll
    for (int kc = 0; kc < 2; kc++)
#pragma unroll
      for (int jn = 0; jn < 2; jn++)
        w[kc][jn].u = Wau[(((wave_n * 2 + jn) << 1) + kc) * 64 + lane];
    const uint4* xh4 = (const uint4*)p.xh;
#pragma unroll
    for (int i = 0; i < 3; i++) {
      if (i >= mcnt) continue;
      int rowid = ridx[((m0 + i) << 4) + (lane & 15)];
      HU xa, xb;
      xa.u = xh4[(long)rowid * 8 + (lane >> 4)];
      xb.u = xh4[(long)rowid * 8 + 4 + (lane >> 4)];
#pragma unroll
      for (int jn = 0; jn < 2; jn++) {
        acc1[i][jn] = __builtin_amdgcn_mfma_f32_16x16x32_f16(w[0][jn].h, xa.h, acc1[i][jn], 0, 0, 0);
        acc1[i][jn] = __builtin_amdgcn_mfma_f32_16x16x32_f16(w[1][jn].h, xb.h, acc1[i][jn], 0, 0, 0);
      }
    }
#pragma unroll
    for (int i = 0; i < 3; i++) {
      if (i >= mcnt) continue;
      int r = ((m0 + i) << 4) + (lane & 15);
#pragma unroll
      for (int jn = 0; jn < 2; jn++) {
        int chq = jn ? chq1 : chq0;
        half4 cv;
#pragma unroll
        for (int reg = 0; reg < 4; reg++) {
          float v = acc1[i][jn][reg];
          cv[reg] = (f16)(v > 0.f ? v : 0.f);
        }
        half4* pxl = (half4*)(xnh + r * 72 + chq);
        *pxl = *pxl + cv;   // v_pk_add_f16 x2
      }
    }
  }
  __syncthreads();
  // conv MFMAs reading xn4 (neighbor rows via LDS tables); bias via acc init
  f32x4 k0 = {kbl[chq0], kbl[chq0 + 1], kbl[chq0 + 2], kbl[chq0 + 3]};
  f32x4 k1 = {kbl[chq1], kbl[chq1 + 1], kbl[chq1 + 2], kbl[chq1 + 3]};
  f32x4 acc2[3][2];
#pragma unroll
  for (int i = 0; i < 3; i++) { acc2[i][0] = k0; acc2[i][1] = k1; }
  int rdw[3][3];
#pragma unroll
  for (int i = 0; i < 3; i++) {
    if (i >= mcnt) continue;
    int mr = ((m0 + i) << 4) + (lane & 15);
    rdw[i][0] = prevs[mr];
    rdw[i][1] = mr;
    rdw[i][2] = nexts[mr];
  }
  const uint4* Bg = (const uint4*)p.Bp[seg];
  __builtin_amdgcn_s_setprio(1);
  for (int kc = 0; kc < 6; kc++) {
    int w_ = kc >> 1;
    int chunk = ((kc & 1) << 2) + (lane >> 4);
    HU ak[2], xv[3];
#pragma unroll
    for (int jn = 0; jn < 2; jn++)
      ak[jn].u = Bg[((wave_n * 2 + jn) * 6 + kc) * 64 + lane];
#pragma unroll
    for (int i = 0; i < 3; i++)
      if (i < mcnt) xv[i].u = xn4[rdw[i][w_] * 9 + chunk];
#pragma unroll
    for (int i = 0; i < 3; i++)
      if (i < mcnt) {
#pragma unroll
        for (int jn = 0; jn < 2; jn++)
          acc2[i][jn] = __builtin_amdgcn_mfma_f32_16x16x32_f16(ak[jn].h, xv[i].h, acc2[i][jn], 0, 0, 0);
      }
  }
  __builtin_amdgcn_s_setprio(0);
  __syncthreads();  // conv reads of xn4 complete before overwrite
  // epilogue 2: final = xn + relu(conv + Kb), pk-f16 RMW in LDS
#pragma unroll
  for (int i = 0; i < 3; i++) {
    if (i >= mcnt) continue;
    int r = ((m0 + i) << 4) + (lane & 15);
#pragma unroll
    for (int jn = 0; jn < 2; jn++) {
      int chq = jn ? chq1 : chq0;
      half4 cv;
#pragma unroll
      for (int reg = 0; reg < 4; reg++) {
        float v = acc2[i][jn][reg];
        cv[reg] = (f16)(v > 0.f ? v : 0.f);
      }
      half4* pxl = (half4*)(xnh + r * 72 + chq);
      *pxl = *pxl + cv;
    }
  }
  __syncthreads();
  // coalesced copy-out (named scalars; uniform fast paths)
  if (n8 == 768) {
    uint4 c0 = xn4[(t >> 3) * 9 + ch];
    uint4 c1 = xn4[((t + 256) >> 3) * 9 + ch];
    uint4 c2 = xn4[((t + 512) >> 3) * 9 + ch];
    xg[t] = c0;
    xg[t + 256] = c1;
    xg[t + 512] = c2;
  } else if (n8 == 640) {
    uint4 c0 = xn4[(t >> 3) * 9 + ch];
    uint4 c1 = xn4[((t + 256) >> 3) * 9 + ch];
    xg[t] = c0;
    xg[t + 256] = c1;
    if (t < 128) {
      uint4 c2 = xn4[((t + 512) >> 3) * 9 + ch];
      xg[t + 512] = c2;
    }
  } else {
    for (int idx = t; idx < n8; idx += 256)
      xg[idx] = xn4[(idx >> 3) * 9 + ch];
  }
}

// ---------------- p2a apply: CSR gather (padded lists, int4 bucket loads) ------------
// Af[2] ping-pong, one barrier/map; gather(next) overlaps MFMA(cur).

struct Apply2Params {
  const f16* xp[3];
  const int* cnt[3];
  const int* basea[3];
  const int* bucket;
  const f16* Wp[3];
  const float* bias[3];
  int nm;
};

__global__ __launch_bounds__(256) void k_apply2(Apply2Params p, f16* x) {
  __shared__ uint4 Af[2][512];
  __shared__ float bl[3][64];
  __shared__ f16 xf[64 * 72];   // 64 atoms x 64 cols, padded stride 72
  int t = threadIdx.x;
  int a0 = blockIdx.x * 64;
  int lane = t & 63, wid = t >> 6;
  int al = t >> 2, q = t & 3;
  int atom = a0 + al;
  int nm = p.nm;
  if (t < 64 * nm) bl[t >> 6][t & 63] = p.bias[t >> 6][t & 63];
  f32x4 addv[4];
#pragma unroll
  for (int nt = 0; nt < 4; nt++) { f32x4 z = {0.f, 0.f, 0.f, 0.f}; addv[nt] = z; }
  float s[16];
  auto gather = [&](int mi) {
#pragma unroll
    for (int i = 0; i < 16; i++) s[i] = 0.f;
    int cb = 0, base = 0;
    if (atom < NA) { cb = p.cnt[mi][atom]; base = p.basea[mi][atom]; }
    const uint4* xpu = (const uint4*)p.xp[mi];
    // lists padded to multiple of 4 with sentinel (zero-row) edges; base 16B-aligned
    for (int i = 0; i < cb; i += 4) {
      int4 e4 = *(const int4*)(p.bucket + base + i);
      HU va0, vb0, va1, vb1, va2, vb2, va3, vb3;
      va0.u = xpu[(long)e4.x * 8 + q * 2]; vb0.u = xpu[(long)e4.x * 8 + q * 2 + 1];
      va1.u = xpu[(long)e4.y * 8 + q * 2]; vb1.u = xpu[(long)e4.y * 8 + q * 2 + 1];
      va2.u = xpu[(long)e4.z * 8 + q * 2]; vb2.u = xpu[(long)e4.z * 8 + q * 2 + 1];
      va3.u = xpu[(long)e4.w * 8 + q * 2]; vb3.u = xpu[(long)e4.w * 8 + q * 2 + 1];
#pragma unroll
      for (int j = 0; j < 8; j++) {
        s[j] += ((float)va0.s[j] + (float)va1.s[j]) + ((float)va2.s[j] + (float)va3.s[j]);
        s[8 + j] += ((float)vb0.s[j] + (float)vb1.s[j]) + ((float)vb2.s[j] + (float)vb3.s[j]);
      }
    }
  };
  gather(0);
  int jb = ((al >> 4) * 2 + (q >> 1)) * 64 + (q & 1) * 32 + (al & 15);
  for (int mi = 0; mi < nm; mi++) {
    int cur = mi & 1;
    int cbi = (atom < NA) ? p.cnt[mi][atom] : 0;
    float inv = 1.f / (float)(cbi > 0 ? cbi : 1);
    HU o0, o1;
#pragma unroll
    for (int j = 0; j < 8; j++) { o0.s[j] = (f16)(s[j] * inv); o1.s[j] = (f16)(s[8 + j] * inv); }
    Af[cur][jb] = o0.u;
    Af[cur][jb + 16] = o1.u;
    __syncthreads();
    HU af0, af1;
    af0.u = Af[cur][((wid << 1) + 0) * 64 + lane];
    af1.u = Af[cur][((wid << 1) + 1) * 64 + lane];
    const uint4* Wu = (const uint4*)p.Wp[mi];
#pragma unroll
    for (int nt = 0; nt < 4; nt++) {
      HU b0, b1;
      b0.u = Wu[((nt << 1) + 0) * 64 + lane];
      b1.u = Wu[((nt << 1) + 1) * 64 + lane];
      float bv = bl[mi][nt * 16 + (lane & 15)];
      f32x4 z = {bv, bv, bv, bv};
      z = __builtin_amdgcn_mfma_f32_16x16x32_f16(af0.h, b0.h, z, 0, 0, 0);
      z = __builtin_amdgcn_mfma_f32_16x16x32_f16(af1.h, b1.h, z, 0, 0, 0);
#pragma unroll
      for (int r = 0; r < 4; r++) {
        float vv = z[r];
        addv[nt][r] += vv > 0.f ? vv : 0.f;
      }
    }
    if (mi + 1 < nm) gather(mi + 1);   // overlaps this map's MFMA/epilogue latency
  }
  // stash addv to LDS (owner-lane scalar writes), then vector RMW of x
  int arow_w = (wid << 4) + ((lane >> 4) << 2);
#pragma unroll
  for (int nt = 0; nt < 4; nt++) {
    int n = nt * 16 + (lane & 15);
#pragma unroll
    for (int r = 0; r < 4; r++)
      xf[(arow_w + r) * 72 + n] = (f16)addv[nt][r];
  }
  __syncthreads();
#pragma unroll
  for (int u = 0; u < 2; u++) {
    int idx = t + 256 * u;
    int arow = idx >> 3, ch8 = idx & 7;
    int atomw = a0 + arow;
    if (atomw < NA) {
      uint4* px = (uint4*)(x + (long)atomw * 64 + ch8 * 8);
      HU old; old.u = *px;
      HU ad; ad.h = *(half8*)(xf + arow * 72 + ch8 * 8);
      HU o; o.h = old.h + ad.h;   // v_pk_add_f16 x4
      *px = o.u;
    }
  }
}

// ---------------- batch mean over f16 x (padded lists: quad gather, no tail) ----------

__global__ __launch_bounds__(256) void k_meanscatter(const f16* src, const int* bucket,
                                                     const int* basea, const int* cnta,
                                                     float* dst, int nseg) {
  int wid = (blockIdx.x * 256 + threadIdx.x) >> 6;
  int lane = threadIdx.x & 63;
  if (wid >= nseg) return;
  int b0 = basea[wid], cnt = cnta[wid];
  float s = 0.f;
  // list padded to multiple of 4 with sentinel atom NA (zeroed x row); b0 16B-aligned
  for (int i = 0; i < cnt; i += 4) {
    int4 e4 = *(const int4*)(bucket + b0 + i);
    float s0 = (float)src[(long)e4.x * 64 + lane];
    float s1 = (float)src[(long)e4.y * 64 + lane];
    float s2 = (float)src[(long)e4.z * 64 + lane];
    float s3 = (float)src[(long)e4.w * 64 + lane];
    s += (s0 + s1) + (s2 + s3);
  }
  dst[(long)wid * 64 + lane] = s / (float)(cnt > 0 ? cnt : 1);
}

// ---------------- head gemm + fused final dot (no g2 round-trip) ----------

__global__ __launch_bounds__(256) void k_head(const float* g1, const float* W,
                                              const float* bias, const float* linW,
                                              const float* linb, float* out) {
  __shared__ float Wl[4096];
  __shared__ float inl[32 * 64];
  __shared__ float bl[64], lwl[64];
  int t = threadIdx.x;
  int brow = blockIdx.x * 32;
#pragma unroll
  for (int i = 0; i < 4; i++) ((float4*)Wl)[t + 256 * i] = ((const float4*)W)[t + 256 * i];
  if (t < 64) { bl[t] = bias[t]; lwl[t] = linW[t]; }
#pragma unroll
  for (int i = 0; i < 2; i++) {
    int idx = t + 256 * i;
    int r = idx >> 4, q = idx & 15;
    ((float4*)inl)[idx] = ((const float4*)(g1 + (long)(brow + r) * 64))[q];
  }
  __syncthreads();
  int c = t & 63, rq = t >> 6;
  float acc[8];
#pragma unroll
  for (int i = 0; i < 8; i++) acc[i] = 0.f;
  for (int j = 0; j < 64; j += 4) {
    float w0 = Wl[(j + 0) * 64 + c], w1 = Wl[(j + 1) * 64 + c];
    float w2 = Wl[(j + 2) * 64 + c], w3 = Wl[(j + 3) * 64 + c];
#pragma unroll
    for (int i = 0; i < 8; i++) {
      int r = rq * 8 + i;
      float4 v = *(const float4*)&inl[r * 64 + j];
      acc[i] += v.x * w0 + v.y * w1 + v.z * w2 + v.w * w3;
    }
  }
  float lw = lwl[c];
  float lb = linb[0];
#pragma unroll
  for (int i = 0; i < 8; i++) {
    float v = acc[i] + bl[c];
    v = (v > 0.f ? v : 0.f) * lw;
    for (int o = 32; o > 0; o >>= 1) v += __shfl_down(v, o, 64);
    if (c == 0) out[brow + rq * 8 + i] = v + lb;
  }
}

__global__ __launch_bounds__(256) void k_zero_out(float* out, int n) {
  for (int i = blockIdx.x * 256 + threadIdx.x; i < n; i += gridDim.x * 256) out[i] = 0.f;
}

// ---------------- launcher ----------------

extern "C" void kernel_launch(void* const* d_in, const int* in_sizes, int n_in,
                              void* d_out, int out_size, void* d_ws, size_t ws_size,
                              hipStream_t stream) {
  (void)in_sizes; (void)n_in;

  const int* x_atom = (const int*)d_in[0];
  const int* vals[5] = {(const int*)d_in[1], (const int*)d_in[4], (const int*)d_in[7],
                        (const int*)d_in[10], (const int*)d_in[13]};
  const int* rowm[5] = {(const int*)d_in[2], (const int*)d_in[5], (const int*)d_in[8],
                        (const int*)d_in[11], (const int*)d_in[14]};
  const int* batch = (const int*)d_in[16];
  const float* aemb0 = (const float*)d_in[17];
  const float* aemb1 = (const float*)d_in[18];
  const float* aemb2 = (const float*)d_in[19];
  const float* path_emb = (const float*)d_in[20];
  const float* cycle_emb = (const float*)d_in[21];
  const float* pW_a2p = (const float*)d_in[22];
  const float* pb_a2p = (const float*)d_in[23];
  const float* pW_p2a = (const float*)d_in[24];
  const float* pb_p2a = (const float*)d_in[25];
  const float* pK = (const float*)d_in[26];
  const float* pKb = (const float*)d_in[27];
  const float* cW_a2p = (const float*)d_in[28];
  const float* cb_a2p = (const float*)d_in[29];
  const float* cW_p2a = (const float*)d_in[30];
  const float* cb_p2a = (const float*)d_in[31];
  const float* cK = (const float*)d_in[32];
  const float* cKb = (const float*)d_in[33];
  const float* alW = (const float*)d_in[34];
  const float* alb = (const float*)d_in[35];
  const float* linW = (const float*)d_in[36];
  const float* linb = (const float*)d_in[37];

  static const int Em[5] = {300000, 400000, 500000, 200000, 240000};
  static const int Km[5] = {3, 4, 5, 5, 6};
  static const int Ppb[5] = {32, 24, 16, 16, 16};
  const int CNT_N = 5 * 100000 + NBATCH;  // 504096
  const int BUCKET_N = 4103744;           // gapped + pad slack (capbase layout)

  char* ws = (char*)d_ws;
  size_t off = 0;
  auto alloc = [&](size_t nbytes) -> char* {
    char* p = ws + off;
    off = (off + nbytes + 255) & ~(size_t)255;
    return p;
  };
  f16* x = (f16*)alloc(((size_t)NA + 8) * 64 * 2);   // f16 master (+ zero sentinel row)
  __half* xp[5];
  for (int m = 0; m < 5; m++) xp[m] = (__half*)alloc(((size_t)Em[m] + 8) * 64 * 2);
  float* g1 = (float*)alloc((size_t)NBATCH * 64 * 4);
  int* cnt = (int*)alloc((size_t)CNT_N * 4);
  int* basea = (int*)alloc((size_t)CNT_N * 4);
  int* bucket = (int*)alloc((size_t)BUCKET_N * 4);
  unsigned* ccursor = (unsigned*)alloc((size_t)NBIN * 4);
  f16* Bp = (f16*)alloc((size_t)10 * 12288 * 2);
  f16* Wpk = (f16*)alloc((size_t)20 * 4096 * 2);
  f16* Tabs = (f16*)alloc((size_t)1664 * 2);
  // pairs array (~16.4 MB) aliases xp[2]: consumed by k_passB before k_fused writes
  // xp[2]; sentinel row at xp[2]+64MB is beyond the pairs region.
  unsigned* pairs = (unsigned*)xp[2];

  if (ws_size < off) {
    k_zero_out<<<16, 256, 0, stream>>>((float*)d_out, out_size);
    return;
  }

  // ---- merged prep (atom_init + prepB + prepW + prepT + initc + sentinel zeroing)
  {
    PrepParams q;
    q.xa = x_atom; q.e0 = aemb0; q.e1 = aemb1; q.e2 = aemb2; q.x = x;
    q.pK = pK; q.cK = cK; q.Bp = Bp;
    q.pW = pW_p2a; q.cW = cW_p2a; q.pWa = pW_a2p; q.cWa = cW_a2p; q.Wp = Wpk;
    q.path_emb = path_emb; q.cycle_emb = cycle_emb; q.T = Tabs;
    q.ccursor = ccursor;
    for (int m = 0; m < 5; m++) q.xpz[m] = (f16*)xp[m];
    k_prep<<<7059, 256, 0, stream>>>(q);
  }

  // ---- CSR build: two-level counting sort (no scan; gapped + padded bucket)
  PassAParams pp;
  {
    int s = 0;
    for (int m = 0; m < 5; m++) { pp.row[m] = rowm[m]; pp.start[m] = s; s += Em[m]; }
    pp.row[5] = batch; pp.start[5] = s;
    pp.total = s + NA;  // 1740000
  }
  k_passA<<<(1740000 + 8191) / 8192, 256, 0, stream>>>(pp, ccursor, pairs);
  k_passB<<<NBIN, 256, 0, stream>>>(ccursor, pairs, bucket, cnt, basea);

  int apply_blocks = (NA + 63) / 64;  // 1563

  auto p2aW = [&](int l, int m) -> const f16* {
    return (m < 3) ? Wpk + (size_t)(l * 3 + m) * 4096
                   : Wpk + (size_t)(6 + l * 2 + (m - 3)) * 4096;
  };
  auto p2aB = [&](int l, int m) -> const float* {
    return (m < 3) ? pb_p2a + (l * 3 + m) * 64 : cb_p2a + (l * 2 + (m - 3)) * 64;
  };

  for (int l = 0; l < 2; l++) {
    // === paths group (maps 0..2), non-cyclic
    {
      FusedParams fp{};
      fp.nseg = 3; fp.cyclic = 0; fp.xh = x; fp.use_tab = (l == 0) ? 1 : 0;
      int bs = 0;
      for (int m = 0; m < 3; m++) {
        fp.gidx[m] = rowm[m]; fp.xp[m] = xp[m];
        fp.vals[m] = vals[m]; fp.tab[m] = Tabs + (size_t)m * 384;
        fp.Wa[m] = Wpk + (size_t)(10 + l * 3 + m) * 4096;
        fp.ba[m] = pb_a2p + (l * 3 + m) * 64;
        fp.Bp[m] = Bp + (size_t)(l * 3 + m) * 12288;
        fp.Kb[m] = pKb + (l * 3 + m) * 64;
        fp.k[m] = Km[m]; fp.P[m] = Em[m] / Km[m]; fp.ppb[m] = Ppb[m];
        fp.blk_start[m] = bs;
        bs += (fp.P[m] + fp.ppb[m] - 1) / fp.ppb[m];
      }
      k_fused<<<bs, 256, 0, stream>>>(fp);

      Apply2Params ap{};
      ap.nm = 3; ap.bucket = bucket;
      for (int m = 0; m < 3; m++) {
        ap.xp[m] = (const f16*)xp[m];
        ap.cnt[m] = cnt + (size_t)m * 100000;
        ap.basea[m] = basea + (size_t)m * 100000;
        ap.Wp[m] = p2aW(l, m); ap.bias[m] = p2aB(l, m);
      }
      k_apply2<<<apply_blocks, 256, 0, stream>>>(ap, x);
    }
    // === cycles group (maps 3..4), cyclic
    {
      FusedParams fp{};
      fp.nseg = 2; fp.cyclic = 1; fp.xh = x; fp.use_tab = (l == 0) ? 1 : 0;
      int bs = 0;
      for (int m = 3; m < 5; m++) {
        int i = m - 3;
        fp.gidx[i] = rowm[m]; fp.xp[i] = xp[m];
        fp.vals[i] = vals[m]; fp.tab[i] = Tabs + 1152 + (size_t)i * 256;
        fp.Wa[i] = Wpk + (size_t)(16 + l * 2 + i) * 4096;
        fp.ba[i] = cb_a2p + (l * 2 + i) * 64;
        fp.Bp[i] = Bp + (size_t)(6 + l * 2 + i) * 12288;
        fp.Kb[i] = cKb + (l * 2 + i) * 64;
        fp.k[i] = Km[m]; fp.P[i] = Em[m] / Km[m]; fp.ppb[i] = Ppb[m];
        fp.blk_start[i] = bs;
        bs += (fp.P[i] + fp.ppb[i] - 1) / fp.ppb[i];
      }
      k_fused<<<bs, 256, 0, stream>>>(fp);

      Apply2Params ap{};
      ap.nm = 2; ap.bucket = bucket;
      for (int m = 3; m < 5; m++) {
        int i = m - 3;
        ap.xp[i] = (const f16*)xp[m];
        ap.cnt[i] = cnt + (size_t)m * 100000;
        ap.basea[i] = basea + (size_t)m * 100000;
        ap.Wp[i] = p2aW(l, m); ap.bias[i] = p2aB(l, m);
      }
      k_apply2<<<apply_blocks, 256, 0, stream>>>(ap, x);
    }
  }

  // ---- head (basea entries for the batch segment are GLOBAL bucket positions)
  k_meanscatter<<<NBATCH / 4, 256, 0, stream>>>(x, bucket, basea + 500000,
                                                cnt + 500000, g1, NBATCH);
  k_head<<<NBATCH / 32, 256, 0, stream>>>(g1, alW, alb, linW, linb, (float*)d_out);
}